// Round 11
// baseline (763.676 us; speedup 1.0000x reference)
//
#include <hip/hip_runtime.h>
#include <hip/hip_bf16.h>

#define DEVI __device__ __forceinline__

typedef __attribute__((ext_vector_type(8))) __bf16 bf16x8;
typedef __attribute__((ext_vector_type(4))) float f32x4;
typedef __attribute__((ext_vector_type(4))) unsigned short u16x4;
typedef __attribute__((ext_vector_type(8))) unsigned short u16x8;

DEVI unsigned short f2bf(float f) {
  unsigned int u = __float_as_uint(f);
  u += 0x7FFFu + ((u >> 16) & 1u);   // RNE
  return (unsigned short)(u >> 16);
}
DEVI float bf2f(unsigned short u) {
  return __uint_as_float(((unsigned int)u) << 16);
}

#define GLD16(g, l) __builtin_amdgcn_global_load_lds(                      \
    (const __attribute__((address_space(1))) void*)(g),                    \
    (__attribute__((address_space(3))) void*)(l), 16, 0, 0)

// ---------------------------------------------------------------- helpers

__global__ __launch_bounds__(256) void cast_k(const float* __restrict__ in,
                                              unsigned short* __restrict__ out,
                                              int n4) {
  for (int i = blockIdx.x * 256 + threadIdx.x; i < n4; i += gridDim.x * 256) {
    f32x4 v = ((const f32x4*)in)[i];
    u16x4 o;
    o.x = f2bf(v.x); o.y = f2bf(v.y); o.z = f2bf(v.z); o.w = f2bf(v.w);
    ((u16x4*)out)[i] = o;
  }
}

// colnorm phase 1: partial column sumsq over a 64-row x 512-col tile.
__global__ __launch_bounds__(256) void colnorm1_k(const float* __restrict__ v,
                                                  float* __restrict__ part,
                                                  int cols) {
  const int tid = threadIdx.x;
  const int g = tid & 127;
  const int s = tid >> 7;
  const int c0 = blockIdx.x * 512;
  const int r0 = blockIdx.y * 64 + s * 32;
  const float* base = v + (size_t)r0 * cols + c0 + g * 4;
  f32x4 acc = {};
#pragma unroll 4
  for (int i = 0; i < 32; ++i) {
    f32x4 x = *(const f32x4*)(base + (size_t)i * cols);
    acc.x += x.x * x.x; acc.y += x.y * x.y;
    acc.z += x.z * x.z; acc.w += x.w * x.w;
  }
  __shared__ f32x4 red[256];
  red[tid] = acc;
  __syncthreads();
  if (s == 0) {
    f32x4 a = red[tid], b = red[tid + 128];
    f32x4 o;
    o.x = a.x + b.x; o.y = a.y + b.y; o.z = a.z + b.z; o.w = a.w + b.w;
    *(f32x4*)(part + (size_t)blockIdx.y * cols + c0 + g * 4) = o;
  }
}

// colnorm phase 2: s[c] = g[c] * rsqrt(sum_rc part[rc][c])
__global__ __launch_bounds__(256) void colnorm2_k(const float* __restrict__ part,
                                                  const float* __restrict__ g,
                                                  float* __restrict__ s,
                                                  int cols, int nrc) {
  const int c = blockIdx.x * 256 + threadIdx.x;
  float acc = 0.f;
  for (int i = 0; i < nrc; ++i) acc += part[(size_t)i * cols + c];
  s[c] = g[c] * rsqrtf(acc);
}

__global__ __launch_bounds__(256) void scale_cast_k(const float* __restrict__ in,
                                                    const float* __restrict__ s,
                                                    unsigned short* __restrict__ out,
                                                    int cols, int n4) {
  const int cmask4 = (cols >> 2) - 1;
  for (int i = blockIdx.x * 256 + threadIdx.x; i < n4; i += gridDim.x * 256) {
    f32x4 v = ((const f32x4*)in)[i];
    f32x4 sv = ((const f32x4*)s)[i & cmask4];
    u16x4 o;
    o.x = f2bf(v.x * sv.x); o.y = f2bf(v.y * sv.y);
    o.z = f2bf(v.z * sv.z); o.w = f2bf(v.w * sv.w);
    ((u16x4*)out)[i] = o;
  }
}

// LayerNorm: one block per row of 2048 fp32, out bf16
__global__ __launch_bounds__(256) void ln_k(const float* __restrict__ x,
                                            const float* __restrict__ g,
                                            const float* __restrict__ b,
                                            unsigned short* __restrict__ out) {
  const int tid = threadIdx.x, lane = tid & 63, wid = tid >> 6;
  const int row = blockIdx.x;
  const float* xr = x + (size_t)row * 2048;
  f32x4 a0 = ((const f32x4*)xr)[tid];
  f32x4 a1 = ((const f32x4*)xr)[tid + 256];
  float s = a0.x + a0.y + a0.z + a0.w + a1.x + a1.y + a1.z + a1.w;
  float ss = a0.x * a0.x + a0.y * a0.y + a0.z * a0.z + a0.w * a0.w +
             a1.x * a1.x + a1.y * a1.y + a1.z * a1.z + a1.w * a1.w;
#pragma unroll
  for (int m = 1; m < 64; m <<= 1) {
    s += __shfl_xor(s, m);
    ss += __shfl_xor(ss, m);
  }
  __shared__ float red[8];
  if (lane == 0) { red[wid] = s; red[4 + wid] = ss; }
  __syncthreads();
  s = red[0] + red[1] + red[2] + red[3];
  ss = red[4] + red[5] + red[6] + red[7];
  const float mu = s * (1.f / 2048.f);
  const float var = ss * (1.f / 2048.f) - mu * mu;
  const float rs = rsqrtf(var + 1e-5f);
  f32x4 g0 = ((const f32x4*)g)[tid], g1 = ((const f32x4*)g)[tid + 256];
  f32x4 b0 = ((const f32x4*)b)[tid], b1 = ((const f32x4*)b)[tid + 256];
  u16x4 o0, o1;
  o0.x = f2bf((a0.x - mu) * rs * g0.x + b0.x);
  o0.y = f2bf((a0.y - mu) * rs * g0.y + b0.y);
  o0.z = f2bf((a0.z - mu) * rs * g0.z + b0.z);
  o0.w = f2bf((a0.w - mu) * rs * g0.w + b0.w);
  o1.x = f2bf((a1.x - mu) * rs * g1.x + b1.x);
  o1.y = f2bf((a1.y - mu) * rs * g1.y + b1.y);
  o1.z = f2bf((a1.z - mu) * rs * g1.z + b1.z);
  o1.w = f2bf((a1.w - mu) * rs * g1.w + b1.w);
  unsigned short* orow = out + (size_t)row * 2048;
  *(u16x4*)(orow + 4 * tid) = o0;
  *(u16x4*)(orow + 1024 + 4 * tid) = o1;
}

// V transpose: V slice of qkv [4096][6144] -> vt [32][128][2048]
__global__ __launch_bounds__(256) void vtrans_k(const unsigned short* __restrict__ qkv,
                                                unsigned short* __restrict__ vt) {
  __shared__ unsigned short t[64][134];
  const int tid = threadIdx.x;
  const int bh = blockIdx.x >> 5, st = blockIdx.x & 31;
  const int b = bh >> 4, h = bh & 15;
  const unsigned short* vb = qkv + (size_t)(b * 2048 + st * 64) * 6144 + 4096 + h * 128;
#pragma unroll
  for (int i = 0; i < 4; ++i) {
    int f = tid + (i << 8);
    int row = f >> 4, c8 = f & 15;
    u16x8 x = *(const u16x8*)(vb + (size_t)row * 6144 + c8 * 8);
#pragma unroll
    for (int j = 0; j < 4; ++j) {
      unsigned int pk = ((unsigned int)x[2 * j + 1] << 16) | x[2 * j];
      *(unsigned int*)&t[row][c8 * 8 + 2 * j] = pk;
    }
  }
  __syncthreads();
  const int lane = tid & 63, wid = tid >> 6;
  unsigned short* ob = vt + ((size_t)bh << 18) + (st << 6);
#pragma unroll
  for (int j = 0; j < 32; ++j) {
    int d = (wid << 5) + j;
    ob[((size_t)d << 11) + lane] = t[lane][d];
  }
}

// split-K4 reduce: out = sum(bf16 parts 0..3) + bias + res (fp32)
__global__ __launch_bounds__(256) void g4red_k(const unsigned short* __restrict__ parts,
                                               const float* __restrict__ bias,
                                               const float* __restrict__ res,
                                               float* __restrict__ out, int n4) {
  const size_t PS = (size_t)4096 * 2048;
  for (int i = blockIdx.x * 256 + threadIdx.x; i < n4; i += gridDim.x * 256) {
    u16x4 a = ((const u16x4*)(parts))[i];
    u16x4 b = ((const u16x4*)(parts + PS))[i];
    u16x4 c = ((const u16x4*)(parts + 2 * PS))[i];
    u16x4 d = ((const u16x4*)(parts + 3 * PS))[i];
    f32x4 r = ((const f32x4*)res)[i];
    f32x4 bb = ((const f32x4*)bias)[i & 511];
    f32x4 o;
    o.x = bf2f(a.x) + bf2f(b.x) + bf2f(c.x) + bf2f(d.x) + r.x + bb.x;
    o.y = bf2f(a.y) + bf2f(b.y) + bf2f(c.y) + bf2f(d.y) + r.y + bb.y;
    o.z = bf2f(a.z) + bf2f(b.z) + bf2f(c.z) + bf2f(d.z) + r.z + bb.z;
    o.w = bf2f(a.w) + bf2f(b.w) + bf2f(c.w) + bf2f(d.w) + r.w + bb.w;
    ((f32x4*)out)[i] = o;
  }
}

// ---------------------------------------------------------------- GEMM params
struct GemmP {
  const unsigned short* A;
  const unsigned short* B;
  const float* bias;
  const float* res;
  float* outF;
  unsigned short* outH;
  int M, N, K;
};

// ---------------------------------------------------------------- 128^2 GEMM (2-phase)
// +bias +res -> fp32
DEVI void gemm128_body(const GemmP& p, int m0, int n0, int k0, int nk) {
  const int tid = threadIdx.x, lane = tid & 63, wid = tid >> 6;
  const int K = p.K;
  const int wr = wid >> 1, wc = wid & 1;

  __shared__ __align__(16) unsigned short sA[2][4096];
  __shared__ __align__(16) unsigned short sB[2][4096];

  const int c0 = tid, c1 = tid + 256;
  const unsigned short* gA0 = p.A + (size_t)(m0 + (c0 >> 2)) * K + k0 + ((c0 & 3) << 3);
  const unsigned short* gA1 = p.A + (size_t)(m0 + (c1 >> 2)) * K + k0 + ((c1 & 3) << 3);
  const unsigned short* gB0 = p.B + (size_t)(n0 + (c0 >> 2)) * K + k0 + ((c0 & 3) << 3);
  const unsigned short* gB1 = p.B + (size_t)(n0 + (c1 >> 2)) * K + k0 + ((c1 & 3) << 3);
  const int l0 = wid << 9, l1 = (wid << 9) + 2048;

  f32x4 acc[4][4] = {};
  const int arow = (wr << 6) + (lane & 15);
  const int brow = (wc << 6) + (lane & 15);
  const int koff = (lane >> 4) << 3;

#define STAGE128(bufi, t) do { int ko = (t) << 5;       \
    GLD16(gA0 + ko, &sA[bufi][l0]);                     \
    GLD16(gA1 + ko, &sA[bufi][l1]);                     \
    GLD16(gB0 + ko, &sB[bufi][l0]);                     \
    GLD16(gB1 + ko, &sB[bufi][l1]); } while (0)

  STAGE128(0, 0);
  __syncthreads();
  int cur = 0;
  for (int t = 0; t < nk; ++t) {
    if (t + 1 < nk) STAGE128(cur ^ 1, t + 1);
    bf16x8 af[4], bfr[4];
#pragma unroll
    for (int i = 0; i < 4; ++i)
      af[i] = *(const bf16x8*)&sA[cur][(arow + (i << 4)) * 32 + koff];
#pragma unroll
    for (int i = 0; i < 4; ++i)
      bfr[i] = *(const bf16x8*)&sB[cur][(brow + (i << 4)) * 32 + koff];
#pragma unroll
    for (int i = 0; i < 4; ++i)
#pragma unroll
      for (int j = 0; j < 4; ++j)
        acc[i][j] = __builtin_amdgcn_mfma_f32_16x16x32_bf16(af[i], bfr[j], acc[i][j], 0, 0, 0);
    __syncthreads();
    cur ^= 1;
  }
#undef STAGE128

  const int rbase = m0 + (wr << 6) + ((lane >> 4) << 2);
  const int cbase = n0 + (wc << 6) + (lane & 15);
#pragma unroll
  for (int mi = 0; mi < 4; ++mi) {
#pragma unroll
    for (int ni = 0; ni < 4; ++ni) {
      const int col = cbase + (ni << 4);
#pragma unroll
      for (int r = 0; r < 4; ++r) {
        const int row = rbase + (mi << 4) + r;
        const size_t o = (size_t)row * p.N + col;
        p.outF[o] = acc[mi][ni][r] + p.bias[col] + p.res[o];
      }
    }
  }
}

// G2: M=4096,N=2048 -> nbm=32,nbn=16. Region/XCD = 8x8.
__global__ __launch_bounds__(256) void g2_proj128(GemmP p) {
  const int x = blockIdx.x & 7, i = blockIdx.x >> 3;  // i in [0,64)
  const int bm = (x >> 1) * 8 + (i >> 3);
  const int bn = (x & 1) * 8 + (i & 7);
  gemm128_body(p, bm << 7, bn << 7, 0, p.K >> 5);
}

// ---------------------------------------------------------------- 256^2 tile common
DEVI void setup256(const GemmP& p, int m0, int n0, int k0,
                   const unsigned short*& gsA0, const unsigned short*& gsA1,
                   const unsigned short*& gsB0, const unsigned short*& gsB1) {
  const int tid = threadIdx.x;
  int r_[2], c_[2];
#pragma unroll
  for (int j = 0; j < 2; ++j) {
    int d = tid * 16 + j * 8192;
    int w = (d & 1023) ^ (((d >> 9) & 1) << 5);   // st_16x32 involution
    r_[j] = ((d >> 10) << 4) + (w >> 6);
    c_[j] = (w & 63) >> 1;
  }
  gsA0 = p.A + (size_t)(m0 + r_[0]) * p.K + k0 + c_[0];
  gsA1 = p.A + (size_t)(m0 + r_[1]) * p.K + k0 + c_[1];
  gsB0 = p.B + (size_t)(n0 + r_[0]) * p.K + k0 + c_[0];
  gsB1 = p.B + (size_t)(n0 + r_[1]) * p.K + k0 + c_[1];
}

// epilogue: EPI 0 = +bias -> bf16   2 = +bias fast-GELU -> bf16   5 = raw -> bf16
template <int EPI>
DEVI void epi256(const GemmP& p, f32x4 (&acc)[8][4], int m0, int n0,
                 unsigned short* outH) {
  const int lane = threadIdx.x & 63, wid = threadIdx.x >> 6;
  const int wr = wid >> 2, wc = wid & 3;
  const int lr = lane & 15, lk = lane >> 4;
  const int rbase = m0 + wr * 128 + (lk << 2);
  const int cbase = n0 + wc * 64 + lr;
#pragma unroll
  for (int m = 0; m < 8; ++m) {
#pragma unroll
    for (int n = 0; n < 4; ++n) {
      const int col = cbase + (n << 4);
      const float bb = (EPI == 5) ? 0.f : p.bias[col];
#pragma unroll
      for (int r = 0; r < 4; ++r) {
        const int row = rbase + (m << 4) + r;
        float v = acc[m][n][r] + bb;
        if constexpr (EPI == 2) {
          float y = 0.7978845608028654f * (v + 0.044715f * v * v * v);
          float u = __expf(2.f * y);
          v = (y > 40.f) ? v : v * (u / (u + 1.f));
        }
        outH[(size_t)row * p.N + col] = f2bf(v);
      }
    }
  }
}

// ---------------------------------------------------------------- 256^2 2-phase
template <int EPI>
DEVI void gemm2p_body(const GemmP& p, unsigned short* lds_raw, int m0, int n0,
                      int k0, int nk, unsigned short* outH) {
  const int tid = threadIdx.x, lane = tid & 63, wid = tid >> 6;
  const int wr = wid >> 2, wc = wid & 3;
  const int lr = lane & 15, lk = lane >> 4;
  const int fb = (lr * 64 + lk * 16) ^ ((lr & 8) << 2);

  const unsigned short *gsA0, *gsA1, *gsB0, *gsB1;
  setup256(p, m0, n0, k0, gsA0, gsA1, gsB0, gsB1);

#define STG2(b, kt) do { unsigned short* _d = lds_raw + ((b) << 14);     \
    GLD16(gsA0 + ((size_t)(kt) << 5), _d + (tid << 3));                  \
    GLD16(gsA1 + ((size_t)(kt) << 5), _d + 4096 + (tid << 3));           \
    GLD16(gsB0 + ((size_t)(kt) << 5), _d + 8192 + (tid << 3));           \
    GLD16(gsB1 + ((size_t)(kt) << 5), _d + 12288 + (tid << 3)); } while (0)

  f32x4 acc[8][4] = {};
  STG2(0, 0);
  __syncthreads();
  int cur = 0;
  for (int t = 0; t < nk; ++t) {
    if (t + 1 < nk) STG2(cur ^ 1, t + 1);
    const char* tA = (const char*)(lds_raw + (cur << 14));
    const char* tB = tA + 16384;
    bf16x8 a_[8], b_[4];
#pragma unroll
    for (int n = 0; n < 4; ++n)
      b_[n] = *(const bf16x8*)(tB + (((wc << 2) + n) << 10) + fb);
#pragma unroll
    for (int m = 0; m < 8; ++m)
      a_[m] = *(const bf16x8*)(tA + (((wr << 3) + m) << 10) + fb);
#pragma unroll
    for (int m = 0; m < 8; ++m)
#pragma unroll
      for (int n = 0; n < 4; ++n)
        acc[m][n] = __builtin_amdgcn_mfma_f32_16x16x32_bf16(a_[m], b_[n], acc[m][n], 0, 0, 0);
    __syncthreads();
    cur ^= 1;
  }
#undef STG2
  epi256<EPI>(p, acc, m0, n0, outH);
}

// ---------------------------------------------------------------- 256^2 ring-4
// counted-vmcnt pipeline (T3+T4 mechanism, race-proof variant):
// 4 x 32KB K-tile buffers; step t reads buf[t&3], stages tile t+3 into
// buf[(t+3)&3] (== buffer consumed at step t-1, dead past the barrier);
// waits vmcnt(8) (leaves tiles t+2,t+3 in flight; tile t+1 guaranteed
// arrived) -> never drains to 0 in steady state. Prefetch distance 3 steps.
template <int EPI>
DEVI void gemmr4_body(const GemmP& p, unsigned short* lds_raw, int m0, int n0,
                      int k0, int nk, unsigned short* outH) {
  const int tid = threadIdx.x, lane = tid & 63, wid = tid >> 6;
  const int wr = wid >> 2, wc = wid & 3;
  const int lr = lane & 15, lk = lane >> 4;
  const int fb = (lr * 64 + lk * 16) ^ ((lr & 8) << 2);

  const unsigned short *gsA0, *gsA1, *gsB0, *gsB1;
  setup256(p, m0, n0, k0, gsA0, gsA1, gsB0, gsB1);

#define STGR(bufi, kt) do { unsigned short* _d = lds_raw + ((bufi) << 14); \
    GLD16(gsA0 + ((size_t)(kt) << 5), _d + (tid << 3));                    \
    GLD16(gsA1 + ((size_t)(kt) << 5), _d + 4096 + (tid << 3));             \
    GLD16(gsB0 + ((size_t)(kt) << 5), _d + 8192 + (tid << 3));             \
    GLD16(gsB1 + ((size_t)(kt) << 5), _d + 12288 + (tid << 3)); } while (0)

  f32x4 acc[8][4] = {};
  STGR(0, 0);
  STGR(1, 1);
  STGR(2, 2);
  asm volatile("s_waitcnt vmcnt(8)" ::: "memory");   // tile 0 arrived
  __builtin_amdgcn_s_barrier();

  for (int t = 0; t < nk; ++t) {
    const char* tA = (const char*)(lds_raw + ((t & 3) << 14));
    const char* tB = tA + 16384;
    bf16x8 a_[8], b_[4];
#pragma unroll
    for (int n = 0; n < 4; ++n)
      b_[n] = *(const bf16x8*)(tB + (((wc << 2) + n) << 10) + fb);
#pragma unroll
    for (int m = 0; m < 8; ++m)
      a_[m] = *(const bf16x8*)(tA + (((wr << 3) + m) << 10) + fb);
    if (t + 3 < nk) STGR((t + 3) & 3, t + 3);
    asm volatile("s_waitcnt lgkmcnt(0)" ::: "memory");
    __builtin_amdgcn_sched_barrier(0);
    __builtin_amdgcn_s_setprio(1);
#pragma unroll
    for (int m = 0; m < 8; ++m)
#pragma unroll
      for (int n = 0; n < 4; ++n)
        acc[m][n] = __builtin_amdgcn_mfma_f32_16x16x32_bf16(a_[m], b_[n], acc[m][n], 0, 0, 0);
    __builtin_amdgcn_s_setprio(0);
    if (t + 3 < nk)      asm volatile("s_waitcnt vmcnt(8)" ::: "memory");
    else if (t + 2 < nk) asm volatile("s_waitcnt vmcnt(4)" ::: "memory");
    else if (t + 1 < nk) asm volatile("s_waitcnt vmcnt(0)" ::: "memory");
    __builtin_amdgcn_s_barrier();
  }
#undef STGR
  epi256<EPI>(p, acc, m0, n0, outH);
}

// G1 (256^2 2-phase): M=4096,N=6144 -> nbm=16,nbn=24; region 8x6 per XCD.
__global__ __launch_bounds__(512, 2) void g1_qkv256(GemmP p) {
  extern __shared__ unsigned short lds_raw[];
  const int x = blockIdx.x & 7, i = blockIdx.x >> 3;   // i in [0,48)
  const int bm = (x & 1) * 8 + (i & 7);
  const int bn = (x >> 1) * 6 + (i >> 3);
  gemm2p_body<0>(p, lds_raw, bm << 8, bn << 8, 0, p.K >> 5, p.outH);
}
// G3 ring-4 (counted vmcnt, 128KB LDS, 1 block/CU). A/B arm vs g4 (2-phase).
__global__ __launch_bounds__(512, 1) void g3_fc256r4(GemmP p) {
  extern __shared__ unsigned short lds_raw[];
  const int x = blockIdx.x & 7, i = blockIdx.x >> 3;   // i in [0,64)
  const int bm = (x & 1) * 8 + (i & 7);
  const int bn = (x >> 1) * 8 + (i >> 3);
  gemmr4_body<2>(p, lds_raw, bm << 8, bn << 8, 0, p.K >> 5, p.outH);
}
// G4 (256^2 2-phase, split-K4): identical per-block work to g3 (control arm).
__global__ __launch_bounds__(512, 2) void g4_splitk256(GemmP p) {
  extern __shared__ unsigned short lds_raw[];
  const int x = blockIdx.x & 7, i = blockIdx.x >> 3;   // i in [0,64)
  const int ks = x & 3;
  const int bm = (x >> 2) * 8 + (i >> 3);
  const int bn = i & 7;
  unsigned short* outH = p.outH + (size_t)ks * 4096 * 2048;
  gemm2p_body<5>(p, lds_raw, bm << 8, bn << 8, ks << 11, 64, outH);
}

// ---------------------------------------------------------------- attention
// QBLK=128 (8 waves). Q,K from unified qkv [4096][6144]; V^T [32][128][2048].
__global__ __launch_bounds__(512) void attn_k(const unsigned short* __restrict__ qkv,
                                              const unsigned short* __restrict__ Vt,
                                              unsigned short* __restrict__ O) {
  const int tid = threadIdx.x, lane = tid & 63, wid = tid >> 6;
  const int bid = blockIdx.x;                 // grid = 512
  const int pos = bid >> 3;                   // [0,64)
  const int bh = (bid & 7) * 4 + (pos >> 4);
  const int qt = pos & 15;
  const int q0 = qt * 128 + wid * 16;
  const int b = bh >> 4, h = bh & 15;

  __shared__ __align__(16) unsigned short sK[64 * 128];
  __shared__ __align__(16) unsigned short sV[128 * 64];
  __shared__ __align__(16) unsigned short sP[8][16 * 72];

  const unsigned short* Qb = qkv + (size_t)(b * 2048) * 6144 + h * 128;
  const unsigned short* Kb = qkv + (size_t)(b * 2048) * 6144 + 2048 + h * 128;
  const unsigned short* Vb = Vt + ((size_t)bh << 18);

  bf16x8 qf[4];
  {
    const unsigned short* qp = Qb + (size_t)(q0 + (lane & 15)) * 6144 + ((lane >> 4) << 3);
#pragma unroll
    for (int kk = 0; kk < 4; ++kk) qf[kk] = *(const bf16x8*)(qp + kk * 32);
  }

  int koffs[2], voffs[2];
#pragma unroll
  for (int i = 0; i < 2; ++i) {
    const int c = tid + (i << 9);
    const int kv = c >> 4, jj = c & 15;
    const int js = (jj & 8) | ((jj ^ kv) & 7);
    koffs[i] = kv * 6144 + (js << 3);
    const int d = c >> 3, j2 = c & 7;
    const int js2 = j2 ^ (d & 7);
    voffs[i] = d * 2048 + (js2 << 3);
  }
  u16x8 kreg[2], vreg[2];
  auto PREF = [&](int kt) {
    const int kv0 = kt << 6;
    const unsigned short* kb = Kb + (size_t)kv0 * 6144;
#pragma unroll
    for (int i = 0; i < 2; ++i) {
      kreg[i] = *(const u16x8*)(kb + koffs[i]);
      vreg[i] = *(const u16x8*)(Vb + kv0 + voffs[i]);
    }
  };

  f32x4 oacc[8] = {};
  float mrun = -3e38f, lrun = 0.f;
  PREF(0);

  for (int kt = 0; kt < 32; ++kt) {
#pragma unroll
    for (int i = 0; i < 2; ++i) {
      const int c8 = (tid + (i << 9)) << 3;
      *(u16x8*)&sK[c8] = kreg[i];
      *(u16x8*)&sV[c8] = vreg[i];
    }
    __syncthreads();
    if (kt + 1 < 32) PREF(kt + 1);

    f32x4 sc[4] = {};
    __builtin_amdgcn_s_setprio(1);
#pragma unroll
    for (int ti = 0; ti < 4; ++ti) {
#pragma unroll
      for (int kk = 0; kk < 4; ++kk) {
        const int row = (ti << 4) + (lane & 15);
        int bo = (row << 8) + (kk << 6) + ((lane >> 4) << 4);
        bo ^= (row & 7) << 4;
        bf16x8 kf = *(const bf16x8*)((const char*)sK + bo);
        sc[ti] = __builtin_amdgcn_mfma_f32_16x16x32_bf16(kf, qf[kk], sc[ti], 0, 0, 0);
      }
    }
    __builtin_amdgcn_s_setprio(0);

    float pv[16];
    float mx = -3e38f;
#pragma unroll
    for (int ti = 0; ti < 4; ++ti)
#pragma unroll
      for (int r = 0; r < 4; ++r) {
        float x = sc[ti][r] * 0.08838834764831845f;
        pv[(ti << 2) + r] = x;
        mx = fmaxf(mx, x);
      }
    mx = fmaxf(mx, __shfl_xor(mx, 16));
    mx = fmaxf(mx, __shfl_xor(mx, 32));

    float corr = 1.f;
    if (!__all(mx - mrun <= 8.f)) {
      const float mnew = fmaxf(mrun, mx);
      corr = __expf(mrun - mnew);
      mrun = mnew;
      float fr[4];
#pragma unroll
      for (int r = 0; r < 4; ++r) fr[r] = __shfl(corr, ((lane >> 4) << 2) + r);
#pragma unroll
      for (int di = 0; di < 8; ++di)
#pragma unroll
        for (int r = 0; r < 4; ++r) oacc[di][r] *= fr[r];
    }
    float psum = 0.f;
#pragma unroll
    for (int i2 = 0; i2 < 16; ++i2) {
      float e = __expf(pv[i2] - mrun);
      pv[i2] = e;
      psum += e;
    }
    psum += __shfl_xor(psum, 16);
    psum += __shfl_xor(psum, 32);
    lrun = lrun * corr + psum;

    unsigned short* prow = &sP[wid][(lane & 15) * 72];
#pragma unroll
    for (int ti = 0; ti < 4; ++ti) {
      u16x4 w4;
      w4.x = f2bf(pv[(ti << 2) + 0]);
      w4.y = f2bf(pv[(ti << 2) + 1]);
      w4.z = f2bf(pv[(ti << 2) + 2]);
      w4.w = f2bf(pv[(ti << 2) + 3]);
      *(u16x4*)&prow[(ti << 4) + ((lane >> 4) << 2)] = w4;
    }

    __builtin_amdgcn_s_setprio(1);
#pragma unroll
    for (int di = 0; di < 8; ++di) {
#pragma unroll
      for (int ks = 0; ks < 2; ++ks) {
        bf16x8 pf = *(const bf16x8*)((const char*)&sP[wid][0] +
                                     (lane & 15) * 144 + (ks << 6) + ((lane >> 4) << 4));
        const int dr = (di << 4) + (lane & 15);
        int bo = (dr << 7) + (ks << 6) + ((lane >> 4) << 4);
        bo ^= (dr & 7) << 4;
        bf16x8 vf = *(const bf16x8*)((const char*)sV + bo);
        oacc[di] = __builtin_amdgcn_mfma_f32_16x16x32_bf16(pf, vf, oacc[di], 0, 0, 0);
      }
    }
    __builtin_amdgcn_s_setprio(0);
    __syncthreads();
  }

  float il[4];
#pragma unroll
  for (int r = 0; r < 4; ++r) il[r] = 1.f / __shfl(lrun, ((lane >> 4) << 2) + r);
  const size_t obase = ((size_t)(b * 2048 + q0)) * 2048 + h * 128;
#pragma unroll
  for (int di = 0; di < 8; ++di)
#pragma unroll
    for (int r = 0; r < 4; ++r) {
      const size_t o = obase + (size_t)(((lane >> 4) << 2) + r) * 2048 + (di << 4) + (lane & 15);
      O[o] = f2bf(oacc[di][r] * il[r]);
    }
}

// ---------------------------------------------------------------- launch

extern "C" void kernel_launch(void* const* d_in, const int* in_sizes, int n_in,
                              void* d_out, int out_size, void* d_ws, size_t ws_size,
                              hipStream_t stream) {
  (void)in_sizes; (void)n_in; (void)out_size; (void)ws_size;
  const float* hidden = (const float*)d_in[0];
  const float* ln1_g = (const float*)d_in[1];
  const float* ln1_b = (const float*)d_in[2];
  const float* w_qkv = (const float*)d_in[3];
  const float* b_qkv = (const float*)d_in[4];
  const float* apv = (const float*)d_in[5];
  const float* apg = (const float*)d_in[6];
  const float* apb = (const float*)d_in[7];
  // d_in[8] emotion_bias: softmax-invariant -> dropped (exact)
  const float* ln2_g = (const float*)d_in[9];
  const float* ln2_b = (const float*)d_in[10];
  const float* w_fc = (const float*)d_in[11];
  const float* b_fc = (const float*)d_in[12];
  const float* mpv = (const float*)d_in[13];
  const float* mpg = (const float*)d_in[14];
  const float* mpb = (const float*)d_in[15];

  char* w = (char*)d_ws;
  const size_t MBs = 1ull << 20;
  unsigned short* xln = (unsigned short*)(w + 0);
  float* hidden2 = (float*)(w + 0);
  unsigned short* vtbuf = (unsigned short*)(w + 32 * MBs);
  unsigned short* hbuf = (unsigned short*)(w + 32 * MBs);
  unsigned short* qkv = (unsigned short*)(w + 96 * MBs);
  unsigned short* wfc_bf = (unsigned short*)(w + 96 * MBs);
  unsigned short* partH = (unsigned short*)(w + 96 * MBs);   // 4x16MB bf16 partials
  unsigned short* xln2 = (unsigned short*)(w + 128 * MBs);
  unsigned short* attn_out = (unsigned short*)(w + 144 * MBs);
  unsigned short* wqkv_bf = (unsigned short*)(w + 160 * MBs);
  unsigned short* w2_bf = (unsigned short*)(w + 160 * MBs);
  unsigned short* wproj_bf = (unsigned short*)(w + 192 * MBs);
  float* s_attn = (float*)(w + 200 * MBs);
  float* s_mlp = (float*)(w + 200 * MBs + 32768);
  float* part_attn = (float*)(w + 201 * MBs);
  float* part_mlp = (float*)(w + 202 * MBs);

  hipFuncSetAttribute((const void*)g1_qkv256, hipFuncAttributeMaxDynamicSharedMemorySize, 65536);
  hipFuncSetAttribute((const void*)g3_fc256r4, hipFuncAttributeMaxDynamicSharedMemorySize, 131072);
  hipFuncSetAttribute((const void*)g4_splitk256, hipFuncAttributeMaxDynamicSharedMemorySize, 65536);

  // weight prep
  cast_k<<<2048, 256, 0, stream>>>(w_qkv, wqkv_bf, (6144 * 2048) / 4);
  colnorm1_k<<<dim3(4, 32), 256, 0, stream>>>(apv, part_attn, 2048);
  colnorm2_k<<<8, 256, 0, stream>>>(part_attn, apg, s_attn, 2048, 32);
  scale_cast_k<<<2048, 256, 0, stream>>>(apv, s_attn, wproj_bf, 2048, (2048 * 2048) / 4);
  colnorm1_k<<<dim3(16, 32), 256, 0, stream>>>(mpv, part_mlp, 8192);
  colnorm2_k<<<32, 256, 0, stream>>>(part_mlp, mpg, s_mlp, 8192, 32);

  // LN1 -> xln (bf16)
  ln_k<<<4096, 256, 0, stream>>>(hidden, ln1_g, ln1_b, xln);

  // GEMM1 (256^2 2-phase): qkv = xln @ w_qkv^T + b
  GemmP p1 = {xln, wqkv_bf, b_qkv, nullptr, nullptr, qkv, 4096, 6144, 2048};
  g1_qkv256<<<384, 512, 65536, stream>>>(p1);

  // V slice of qkv -> V^T
  vtrans_k<<<1024, 256, 0, stream>>>(qkv, vtbuf);

  // attention (QBLK=128, 8 waves) -> attn_out
  attn_k<<<512, 512, 0, stream>>>(qkv, vtbuf, attn_out);

  // weight casts for MLP
  cast_k<<<2048, 256, 0, stream>>>(w_fc, wfc_bf, (8192 * 2048) / 4);
  scale_cast_k<<<4096, 256, 0, stream>>>(mpv, s_mlp, w2_bf, 8192, (2048 * 8192) / 4);

  // GEMM2 (128^2): hidden2 = attn_out @ w_proj^T + b + hidden
  GemmP p2 = {attn_out, wproj_bf, apb, hidden, hidden2, nullptr, 4096, 2048, 2048};
  g2_proj128<<<512, 256, 0, stream>>>(p2);

  // LN2 -> xln2
  ln_k<<<4096, 256, 0, stream>>>(hidden2, ln2_g, ln2_b, xln2);

  // GEMM3 (ring-4 counted-vmcnt) -- A/B vs g4's 2-phase (identical block work)
  GemmP p3 = {xln2, wfc_bf, b_fc, nullptr, nullptr, hbuf, 4096, 8192, 2048};
  g3_fc256r4<<<512, 512, 131072, stream>>>(p3);

  // GEMM4 (256^2 2-phase split-K4) -> fused reduce
  GemmP p4 = {hbuf, w2_bf, mpb, nullptr, nullptr, partH, 4096, 2048, 8192};
  g4_splitk256<<<512, 512, 65536, stream>>>(p4);
  g4red_k<<<2048, 256, 0, stream>>>(partH, mpb, hidden2, (float*)d_out,
                                    (4096 * 2048) / 4);
}

// Round 12
// 750.519 us; speedup vs baseline: 1.0175x; 1.0175x over previous
//
#include <hip/hip_runtime.h>
#include <hip/hip_bf16.h>

#define DEVI __device__ __forceinline__

typedef __attribute__((ext_vector_type(8))) __bf16 bf16x8;
typedef __attribute__((ext_vector_type(4))) float f32x4;
typedef __attribute__((ext_vector_type(4))) unsigned short u16x4;
typedef __attribute__((ext_vector_type(8))) unsigned short u16x8;

DEVI unsigned short f2bf(float f) {
  unsigned int u = __float_as_uint(f);
  u += 0x7FFFu + ((u >> 16) & 1u);   // RNE
  return (unsigned short)(u >> 16);
}
DEVI float bf2f(unsigned short u) {
  return __uint_as_float(((unsigned int)u) << 16);
}

#define GLD16(g, l) __builtin_amdgcn_global_load_lds(                      \
    (const __attribute__((address_space(1))) void*)(g),                    \
    (__attribute__((address_space(3))) void*)(l), 16, 0, 0)

// ---------------------------------------------------------------- helpers

__global__ __launch_bounds__(256) void cast_k(const float* __restrict__ in,
                                              unsigned short* __restrict__ out,
                                              int n4) {
  for (int i = blockIdx.x * 256 + threadIdx.x; i < n4; i += gridDim.x * 256) {
    f32x4 v = ((const f32x4*)in)[i];
    u16x4 o;
    o.x = f2bf(v.x); o.y = f2bf(v.y); o.z = f2bf(v.z); o.w = f2bf(v.w);
    ((u16x4*)out)[i] = o;
  }
}

// colnorm phase 1: partial column sumsq over a 64-row x 512-col tile.
__global__ __launch_bounds__(256) void colnorm1_k(const float* __restrict__ v,
                                                  float* __restrict__ part,
                                                  int cols) {
  const int tid = threadIdx.x;
  const int g = tid & 127;
  const int s = tid >> 7;
  const int c0 = blockIdx.x * 512;
  const int r0 = blockIdx.y * 64 + s * 32;
  const float* base = v + (size_t)r0 * cols + c0 + g * 4;
  f32x4 acc = {};
#pragma unroll 4
  for (int i = 0; i < 32; ++i) {
    f32x4 x = *(const f32x4*)(base + (size_t)i * cols);
    acc.x += x.x * x.x; acc.y += x.y * x.y;
    acc.z += x.z * x.z; acc.w += x.w * x.w;
  }
  __shared__ f32x4 red[256];
  red[tid] = acc;
  __syncthreads();
  if (s == 0) {
    f32x4 a = red[tid], b = red[tid + 128];
    f32x4 o;
    o.x = a.x + b.x; o.y = a.y + b.y; o.z = a.z + b.z; o.w = a.w + b.w;
    *(f32x4*)(part + (size_t)blockIdx.y * cols + c0 + g * 4) = o;
  }
}

// colnorm phase 2: s[c] = g[c] * rsqrt(sum_rc part[rc][c])
__global__ __launch_bounds__(256) void colnorm2_k(const float* __restrict__ part,
                                                  const float* __restrict__ g,
                                                  float* __restrict__ s,
                                                  int cols, int nrc) {
  const int c = blockIdx.x * 256 + threadIdx.x;
  float acc = 0.f;
  for (int i = 0; i < nrc; ++i) acc += part[(size_t)i * cols + c];
  s[c] = g[c] * rsqrtf(acc);
}

__global__ __launch_bounds__(256) void scale_cast_k(const float* __restrict__ in,
                                                    const float* __restrict__ s,
                                                    unsigned short* __restrict__ out,
                                                    int cols, int n4) {
  const int cmask4 = (cols >> 2) - 1;
  for (int i = blockIdx.x * 256 + threadIdx.x; i < n4; i += gridDim.x * 256) {
    f32x4 v = ((const f32x4*)in)[i];
    f32x4 sv = ((const f32x4*)s)[i & cmask4];
    u16x4 o;
    o.x = f2bf(v.x * sv.x); o.y = f2bf(v.y * sv.y);
    o.z = f2bf(v.z * sv.z); o.w = f2bf(v.w * sv.w);
    ((u16x4*)out)[i] = o;
  }
}

// LayerNorm: one block per row of 2048 fp32, out bf16
__global__ __launch_bounds__(256) void ln_k(const float* __restrict__ x,
                                            const float* __restrict__ g,
                                            const float* __restrict__ b,
                                            unsigned short* __restrict__ out) {
  const int tid = threadIdx.x, lane = tid & 63, wid = tid >> 6;
  const int row = blockIdx.x;
  const float* xr = x + (size_t)row * 2048;
  f32x4 a0 = ((const f32x4*)xr)[tid];
  f32x4 a1 = ((const f32x4*)xr)[tid + 256];
  float s = a0.x + a0.y + a0.z + a0.w + a1.x + a1.y + a1.z + a1.w;
  float ss = a0.x * a0.x + a0.y * a0.y + a0.z * a0.z + a0.w * a0.w +
             a1.x * a1.x + a1.y * a1.y + a1.z * a1.z + a1.w * a1.w;
#pragma unroll
  for (int m = 1; m < 64; m <<= 1) {
    s += __shfl_xor(s, m);
    ss += __shfl_xor(ss, m);
  }
  __shared__ float red[8];
  if (lane == 0) { red[wid] = s; red[4 + wid] = ss; }
  __syncthreads();
  s = red[0] + red[1] + red[2] + red[3];
  ss = red[4] + red[5] + red[6] + red[7];
  const float mu = s * (1.f / 2048.f);
  const float var = ss * (1.f / 2048.f) - mu * mu;
  const float rs = rsqrtf(var + 1e-5f);
  f32x4 g0 = ((const f32x4*)g)[tid], g1 = ((const f32x4*)g)[tid + 256];
  f32x4 b0 = ((const f32x4*)b)[tid], b1 = ((const f32x4*)b)[tid + 256];
  u16x4 o0, o1;
  o0.x = f2bf((a0.x - mu) * rs * g0.x + b0.x);
  o0.y = f2bf((a0.y - mu) * rs * g0.y + b0.y);
  o0.z = f2bf((a0.z - mu) * rs * g0.z + b0.z);
  o0.w = f2bf((a0.w - mu) * rs * g0.w + b0.w);
  o1.x = f2bf((a1.x - mu) * rs * g1.x + b1.x);
  o1.y = f2bf((a1.y - mu) * rs * g1.y + b1.y);
  o1.z = f2bf((a1.z - mu) * rs * g1.z + b1.z);
  o1.w = f2bf((a1.w - mu) * rs * g1.w + b1.w);
  unsigned short* orow = out + (size_t)row * 2048;
  *(u16x4*)(orow + 4 * tid) = o0;
  *(u16x4*)(orow + 1024 + 4 * tid) = o1;
}

// V transpose: V slice of qkv [4096][6144] -> vt [32][128][2048]
__global__ __launch_bounds__(256) void vtrans_k(const unsigned short* __restrict__ qkv,
                                                unsigned short* __restrict__ vt) {
  __shared__ unsigned short t[64][134];
  const int tid = threadIdx.x;
  const int bh = blockIdx.x >> 5, st = blockIdx.x & 31;
  const int b = bh >> 4, h = bh & 15;
  const unsigned short* vb = qkv + (size_t)(b * 2048 + st * 64) * 6144 + 4096 + h * 128;
#pragma unroll
  for (int i = 0; i < 4; ++i) {
    int f = tid + (i << 8);
    int row = f >> 4, c8 = f & 15;
    u16x8 x = *(const u16x8*)(vb + (size_t)row * 6144 + c8 * 8);
#pragma unroll
    for (int j = 0; j < 4; ++j) {
      unsigned int pk = ((unsigned int)x[2 * j + 1] << 16) | x[2 * j];
      *(unsigned int*)&t[row][c8 * 8 + 2 * j] = pk;
    }
  }
  __syncthreads();
  const int lane = tid & 63, wid = tid >> 6;
  unsigned short* ob = vt + ((size_t)bh << 18) + (st << 6);
#pragma unroll
  for (int j = 0; j < 32; ++j) {
    int d = (wid << 5) + j;
    ob[((size_t)d << 11) + lane] = t[lane][d];
  }
}

// split-K4 reduce: out = sum(bf16 parts 0..3) + bias + res (fp32)
__global__ __launch_bounds__(256) void g4red_k(const unsigned short* __restrict__ parts,
                                               const float* __restrict__ bias,
                                               const float* __restrict__ res,
                                               float* __restrict__ out, int n4) {
  const size_t PS = (size_t)4096 * 2048;
  for (int i = blockIdx.x * 256 + threadIdx.x; i < n4; i += gridDim.x * 256) {
    u16x4 a = ((const u16x4*)(parts))[i];
    u16x4 b = ((const u16x4*)(parts + PS))[i];
    u16x4 c = ((const u16x4*)(parts + 2 * PS))[i];
    u16x4 d = ((const u16x4*)(parts + 3 * PS))[i];
    f32x4 r = ((const f32x4*)res)[i];
    f32x4 bb = ((const f32x4*)bias)[i & 511];
    f32x4 o;
    o.x = bf2f(a.x) + bf2f(b.x) + bf2f(c.x) + bf2f(d.x) + r.x + bb.x;
    o.y = bf2f(a.y) + bf2f(b.y) + bf2f(c.y) + bf2f(d.y) + r.y + bb.y;
    o.z = bf2f(a.z) + bf2f(b.z) + bf2f(c.z) + bf2f(d.z) + r.z + bb.z;
    o.w = bf2f(a.w) + bf2f(b.w) + bf2f(c.w) + bf2f(d.w) + r.w + bb.w;
    ((f32x4*)out)[i] = o;
  }
}

// ---------------------------------------------------------------- GEMM params
struct GemmP {
  const unsigned short* A;
  const unsigned short* B;
  const float* bias;
  const float* res;
  float* outF;
  unsigned short* outH;
  int M, N, K;
};

// ---------------------------------------------------------------- 128^2 GEMM (2-phase)
// +bias +res -> fp32
DEVI void gemm128_body(const GemmP& p, int m0, int n0, int k0, int nk) {
  const int tid = threadIdx.x, lane = tid & 63, wid = tid >> 6;
  const int K = p.K;
  const int wr = wid >> 1, wc = wid & 1;

  __shared__ __align__(16) unsigned short sA[2][4096];
  __shared__ __align__(16) unsigned short sB[2][4096];

  const int c0 = tid, c1 = tid + 256;
  const unsigned short* gA0 = p.A + (size_t)(m0 + (c0 >> 2)) * K + k0 + ((c0 & 3) << 3);
  const unsigned short* gA1 = p.A + (size_t)(m0 + (c1 >> 2)) * K + k0 + ((c1 & 3) << 3);
  const unsigned short* gB0 = p.B + (size_t)(n0 + (c0 >> 2)) * K + k0 + ((c0 & 3) << 3);
  const unsigned short* gB1 = p.B + (size_t)(n0 + (c1 >> 2)) * K + k0 + ((c1 & 3) << 3);
  const int l0 = wid << 9, l1 = (wid << 9) + 2048;

  f32x4 acc[4][4] = {};
  const int arow = (wr << 6) + (lane & 15);
  const int brow = (wc << 6) + (lane & 15);
  const int koff = (lane >> 4) << 3;

#define STAGE128(bufi, t) do { int ko = (t) << 5;       \
    GLD16(gA0 + ko, &sA[bufi][l0]);                     \
    GLD16(gA1 + ko, &sA[bufi][l1]);                     \
    GLD16(gB0 + ko, &sB[bufi][l0]);                     \
    GLD16(gB1 + ko, &sB[bufi][l1]); } while (0)

  STAGE128(0, 0);
  __syncthreads();
  int cur = 0;
  for (int t = 0; t < nk; ++t) {
    if (t + 1 < nk) STAGE128(cur ^ 1, t + 1);
    bf16x8 af[4], bfr[4];
#pragma unroll
    for (int i = 0; i < 4; ++i)
      af[i] = *(const bf16x8*)&sA[cur][(arow + (i << 4)) * 32 + koff];
#pragma unroll
    for (int i = 0; i < 4; ++i)
      bfr[i] = *(const bf16x8*)&sB[cur][(brow + (i << 4)) * 32 + koff];
#pragma unroll
    for (int i = 0; i < 4; ++i)
#pragma unroll
      for (int j = 0; j < 4; ++j)
        acc[i][j] = __builtin_amdgcn_mfma_f32_16x16x32_bf16(af[i], bfr[j], acc[i][j], 0, 0, 0);
    __syncthreads();
    cur ^= 1;
  }
#undef STAGE128

  const int rbase = m0 + (wr << 6) + ((lane >> 4) << 2);
  const int cbase = n0 + (wc << 6) + (lane & 15);
#pragma unroll
  for (int mi = 0; mi < 4; ++mi) {
#pragma unroll
    for (int ni = 0; ni < 4; ++ni) {
      const int col = cbase + (ni << 4);
#pragma unroll
      for (int r = 0; r < 4; ++r) {
        const int row = rbase + (mi << 4) + r;
        const size_t o = (size_t)row * p.N + col;
        p.outF[o] = acc[mi][ni][r] + p.bias[col] + p.res[o];
      }
    }
  }
}

// G2: M=4096,N=2048 -> nbm=32,nbn=16. Region/XCD = 8x8.
__global__ __launch_bounds__(256) void g2_proj128(GemmP p) {
  const int x = blockIdx.x & 7, i = blockIdx.x >> 3;  // i in [0,64)
  const int bm = (x >> 1) * 8 + (i >> 3);
  const int bn = (x & 1) * 8 + (i & 7);
  gemm128_body(p, bm << 7, bn << 7, 0, p.K >> 5);
}

// ---------------------------------------------------------------- 256^2 tile common
DEVI void setup256(const GemmP& p, int m0, int n0, int k0,
                   const unsigned short*& gsA0, const unsigned short*& gsA1,
                   const unsigned short*& gsB0, const unsigned short*& gsB1) {
  const int tid = threadIdx.x;
  int r_[2], c_[2];
#pragma unroll
  for (int j = 0; j < 2; ++j) {
    int d = tid * 16 + j * 8192;
    int w = (d & 1023) ^ (((d >> 9) & 1) << 5);   // st_16x32 involution
    r_[j] = ((d >> 10) << 4) + (w >> 6);
    c_[j] = (w & 63) >> 1;
  }
  gsA0 = p.A + (size_t)(m0 + r_[0]) * p.K + k0 + c_[0];
  gsA1 = p.A + (size_t)(m0 + r_[1]) * p.K + k0 + c_[1];
  gsB0 = p.B + (size_t)(n0 + r_[0]) * p.K + k0 + c_[0];
  gsB1 = p.B + (size_t)(n0 + r_[1]) * p.K + k0 + c_[1];
}

// epilogue: EPI 0 = +bias -> bf16   2 = +bias fast-GELU -> bf16   5 = raw -> bf16
template <int EPI>
DEVI void epi256(const GemmP& p, f32x4 (&acc)[8][4], int m0, int n0,
                 unsigned short* outH) {
  const int lane = threadIdx.x & 63, wid = threadIdx.x >> 6;
  const int wr = wid >> 2, wc = wid & 3;
  const int lr = lane & 15, lk = lane >> 4;
  const int rbase = m0 + wr * 128 + (lk << 2);
  const int cbase = n0 + wc * 64 + lr;
#pragma unroll
  for (int m = 0; m < 8; ++m) {
#pragma unroll
    for (int n = 0; n < 4; ++n) {
      const int col = cbase + (n << 4);
      const float bb = (EPI == 5) ? 0.f : p.bias[col];
#pragma unroll
      for (int r = 0; r < 4; ++r) {
        const int row = rbase + (m << 4) + r;
        float v = acc[m][n][r] + bb;
        if constexpr (EPI == 2) {
          float y = 0.7978845608028654f * (v + 0.044715f * v * v * v);
          float u = __expf(2.f * y);
          v = (y > 40.f) ? v : v * (u / (u + 1.f));
        }
        outH[(size_t)row * p.N + col] = f2bf(v);
      }
    }
  }
}

// ---------------------------------------------------------------- 256^2 2-phase
template <int EPI>
DEVI void gemm2p_body(const GemmP& p, unsigned short* lds_raw, int m0, int n0,
                      int k0, int nk, unsigned short* outH) {
  const int tid = threadIdx.x, lane = tid & 63, wid = tid >> 6;
  const int wr = wid >> 2, wc = wid & 3;
  const int lr = lane & 15, lk = lane >> 4;
  const int fb = (lr * 64 + lk * 16) ^ ((lr & 8) << 2);

  const unsigned short *gsA0, *gsA1, *gsB0, *gsB1;
  setup256(p, m0, n0, k0, gsA0, gsA1, gsB0, gsB1);

#define STG2(b, kt) do { unsigned short* _d = lds_raw + ((b) << 14);     \
    GLD16(gsA0 + ((size_t)(kt) << 5), _d + (tid << 3));                  \
    GLD16(gsA1 + ((size_t)(kt) << 5), _d + 4096 + (tid << 3));           \
    GLD16(gsB0 + ((size_t)(kt) << 5), _d + 8192 + (tid << 3));           \
    GLD16(gsB1 + ((size_t)(kt) << 5), _d + 12288 + (tid << 3)); } while (0)

  f32x4 acc[8][4] = {};
  STG2(0, 0);
  __syncthreads();
  int cur = 0;
  for (int t = 0; t < nk; ++t) {
    if (t + 1 < nk) STG2(cur ^ 1, t + 1);
    const char* tA = (const char*)(lds_raw + (cur << 14));
    const char* tB = tA + 16384;
    bf16x8 a_[8], b_[4];
#pragma unroll
    for (int n = 0; n < 4; ++n)
      b_[n] = *(const bf16x8*)(tB + (((wc << 2) + n) << 10) + fb);
#pragma unroll
    for (int m = 0; m < 8; ++m)
      a_[m] = *(const bf16x8*)(tA + (((wr << 3) + m) << 10) + fb);
#pragma unroll
    for (int m = 0; m < 8; ++m)
#pragma unroll
      for (int n = 0; n < 4; ++n)
        acc[m][n] = __builtin_amdgcn_mfma_f32_16x16x32_bf16(a_[m], b_[n], acc[m][n], 0, 0, 0);
    __syncthreads();
    cur ^= 1;
  }
#undef STG2
  epi256<EPI>(p, acc, m0, n0, outH);
}

// ---------------------------------------------------------------- 256^2 ring-4
// counted-vmcnt pipeline, UNPINNED: no explicit lgkmcnt/sched_barrier — the
// compiler emits fine-grained lgkmcnt interleaved with MFMAs (m97 behavior).
// Safety: per-wave counted vmcnt + s_barrier gives cross-wave tile arrival;
// compiler drains ds_reads into regs before last MFMA (pre-barrier); the empty
// asm "memory" fence after each barrier stops hoisting next-step LDS reads.
template <int EPI>
DEVI void gemmr4_body(const GemmP& p, unsigned short* lds_raw, int m0, int n0,
                      int k0, int nk, unsigned short* outH) {
  const int tid = threadIdx.x, lane = tid & 63, wid = tid >> 6;
  const int wr = wid >> 2, wc = wid & 3;
  const int lr = lane & 15, lk = lane >> 4;
  const int fb = (lr * 64 + lk * 16) ^ ((lr & 8) << 2);

  const unsigned short *gsA0, *gsA1, *gsB0, *gsB1;
  setup256(p, m0, n0, k0, gsA0, gsA1, gsB0, gsB1);

#define STGR(bufi, kt) do { unsigned short* _d = lds_raw + ((bufi) << 14); \
    GLD16(gsA0 + ((size_t)(kt) << 5), _d + (tid << 3));                    \
    GLD16(gsA1 + ((size_t)(kt) << 5), _d + 4096 + (tid << 3));             \
    GLD16(gsB0 + ((size_t)(kt) << 5), _d + 8192 + (tid << 3));             \
    GLD16(gsB1 + ((size_t)(kt) << 5), _d + 12288 + (tid << 3)); } while (0)

  f32x4 acc[8][4] = {};
  STGR(0, 0);
  STGR(1, 1);
  STGR(2, 2);
  asm volatile("s_waitcnt vmcnt(8)" ::: "memory");   // tile 0 arrived
  __builtin_amdgcn_s_barrier();
  asm volatile("" ::: "memory");

  for (int t = 0; t < nk; ++t) {
    const char* tA = (const char*)(lds_raw + ((t & 3) << 14));
    const char* tB = tA + 16384;
    bf16x8 a_[8], b_[4];
#pragma unroll
    for (int n = 0; n < 4; ++n)
      b_[n] = *(const bf16x8*)(tB + (((wc << 2) + n) << 10) + fb);
#pragma unroll
    for (int m = 0; m < 8; ++m)
      a_[m] = *(const bf16x8*)(tA + (((wr << 3) + m) << 10) + fb);
    if (t + 3 < nk) STGR((t + 3) & 3, t + 3);
    __builtin_amdgcn_s_setprio(1);
#pragma unroll
    for (int m = 0; m < 8; ++m)
#pragma unroll
      for (int n = 0; n < 4; ++n)
        acc[m][n] = __builtin_amdgcn_mfma_f32_16x16x32_bf16(a_[m], b_[n], acc[m][n], 0, 0, 0);
    __builtin_amdgcn_s_setprio(0);
    if (t + 3 < nk)      asm volatile("s_waitcnt vmcnt(8)" ::: "memory");
    else if (t + 2 < nk) asm volatile("s_waitcnt vmcnt(4)" ::: "memory");
    else if (t + 1 < nk) asm volatile("s_waitcnt vmcnt(0)" ::: "memory");
    __builtin_amdgcn_s_barrier();
    asm volatile("" ::: "memory");
  }
#undef STGR
  epi256<EPI>(p, acc, m0, n0, outH);
}

// G1 (256^2 2-phase): M=4096,N=6144 -> nbm=16,nbn=24; region 8x6 per XCD.
__global__ __launch_bounds__(512, 2) void g1_qkv256(GemmP p) {
  extern __shared__ unsigned short lds_raw[];
  const int x = blockIdx.x & 7, i = blockIdx.x >> 3;   // i in [0,48)
  const int bm = (x & 1) * 8 + (i & 7);
  const int bn = (x >> 1) * 6 + (i >> 3);
  gemm2p_body<0>(p, lds_raw, bm << 8, bn << 8, 0, p.K >> 5, p.outH);
}
// G3 ring-4 unpinned (counted vmcnt, 128KB LDS, 1 block/CU).
__global__ __launch_bounds__(512, 1) void g3_fc256r4(GemmP p) {
  extern __shared__ unsigned short lds_raw[];
  const int x = blockIdx.x & 7, i = blockIdx.x >> 3;   // i in [0,64)
  const int bm = (x & 1) * 8 + (i & 7);
  const int bn = (x >> 1) * 8 + (i >> 3);
  gemmr4_body<2>(p, lds_raw, bm << 8, bn << 8, 0, p.K >> 5, p.outH);
}
// G4 ring-4 unpinned, split-K4: nbm=16,nbn=8, ks in [0,4).
__global__ __launch_bounds__(512, 1) void g4_splitk256r4(GemmP p) {
  extern __shared__ unsigned short lds_raw[];
  const int x = blockIdx.x & 7, i = blockIdx.x >> 3;   // i in [0,64)
  const int ks = x & 3;
  const int bm = (x >> 2) * 8 + (i >> 3);
  const int bn = i & 7;
  unsigned short* outH = p.outH + (size_t)ks * 4096 * 2048;
  gemmr4_body<5>(p, lds_raw, bm << 8, bn << 8, ks << 11, 64, outH);
}

// ---------------------------------------------------------------- attention
// QBLK=128 (8 waves). Q,K from unified qkv [4096][6144]; V^T [32][128][2048].
__global__ __launch_bounds__(512) void attn_k(const unsigned short* __restrict__ qkv,
                                              const unsigned short* __restrict__ Vt,
                                              unsigned short* __restrict__ O) {
  const int tid = threadIdx.x, lane = tid & 63, wid = tid >> 6;
  const int bid = blockIdx.x;                 // grid = 512
  const int pos = bid >> 3;                   // [0,64)
  const int bh = (bid & 7) * 4 + (pos >> 4);
  const int qt = pos & 15;
  const int q0 = qt * 128 + wid * 16;
  const int b = bh >> 4, h = bh & 15;

  __shared__ __align__(16) unsigned short sK[64 * 128];
  __shared__ __align__(16) unsigned short sV[128 * 64];
  __shared__ __align__(16) unsigned short sP[8][16 * 72];

  const unsigned short* Qb = qkv + (size_t)(b * 2048) * 6144 + h * 128;
  const unsigned short* Kb = qkv + (size_t)(b * 2048) * 6144 + 2048 + h * 128;
  const unsigned short* Vb = Vt + ((size_t)bh << 18);

  bf16x8 qf[4];
  {
    const unsigned short* qp = Qb + (size_t)(q0 + (lane & 15)) * 6144 + ((lane >> 4) << 3);
#pragma unroll
    for (int kk = 0; kk < 4; ++kk) qf[kk] = *(const bf16x8*)(qp + kk * 32);
  }

  int koffs[2], voffs[2];
#pragma unroll
  for (int i = 0; i < 2; ++i) {
    const int c = tid + (i << 9);
    const int kv = c >> 4, jj = c & 15;
    const int js = (jj & 8) | ((jj ^ kv) & 7);
    koffs[i] = kv * 6144 + (js << 3);
    const int d = c >> 3, j2 = c & 7;
    const int js2 = j2 ^ (d & 7);
    voffs[i] = d * 2048 + (js2 << 3);
  }
  u16x8 kreg[2], vreg[2];
  auto PREF = [&](int kt) {
    const int kv0 = kt << 6;
    const unsigned short* kb = Kb + (size_t)kv0 * 6144;
#pragma unroll
    for (int i = 0; i < 2; ++i) {
      kreg[i] = *(const u16x8*)(kb + koffs[i]);
      vreg[i] = *(const u16x8*)(Vb + kv0 + voffs[i]);
    }
  };

  f32x4 oacc[8] = {};
  float mrun = -3e38f, lrun = 0.f;
  PREF(0);

  for (int kt = 0; kt < 32; ++kt) {
#pragma unroll
    for (int i = 0; i < 2; ++i) {
      const int c8 = (tid + (i << 9)) << 3;
      *(u16x8*)&sK[c8] = kreg[i];
      *(u16x8*)&sV[c8] = vreg[i];
    }
    __syncthreads();
    if (kt + 1 < 32) PREF(kt + 1);

    f32x4 sc[4] = {};
    __builtin_amdgcn_s_setprio(1);
#pragma unroll
    for (int ti = 0; ti < 4; ++ti) {
#pragma unroll
      for (int kk = 0; kk < 4; ++kk) {
        const int row = (ti << 4) + (lane & 15);
        int bo = (row << 8) + (kk << 6) + ((lane >> 4) << 4);
        bo ^= (row & 7) << 4;
        bf16x8 kf = *(const bf16x8*)((const char*)sK + bo);
        sc[ti] = __builtin_amdgcn_mfma_f32_16x16x32_bf16(kf, qf[kk], sc[ti], 0, 0, 0);
      }
    }
    __builtin_amdgcn_s_setprio(0);

    float pv[16];
    float mx = -3e38f;
#pragma unroll
    for (int ti = 0; ti < 4; ++ti)
#pragma unroll
      for (int r = 0; r < 4; ++r) {
        float x = sc[ti][r] * 0.08838834764831845f;
        pv[(ti << 2) + r] = x;
        mx = fmaxf(mx, x);
      }
    mx = fmaxf(mx, __shfl_xor(mx, 16));
    mx = fmaxf(mx, __shfl_xor(mx, 32));

    float corr = 1.f;
    if (!__all(mx - mrun <= 8.f)) {
      const float mnew = fmaxf(mrun, mx);
      corr = __expf(mrun - mnew);
      mrun = mnew;
      float fr[4];
#pragma unroll
      for (int r = 0; r < 4; ++r) fr[r] = __shfl(corr, ((lane >> 4) << 2) + r);
#pragma unroll
      for (int di = 0; di < 8; ++di)
#pragma unroll
        for (int r = 0; r < 4; ++r) oacc[di][r] *= fr[r];
    }
    float psum = 0.f;
#pragma unroll
    for (int i2 = 0; i2 < 16; ++i2) {
      float e = __expf(pv[i2] - mrun);
      pv[i2] = e;
      psum += e;
    }
    psum += __shfl_xor(psum, 16);
    psum += __shfl_xor(psum, 32);
    lrun = lrun * corr + psum;

    unsigned short* prow = &sP[wid][(lane & 15) * 72];
#pragma unroll
    for (int ti = 0; ti < 4; ++ti) {
      u16x4 w4;
      w4.x = f2bf(pv[(ti << 2) + 0]);
      w4.y = f2bf(pv[(ti << 2) + 1]);
      w4.z = f2bf(pv[(ti << 2) + 2]);
      w4.w = f2bf(pv[(ti << 2) + 3]);
      *(u16x4*)&prow[(ti << 4) + ((lane >> 4) << 2)] = w4;
    }

    __builtin_amdgcn_s_setprio(1);
#pragma unroll
    for (int di = 0; di < 8; ++di) {
#pragma unroll
      for (int ks = 0; ks < 2; ++ks) {
        bf16x8 pf = *(const bf16x8*)((const char*)&sP[wid][0] +
                                     (lane & 15) * 144 + (ks << 6) + ((lane >> 4) << 4));
        const int dr = (di << 4) + (lane & 15);
        int bo = (dr << 7) + (ks << 6) + ((lane >> 4) << 4);
        bo ^= (dr & 7) << 4;
        bf16x8 vf = *(const bf16x8*)((const char*)sV + bo);
        oacc[di] = __builtin_amdgcn_mfma_f32_16x16x32_bf16(pf, vf, oacc[di], 0, 0, 0);
      }
    }
    __builtin_amdgcn_s_setprio(0);
    __syncthreads();
  }

  float il[4];
#pragma unroll
  for (int r = 0; r < 4; ++r) il[r] = 1.f / __shfl(lrun, ((lane >> 4) << 2) + r);
  const size_t obase = ((size_t)(b * 2048 + q0)) * 2048 + h * 128;
#pragma unroll
  for (int di = 0; di < 8; ++di)
#pragma unroll
    for (int r = 0; r < 4; ++r) {
      const size_t o = obase + (size_t)(((lane >> 4) << 2) + r) * 2048 + (di << 4) + (lane & 15);
      O[o] = f2bf(oacc[di][r] * il[r]);
    }
}

// ---------------------------------------------------------------- launch

extern "C" void kernel_launch(void* const* d_in, const int* in_sizes, int n_in,
                              void* d_out, int out_size, void* d_ws, size_t ws_size,
                              hipStream_t stream) {
  (void)in_sizes; (void)n_in; (void)out_size; (void)ws_size;
  const float* hidden = (const float*)d_in[0];
  const float* ln1_g = (const float*)d_in[1];
  const float* ln1_b = (const float*)d_in[2];
  const float* w_qkv = (const float*)d_in[3];
  const float* b_qkv = (const float*)d_in[4];
  const float* apv = (const float*)d_in[5];
  const float* apg = (const float*)d_in[6];
  const float* apb = (const float*)d_in[7];
  // d_in[8] emotion_bias: softmax-invariant -> dropped (exact)
  const float* ln2_g = (const float*)d_in[9];
  const float* ln2_b = (const float*)d_in[10];
  const float* w_fc = (const float*)d_in[11];
  const float* b_fc = (const float*)d_in[12];
  const float* mpv = (const float*)d_in[13];
  const float* mpg = (const float*)d_in[14];
  const float* mpb = (const float*)d_in[15];

  char* w = (char*)d_ws;
  const size_t MBs = 1ull << 20;
  unsigned short* xln = (unsigned short*)(w + 0);
  float* hidden2 = (float*)(w + 0);
  unsigned short* vtbuf = (unsigned short*)(w + 32 * MBs);
  unsigned short* hbuf = (unsigned short*)(w + 32 * MBs);
  unsigned short* qkv = (unsigned short*)(w + 96 * MBs);
  unsigned short* wfc_bf = (unsigned short*)(w + 96 * MBs);
  unsigned short* partH = (unsigned short*)(w + 96 * MBs);   // 4x16MB bf16 partials
  unsigned short* xln2 = (unsigned short*)(w + 128 * MBs);
  unsigned short* attn_out = (unsigned short*)(w + 144 * MBs);
  unsigned short* wqkv_bf = (unsigned short*)(w + 160 * MBs);
  unsigned short* w2_bf = (unsigned short*)(w + 160 * MBs);
  unsigned short* wproj_bf = (unsigned short*)(w + 192 * MBs);
  float* s_attn = (float*)(w + 200 * MBs);
  float* s_mlp = (float*)(w + 200 * MBs + 32768);
  float* part_attn = (float*)(w + 201 * MBs);
  float* part_mlp = (float*)(w + 202 * MBs);

  hipFuncSetAttribute((const void*)g1_qkv256, hipFuncAttributeMaxDynamicSharedMemorySize, 65536);
  hipFuncSetAttribute((const void*)g3_fc256r4, hipFuncAttributeMaxDynamicSharedMemorySize, 131072);
  hipFuncSetAttribute((const void*)g4_splitk256r4, hipFuncAttributeMaxDynamicSharedMemorySize, 131072);

  // weight prep
  cast_k<<<2048, 256, 0, stream>>>(w_qkv, wqkv_bf, (6144 * 2048) / 4);
  colnorm1_k<<<dim3(4, 32), 256, 0, stream>>>(apv, part_attn, 2048);
  colnorm2_k<<<8, 256, 0, stream>>>(part_attn, apg, s_attn, 2048, 32);
  scale_cast_k<<<2048, 256, 0, stream>>>(apv, s_attn, wproj_bf, 2048, (2048 * 2048) / 4);
  colnorm1_k<<<dim3(16, 32), 256, 0, stream>>>(mpv, part_mlp, 8192);
  colnorm2_k<<<32, 256, 0, stream>>>(part_mlp, mpg, s_mlp, 8192, 32);

  // LN1 -> xln (bf16)
  ln_k<<<4096, 256, 0, stream>>>(hidden, ln1_g, ln1_b, xln);

  // GEMM1 (256^2 2-phase): qkv = xln @ w_qkv^T + b
  GemmP p1 = {xln, wqkv_bf, b_qkv, nullptr, nullptr, qkv, 4096, 6144, 2048};
  g1_qkv256<<<384, 512, 65536, stream>>>(p1);

  // V slice of qkv -> V^T
  vtrans_k<<<1024, 256, 0, stream>>>(qkv, vtbuf);

  // attention (QBLK=128, 8 waves) -> attn_out
  attn_k<<<512, 512, 0, stream>>>(qkv, vtbuf, attn_out);

  // weight casts for MLP
  cast_k<<<2048, 256, 0, stream>>>(w_fc, wfc_bf, (8192 * 2048) / 4);
  scale_cast_k<<<4096, 256, 0, stream>>>(mpv, s_mlp, w2_bf, 8192, (2048 * 8192) / 4);

  // GEMM2 (128^2): hidden2 = attn_out @ w_proj^T + b + hidden
  GemmP p2 = {attn_out, wproj_bf, apb, hidden, hidden2, nullptr, 4096, 2048, 2048};
  g2_proj128<<<512, 256, 0, stream>>>(p2);

  // LN2 -> xln2
  ln_k<<<4096, 256, 0, stream>>>(hidden2, ln2_g, ln2_b, xln2);

  // GEMM3 (ring-4 unpinned, counted vmcnt)
  GemmP p3 = {xln2, wfc_bf, b_fc, nullptr, nullptr, hbuf, 4096, 8192, 2048};
  g3_fc256r4<<<512, 512, 131072, stream>>>(p3);

  // GEMM4 (ring-4 unpinned, split-K4) -> fused reduce
  GemmP p4 = {hbuf, w2_bf, mpb, nullptr, nullptr, partH, 4096, 2048, 8192};
  g4_splitk256r4<<<512, 512, 131072, stream>>>(p4);
  g4red_k<<<2048, 256, 0, stream>>>(partH, mpb, hidden2, (float*)d_out,
                                    (4096 * 2048) / 4);
}

// Round 13
// 735.829 us; speedup vs baseline: 1.0378x; 1.0200x over previous
//
#include <hip/hip_runtime.h>
#include <hip/hip_bf16.h>

#define DEVI __device__ __forceinline__

typedef __attribute__((ext_vector_type(8))) __bf16 bf16x8;
typedef __attribute__((ext_vector_type(4))) float f32x4;
typedef __attribute__((ext_vector_type(4))) unsigned short u16x4;
typedef __attribute__((ext_vector_type(8))) unsigned short u16x8;

DEVI unsigned short f2bf(float f) {
  unsigned int u = __float_as_uint(f);
  u += 0x7FFFu + ((u >> 16) & 1u);   // RNE
  return (unsigned short)(u >> 16);
}
DEVI float bf2f(unsigned short u) {
  return __uint_as_float(((unsigned int)u) << 16);
}

#define GLD16(g, l) __builtin_amdgcn_global_load_lds(                      \
    (const __attribute__((address_space(1))) void*)(g),                    \
    (__attribute__((address_space(3))) void*)(l), 16, 0, 0)

// ---------------------------------------------------------------- helpers

__global__ __launch_bounds__(256) void cast_k(const float* __restrict__ in,
                                              unsigned short* __restrict__ out,
                                              int n4) {
  for (int i = blockIdx.x * 256 + threadIdx.x; i < n4; i += gridDim.x * 256) {
    f32x4 v = ((const f32x4*)in)[i];
    u16x4 o;
    o.x = f2bf(v.x); o.y = f2bf(v.y); o.z = f2bf(v.z); o.w = f2bf(v.w);
    ((u16x4*)out)[i] = o;
  }
}

// colnorm phase 1: partial column sumsq over a 64-row x 512-col tile.
__global__ __launch_bounds__(256) void colnorm1_k(const float* __restrict__ v,
                                                  float* __restrict__ part,
                                                  int cols) {
  const int tid = threadIdx.x;
  const int g = tid & 127;
  const int s = tid >> 7;
  const int c0 = blockIdx.x * 512;
  const int r0 = blockIdx.y * 64 + s * 32;
  const float* base = v + (size_t)r0 * cols + c0 + g * 4;
  f32x4 acc = {};
#pragma unroll 4
  for (int i = 0; i < 32; ++i) {
    f32x4 x = *(const f32x4*)(base + (size_t)i * cols);
    acc.x += x.x * x.x; acc.y += x.y * x.y;
    acc.z += x.z * x.z; acc.w += x.w * x.w;
  }
  __shared__ f32x4 red[256];
  red[tid] = acc;
  __syncthreads();
  if (s == 0) {
    f32x4 a = red[tid], b = red[tid + 128];
    f32x4 o;
    o.x = a.x + b.x; o.y = a.y + b.y; o.z = a.z + b.z; o.w = a.w + b.w;
    *(f32x4*)(part + (size_t)blockIdx.y * cols + c0 + g * 4) = o;
  }
}

// colnorm phase 2: s[c] = g[c] * rsqrt(sum_rc part[rc][c])
__global__ __launch_bounds__(256) void colnorm2_k(const float* __restrict__ part,
                                                  const float* __restrict__ g,
                                                  float* __restrict__ s,
                                                  int cols, int nrc) {
  const int c = blockIdx.x * 256 + threadIdx.x;
  float acc = 0.f;
  for (int i = 0; i < nrc; ++i) acc += part[(size_t)i * cols + c];
  s[c] = g[c] * rsqrtf(acc);
}

__global__ __launch_bounds__(256) void scale_cast_k(const float* __restrict__ in,
                                                    const float* __restrict__ s,
                                                    unsigned short* __restrict__ out,
                                                    int cols, int n4) {
  const int cmask4 = (cols >> 2) - 1;
  for (int i = blockIdx.x * 256 + threadIdx.x; i < n4; i += gridDim.x * 256) {
    f32x4 v = ((const f32x4*)in)[i];
    f32x4 sv = ((const f32x4*)s)[i & cmask4];
    u16x4 o;
    o.x = f2bf(v.x * sv.x); o.y = f2bf(v.y * sv.y);
    o.z = f2bf(v.z * sv.z); o.w = f2bf(v.w * sv.w);
    ((u16x4*)out)[i] = o;
  }
}

// LayerNorm: one block per row of 2048 fp32, out bf16
__global__ __launch_bounds__(256) void ln_k(const float* __restrict__ x,
                                            const float* __restrict__ g,
                                            const float* __restrict__ b,
                                            unsigned short* __restrict__ out) {
  const int tid = threadIdx.x, lane = tid & 63, wid = tid >> 6;
  const int row = blockIdx.x;
  const float* xr = x + (size_t)row * 2048;
  f32x4 a0 = ((const f32x4*)xr)[tid];
  f32x4 a1 = ((const f32x4*)xr)[tid + 256];
  float s = a0.x + a0.y + a0.z + a0.w + a1.x + a1.y + a1.z + a1.w;
  float ss = a0.x * a0.x + a0.y * a0.y + a0.z * a0.z + a0.w * a0.w +
             a1.x * a1.x + a1.y * a1.y + a1.z * a1.z + a1.w * a1.w;
#pragma unroll
  for (int m = 1; m < 64; m <<= 1) {
    s += __shfl_xor(s, m);
    ss += __shfl_xor(ss, m);
  }
  __shared__ float red[8];
  if (lane == 0) { red[wid] = s; red[4 + wid] = ss; }
  __syncthreads();
  s = red[0] + red[1] + red[2] + red[3];
  ss = red[4] + red[5] + red[6] + red[7];
  const float mu = s * (1.f / 2048.f);
  const float var = ss * (1.f / 2048.f) - mu * mu;
  const float rs = rsqrtf(var + 1e-5f);
  f32x4 g0 = ((const f32x4*)g)[tid], g1 = ((const f32x4*)g)[tid + 256];
  f32x4 b0 = ((const f32x4*)b)[tid], b1 = ((const f32x4*)b)[tid + 256];
  u16x4 o0, o1;
  o0.x = f2bf((a0.x - mu) * rs * g0.x + b0.x);
  o0.y = f2bf((a0.y - mu) * rs * g0.y + b0.y);
  o0.z = f2bf((a0.z - mu) * rs * g0.z + b0.z);
  o0.w = f2bf((a0.w - mu) * rs * g0.w + b0.w);
  o1.x = f2bf((a1.x - mu) * rs * g1.x + b1.x);
  o1.y = f2bf((a1.y - mu) * rs * g1.y + b1.y);
  o1.z = f2bf((a1.z - mu) * rs * g1.z + b1.z);
  o1.w = f2bf((a1.w - mu) * rs * g1.w + b1.w);
  unsigned short* orow = out + (size_t)row * 2048;
  *(u16x4*)(orow + 4 * tid) = o0;
  *(u16x4*)(orow + 1024 + 4 * tid) = o1;
}

// V transpose: V slice of qkv [4096][6144] -> vt [32][128][2048]
__global__ __launch_bounds__(256) void vtrans_k(const unsigned short* __restrict__ qkv,
                                                unsigned short* __restrict__ vt) {
  __shared__ unsigned short t[64][134];
  const int tid = threadIdx.x;
  const int bh = blockIdx.x >> 5, st = blockIdx.x & 31;
  const int b = bh >> 4, h = bh & 15;
  const unsigned short* vb = qkv + (size_t)(b * 2048 + st * 64) * 6144 + 4096 + h * 128;
#pragma unroll
  for (int i = 0; i < 4; ++i) {
    int f = tid + (i << 8);
    int row = f >> 4, c8 = f & 15;
    u16x8 x = *(const u16x8*)(vb + (size_t)row * 6144 + c8 * 8);
#pragma unroll
    for (int j = 0; j < 4; ++j) {
      unsigned int pk = ((unsigned int)x[2 * j + 1] << 16) | x[2 * j];
      *(unsigned int*)&t[row][c8 * 8 + 2 * j] = pk;
    }
  }
  __syncthreads();
  const int lane = tid & 63, wid = tid >> 6;
  unsigned short* ob = vt + ((size_t)bh << 18) + (st << 6);
#pragma unroll
  for (int j = 0; j < 32; ++j) {
    int d = (wid << 5) + j;
    ob[((size_t)d << 11) + lane] = t[lane][d];
  }
}

// split-K4 reduce: out = sum(bf16 parts 0..3) + bias + res (fp32)
__global__ __launch_bounds__(256) void g4red_k(const unsigned short* __restrict__ parts,
                                               const float* __restrict__ bias,
                                               const float* __restrict__ res,
                                               float* __restrict__ out, int n4) {
  const size_t PS = (size_t)4096 * 2048;
  for (int i = blockIdx.x * 256 + threadIdx.x; i < n4; i += gridDim.x * 256) {
    u16x4 a = ((const u16x4*)(parts))[i];
    u16x4 b = ((const u16x4*)(parts + PS))[i];
    u16x4 c = ((const u16x4*)(parts + 2 * PS))[i];
    u16x4 d = ((const u16x4*)(parts + 3 * PS))[i];
    f32x4 r = ((const f32x4*)res)[i];
    f32x4 bb = ((const f32x4*)bias)[i & 511];
    f32x4 o;
    o.x = bf2f(a.x) + bf2f(b.x) + bf2f(c.x) + bf2f(d.x) + r.x + bb.x;
    o.y = bf2f(a.y) + bf2f(b.y) + bf2f(c.y) + bf2f(d.y) + r.y + bb.y;
    o.z = bf2f(a.z) + bf2f(b.z) + bf2f(c.z) + bf2f(d.z) + r.z + bb.z;
    o.w = bf2f(a.w) + bf2f(b.w) + bf2f(c.w) + bf2f(d.w) + r.w + bb.w;
    ((f32x4*)out)[i] = o;
  }
}

// ---------------------------------------------------------------- GEMM params
struct GemmP {
  const unsigned short* A;
  const unsigned short* B;
  const float* bias;
  const float* res;
  float* outF;
  unsigned short* outH;
  int M, N, K;
};

// ---------------------------------------------------------------- 128^2 GEMM (2-phase)
// +bias +res -> fp32
DEVI void gemm128_body(const GemmP& p, int m0, int n0, int k0, int nk) {
  const int tid = threadIdx.x, lane = tid & 63, wid = tid >> 6;
  const int K = p.K;
  const int wr = wid >> 1, wc = wid & 1;

  __shared__ __align__(16) unsigned short sA[2][4096];
  __shared__ __align__(16) unsigned short sB[2][4096];

  const int c0 = tid, c1 = tid + 256;
  const unsigned short* gA0 = p.A + (size_t)(m0 + (c0 >> 2)) * K + k0 + ((c0 & 3) << 3);
  const unsigned short* gA1 = p.A + (size_t)(m0 + (c1 >> 2)) * K + k0 + ((c1 & 3) << 3);
  const unsigned short* gB0 = p.B + (size_t)(n0 + (c0 >> 2)) * K + k0 + ((c0 & 3) << 3);
  const unsigned short* gB1 = p.B + (size_t)(n0 + (c1 >> 2)) * K + k0 + ((c1 & 3) << 3);
  const int l0 = wid << 9, l1 = (wid << 9) + 2048;

  f32x4 acc[4][4] = {};
  const int arow = (wr << 6) + (lane & 15);
  const int brow = (wc << 6) + (lane & 15);
  const int koff = (lane >> 4) << 3;

#define STAGE128(bufi, t) do { int ko = (t) << 5;       \
    GLD16(gA0 + ko, &sA[bufi][l0]);                     \
    GLD16(gA1 + ko, &sA[bufi][l1]);                     \
    GLD16(gB0 + ko, &sB[bufi][l0]);                     \
    GLD16(gB1 + ko, &sB[bufi][l1]); } while (0)

  STAGE128(0, 0);
  __syncthreads();
  int cur = 0;
  for (int t = 0; t < nk; ++t) {
    if (t + 1 < nk) STAGE128(cur ^ 1, t + 1);
    bf16x8 af[4], bfr[4];
#pragma unroll
    for (int i = 0; i < 4; ++i)
      af[i] = *(const bf16x8*)&sA[cur][(arow + (i << 4)) * 32 + koff];
#pragma unroll
    for (int i = 0; i < 4; ++i)
      bfr[i] = *(const bf16x8*)&sB[cur][(brow + (i << 4)) * 32 + koff];
#pragma unroll
    for (int i = 0; i < 4; ++i)
#pragma unroll
      for (int j = 0; j < 4; ++j)
        acc[i][j] = __builtin_amdgcn_mfma_f32_16x16x32_bf16(af[i], bfr[j], acc[i][j], 0, 0, 0);
    __syncthreads();
    cur ^= 1;
  }
#undef STAGE128

  const int rbase = m0 + (wr << 6) + ((lane >> 4) << 2);
  const int cbase = n0 + (wc << 6) + (lane & 15);
#pragma unroll
  for (int mi = 0; mi < 4; ++mi) {
#pragma unroll
    for (int ni = 0; ni < 4; ++ni) {
      const int col = cbase + (ni << 4);
#pragma unroll
      for (int r = 0; r < 4; ++r) {
        const int row = rbase + (mi << 4) + r;
        const size_t o = (size_t)row * p.N + col;
        p.outF[o] = acc[mi][ni][r] + p.bias[col] + p.res[o];
      }
    }
  }
}

// G2: M=4096,N=2048 -> nbm=32,nbn=16. Region/XCD = 8x8.
__global__ __launch_bounds__(256) void g2_proj128(GemmP p) {
  const int x = blockIdx.x & 7, i = blockIdx.x >> 3;  // i in [0,64)
  const int bm = (x >> 1) * 8 + (i >> 3);
  const int bn = (x & 1) * 8 + (i & 7);
  gemm128_body(p, bm << 7, bn << 7, 0, p.K >> 5);
}

// ---------------------------------------------------------------- 256^2 tile common
DEVI void setup256(const GemmP& p, int m0, int n0, int k0,
                   const unsigned short*& gsA0, const unsigned short*& gsA1,
                   const unsigned short*& gsB0, const unsigned short*& gsB1) {
  const int tid = threadIdx.x;
  int r_[2], c_[2];
#pragma unroll
  for (int j = 0; j < 2; ++j) {
    int d = tid * 16 + j * 8192;
    int w = (d & 1023) ^ (((d >> 9) & 1) << 5);   // st_16x32 involution
    r_[j] = ((d >> 10) << 4) + (w >> 6);
    c_[j] = (w & 63) >> 1;
  }
  gsA0 = p.A + (size_t)(m0 + r_[0]) * p.K + k0 + c_[0];
  gsA1 = p.A + (size_t)(m0 + r_[1]) * p.K + k0 + c_[1];
  gsB0 = p.B + (size_t)(n0 + r_[0]) * p.K + k0 + c_[0];
  gsB1 = p.B + (size_t)(n0 + r_[1]) * p.K + k0 + c_[1];
}

// epilogue: EPI 0 = +bias -> bf16   2 = +bias fast-GELU -> bf16   5 = raw -> bf16
template <int EPI>
DEVI void epi256(const GemmP& p, f32x4 (&acc)[8][4], int m0, int n0,
                 unsigned short* outH) {
  const int lane = threadIdx.x & 63, wid = threadIdx.x >> 6;
  const int wr = wid >> 2, wc = wid & 3;
  const int lr = lane & 15, lk = lane >> 4;
  const int rbase = m0 + wr * 128 + (lk << 2);
  const int cbase = n0 + wc * 64 + lr;
#pragma unroll
  for (int m = 0; m < 8; ++m) {
#pragma unroll
    for (int n = 0; n < 4; ++n) {
      const int col = cbase + (n << 4);
      const float bb = (EPI == 5) ? 0.f : p.bias[col];
#pragma unroll
      for (int r = 0; r < 4; ++r) {
        const int row = rbase + (m << 4) + r;
        float v = acc[m][n][r] + bb;
        if constexpr (EPI == 2) {
          float y = 0.7978845608028654f * (v + 0.044715f * v * v * v);
          float u = __expf(2.f * y);
          v = (y > 40.f) ? v : v * (u / (u + 1.f));
        }
        outH[(size_t)row * p.N + col] = f2bf(v);
      }
    }
  }
}

// ---------------------------------------------------------------- 256^2 2-phase
template <int EPI>
DEVI void gemm2p_body(const GemmP& p, unsigned short* lds_raw, int m0, int n0,
                      int k0, int nk, unsigned short* outH) {
  const int tid = threadIdx.x, lane = tid & 63, wid = tid >> 6;
  const int wr = wid >> 2, wc = wid & 3;
  const int lr = lane & 15, lk = lane >> 4;
  const int fb = (lr * 64 + lk * 16) ^ ((lr & 8) << 2);

  const unsigned short *gsA0, *gsA1, *gsB0, *gsB1;
  setup256(p, m0, n0, k0, gsA0, gsA1, gsB0, gsB1);

#define STG2(b, kt) do { unsigned short* _d = lds_raw + ((b) << 14);     \
    GLD16(gsA0 + ((size_t)(kt) << 5), _d + (tid << 3));                  \
    GLD16(gsA1 + ((size_t)(kt) << 5), _d + 4096 + (tid << 3));           \
    GLD16(gsB0 + ((size_t)(kt) << 5), _d + 8192 + (tid << 3));           \
    GLD16(gsB1 + ((size_t)(kt) << 5), _d + 12288 + (tid << 3)); } while (0)

  f32x4 acc[8][4] = {};
  STG2(0, 0);
  __syncthreads();
  int cur = 0;
  for (int t = 0; t < nk; ++t) {
    if (t + 1 < nk) STG2(cur ^ 1, t + 1);
    const char* tA = (const char*)(lds_raw + (cur << 14));
    const char* tB = tA + 16384;
    bf16x8 a_[8], b_[4];
#pragma unroll
    for (int n = 0; n < 4; ++n)
      b_[n] = *(const bf16x8*)(tB + (((wc << 2) + n) << 10) + fb);
#pragma unroll
    for (int m = 0; m < 8; ++m)
      a_[m] = *(const bf16x8*)(tA + (((wr << 3) + m) << 10) + fb);
#pragma unroll
    for (int m = 0; m < 8; ++m)
#pragma unroll
      for (int n = 0; n < 4; ++n)
        acc[m][n] = __builtin_amdgcn_mfma_f32_16x16x32_bf16(a_[m], b_[n], acc[m][n], 0, 0, 0);
    __syncthreads();
    cur ^= 1;
  }
#undef STG2
  epi256<EPI>(p, acc, m0, n0, outH);
}

// ---------------------------------------------------------------- 256^2 BK=64 ring-2
// Halves sync events vs BK=32: per step = 24 ds_read + 8 staging loads + 64 MFMA
// (~310 cy >= L2 latency, so the end-of-step vmcnt(0) is mostly covered) + 1 barrier.
// Buffer (64KB) = 4 x 16KB subtiles: A_ks0, A_ks1, B_ks0, B_ks1 (proven swizzle).
// Race safety: reads of buf X drain (lgkmcnt before consuming MFMAs) before the
// step barrier; stage into X issues only after that barrier; RAW by own vmcnt(0).
template <int EPI>
DEVI void gemmr2k64_body(const GemmP& p, unsigned short* lds_raw, int m0, int n0,
                         int k0, int nk64, unsigned short* outH) {
  const int tid = threadIdx.x, lane = tid & 63, wid = tid >> 6;
  const int wr = wid >> 2, wc = wid & 3;
  const int lr = lane & 15, lk = lane >> 4;
  const int fb = (lr * 64 + lk * 16) ^ ((lr & 8) << 2);

  const unsigned short *gsA0, *gsA1, *gsB0, *gsB1;
  setup256(p, m0, n0, k0, gsA0, gsA1, gsB0, gsB1);

#define STG64(bufi, kt) do { unsigned short* _d = lds_raw + ((bufi) << 15);  \
    int _ko = (kt) << 6;                                                     \
    GLD16(gsA0 + _ko,      _d + (tid << 3));                                 \
    GLD16(gsA1 + _ko,      _d + 4096 + (tid << 3));                          \
    GLD16(gsA0 + _ko + 32, _d + 8192 + (tid << 3));                          \
    GLD16(gsA1 + _ko + 32, _d + 12288 + (tid << 3));                         \
    GLD16(gsB0 + _ko,      _d + 16384 + (tid << 3));                         \
    GLD16(gsB1 + _ko,      _d + 20480 + (tid << 3));                         \
    GLD16(gsB0 + _ko + 32, _d + 24576 + (tid << 3));                         \
    GLD16(gsB1 + _ko + 32, _d + 28672 + (tid << 3)); } while (0)

  f32x4 acc[8][4] = {};
  STG64(0, 0);
  asm volatile("s_waitcnt vmcnt(0)" ::: "memory");
  __builtin_amdgcn_s_barrier();
  asm volatile("" ::: "memory");

  for (int t = 0; t < nk64; ++t) {
    if (t + 1 < nk64) STG64((t + 1) & 1, t + 1);
    const char* base = (const char*)(lds_raw + ((t & 1) << 15));
#pragma unroll
    for (int s = 0; s < 2; ++s) {
      const char* tA = base + s * 16384;
      const char* tB = base + 32768 + s * 16384;
      bf16x8 a_[8], b_[4];
#pragma unroll
      for (int n = 0; n < 4; ++n)
        b_[n] = *(const bf16x8*)(tB + (((wc << 2) + n) << 10) + fb);
#pragma unroll
      for (int m = 0; m < 8; ++m)
        a_[m] = *(const bf16x8*)(tA + (((wr << 3) + m) << 10) + fb);
      __builtin_amdgcn_s_setprio(1);
#pragma unroll
      for (int m = 0; m < 8; ++m)
#pragma unroll
        for (int n = 0; n < 4; ++n)
          acc[m][n] = __builtin_amdgcn_mfma_f32_16x16x32_bf16(a_[m], b_[n], acc[m][n], 0, 0, 0);
      __builtin_amdgcn_s_setprio(0);
    }
    if (t + 1 < nk64) asm volatile("s_waitcnt vmcnt(0)" ::: "memory");
    __builtin_amdgcn_s_barrier();
    asm volatile("" ::: "memory");
  }
#undef STG64
  epi256<EPI>(p, acc, m0, n0, outH);
}

// G1 (256^2 2-phase): M=4096,N=6144 -> nbm=16,nbn=24; region 8x6 per XCD.
// (stays 2-phase: 384 blocks at 1/CU would leave half the chip idle in round 2)
__global__ __launch_bounds__(512, 2) void g1_qkv256(GemmP p) {
  extern __shared__ unsigned short lds_raw[];
  const int x = blockIdx.x & 7, i = blockIdx.x >> 3;   // i in [0,48)
  const int bm = (x & 1) * 8 + (i & 7);
  const int bn = (x >> 1) * 6 + (i >> 3);
  gemm2p_body<0>(p, lds_raw, bm << 8, bn << 8, 0, p.K >> 5, p.outH);
}
// G3 BK=64 ring-2 (128KB LDS, 1 block/CU)
__global__ __launch_bounds__(512, 1) void g3_fc64(GemmP p) {
  extern __shared__ unsigned short lds_raw[];
  const int x = blockIdx.x & 7, i = blockIdx.x >> 3;   // i in [0,64)
  const int bm = (x & 1) * 8 + (i & 7);
  const int bn = (x >> 1) * 8 + (i >> 3);
  gemmr2k64_body<2>(p, lds_raw, bm << 8, bn << 8, 0, 32, p.outH);
}
// G4 BK=64 ring-2, split-K4: nbm=16,nbn=8, ks in [0,4).
__global__ __launch_bounds__(512, 1) void g4_sk64(GemmP p) {
  extern __shared__ unsigned short lds_raw[];
  const int x = blockIdx.x & 7, i = blockIdx.x >> 3;   // i in [0,64)
  const int ks = x & 3;
  const int bm = (x >> 2) * 8 + (i >> 3);
  const int bn = i & 7;
  unsigned short* outH = p.outH + (size_t)ks * 4096 * 2048;
  gemmr2k64_body<5>(p, lds_raw, bm << 8, bn << 8, ks << 11, 32, outH);
}

// ---------------------------------------------------------------- attention
// QBLK=128 (8 waves). Q,K from unified qkv [4096][6144]; V^T [32][128][2048].
// Softmax in raw-score domain: single exp2 constant, threshold 8/scale.
__global__ __launch_bounds__(512) void attn_k(const unsigned short* __restrict__ qkv,
                                              const unsigned short* __restrict__ Vt,
                                              unsigned short* __restrict__ O) {
  const int tid = threadIdx.x, lane = tid & 63, wid = tid >> 6;
  const int bid = blockIdx.x;                 // grid = 512
  const int pos = bid >> 3;                   // [0,64)
  const int bh = (bid & 7) * 4 + (pos >> 4);
  const int qt = pos & 15;
  const int q0 = qt * 128 + wid * 16;
  const int b = bh >> 4, h = bh & 15;
  const float C = 0.08838834764831845f * 1.4426950408889634f;  // scale*log2e

  __shared__ __align__(16) unsigned short sK[64 * 128];
  __shared__ __align__(16) unsigned short sV[128 * 64];
  __shared__ __align__(16) unsigned short sP[8][16 * 72];

  const unsigned short* Qb = qkv + (size_t)(b * 2048) * 6144 + h * 128;
  const unsigned short* Kb = qkv + (size_t)(b * 2048) * 6144 + 2048 + h * 128;
  const unsigned short* Vb = Vt + ((size_t)bh << 18);

  bf16x8 qf[4];
  {
    const unsigned short* qp = Qb + (size_t)(q0 + (lane & 15)) * 6144 + ((lane >> 4) << 3);
#pragma unroll
    for (int kk = 0; kk < 4; ++kk) qf[kk] = *(const bf16x8*)(qp + kk * 32);
  }

  int koffs[2], voffs[2];
#pragma unroll
  for (int i = 0; i < 2; ++i) {
    const int c = tid + (i << 9);
    const int kv = c >> 4, jj = c & 15;
    const int js = (jj & 8) | ((jj ^ kv) & 7);
    koffs[i] = kv * 6144 + (js << 3);
    const int d = c >> 3, j2 = c & 7;
    const int js2 = j2 ^ (d & 7);
    voffs[i] = d * 2048 + (js2 << 3);
  }
  u16x8 kreg[2], vreg[2];
  auto PREF = [&](int kt) {
    const int kv0 = kt << 6;
    const unsigned short* kb = Kb + (size_t)kv0 * 6144;
#pragma unroll
    for (int i = 0; i < 2; ++i) {
      kreg[i] = *(const u16x8*)(kb + koffs[i]);
      vreg[i] = *(const u16x8*)(Vb + kv0 + voffs[i]);
    }
  };

  f32x4 oacc[8] = {};
  float mrun = -3e38f, lrun = 0.f;
  PREF(0);

  for (int kt = 0; kt < 32; ++kt) {
#pragma unroll
    for (int i = 0; i < 2; ++i) {
      const int c8 = (tid + (i << 9)) << 3;
      *(u16x8*)&sK[c8] = kreg[i];
      *(u16x8*)&sV[c8] = vreg[i];
    }
    __syncthreads();
    if (kt + 1 < 32) PREF(kt + 1);

    f32x4 sc[4] = {};
    __builtin_amdgcn_s_setprio(1);
#pragma unroll
    for (int ti = 0; ti < 4; ++ti) {
#pragma unroll
      for (int kk = 0; kk < 4; ++kk) {
        const int row = (ti << 4) + (lane & 15);
        int bo = (row << 8) + (kk << 6) + ((lane >> 4) << 4);
        bo ^= (row & 7) << 4;
        bf16x8 kf = *(const bf16x8*)((const char*)sK + bo);
        sc[ti] = __builtin_amdgcn_mfma_f32_16x16x32_bf16(kf, qf[kk], sc[ti], 0, 0, 0);
      }
    }
    __builtin_amdgcn_s_setprio(0);

    float pv[16];
    float mx = -3e38f;
#pragma unroll
    for (int ti = 0; ti < 4; ++ti)
#pragma unroll
      for (int r = 0; r < 4; ++r) {
        float x = sc[ti][r];         // raw scores
        pv[(ti << 2) + r] = x;
        mx = fmaxf(mx, x);
      }
    mx = fmaxf(mx, __shfl_xor(mx, 16));
    mx = fmaxf(mx, __shfl_xor(mx, 32));

    float corr = 1.f;
    if (!__all(mx - mrun <= 90.50966799f)) {   // 8 / scale
      const float mnew = fmaxf(mrun, mx);
      corr = exp2f((mrun - mnew) * C);
      mrun = mnew;
      float fr[4];
#pragma unroll
      for (int r = 0; r < 4; ++r) fr[r] = __shfl(corr, ((lane >> 4) << 2) + r);
#pragma unroll
      for (int di = 0; di < 8; ++di)
#pragma unroll
        for (int r = 0; r < 4; ++r) oacc[di][r] *= fr[r];
    }
    float psum = 0.f;
#pragma unroll
    for (int i2 = 0; i2 < 16; ++i2) {
      float e = exp2f((pv[i2] - mrun) * C);
      pv[i2] = e;
      psum += e;
    }
    psum += __shfl_xor(psum, 16);
    psum += __shfl_xor(psum, 32);
    lrun = lrun * corr + psum;

    unsigned short* prow = &sP[wid][(lane & 15) * 72];
#pragma unroll
    for (int ti = 0; ti < 4; ++ti) {
      u16x4 w4;
      w4.x = f2bf(pv[(ti << 2) + 0]);
      w4.y = f2bf(pv[(ti << 2) + 1]);
      w4.z = f2bf(pv[(ti << 2) + 2]);
      w4.w = f2bf(pv[(ti << 2) + 3]);
      *(u16x4*)&prow[(ti << 4) + ((lane >> 4) << 2)] = w4;
    }

    bf16x8 pfA, pfB;
    {
      const char* pb = (const char*)&sP[wid][0] + (lane & 15) * 144 + ((lane >> 4) << 4);
      pfA = *(const bf16x8*)(pb);
      pfB = *(const bf16x8*)(pb + 64);
    }
    __builtin_amdgcn_s_setprio(1);
#pragma unroll
    for (int di = 0; di < 8; ++di) {
#pragma unroll
      for (int ks = 0; ks < 2; ++ks) {
        const int dr = (di << 4) + (lane & 15);
        int bo = (dr << 7) + (ks << 6) + ((lane >> 4) << 4);
        bo ^= (dr & 7) << 4;
        bf16x8 vf = *(const bf16x8*)((const char*)sV + bo);
        oacc[di] = __builtin_amdgcn_mfma_f32_16x16x32_bf16(ks ? pfB : pfA, vf, oacc[di], 0, 0, 0);
      }
    }
    __builtin_amdgcn_s_setprio(0);
    __syncthreads();
  }

  float il[4];
#pragma unroll
  for (int r = 0; r < 4; ++r) il[r] = 1.f / __shfl(lrun, ((lane >> 4) << 2) + r);
  const size_t obase = ((size_t)(b * 2048 + q0)) * 2048 + h * 128;
#pragma unroll
  for (int di = 0; di < 8; ++di)
#pragma unroll
    for (int r = 0; r < 4; ++r) {
      const size_t o = obase + (size_t)(((lane >> 4) << 2) + r) * 2048 + (di << 4) + (lane & 15);
      O[o] = f2bf(oacc[di][r] * il[r]);
    }
}

// ---------------------------------------------------------------- launch

extern "C" void kernel_launch(void* const* d_in, const int* in_sizes, int n_in,
                              void* d_out, int out_size, void* d_ws, size_t ws_size,
                              hipStream_t stream) {
  (void)in_sizes; (void)n_in; (void)out_size; (void)ws_size;
  const float* hidden = (const float*)d_in[0];
  const float* ln1_g = (const float*)d_in[1];
  const float* ln1_b = (const float*)d_in[2];
  const float* w_qkv = (const float*)d_in[3];
  const float* b_qkv = (const float*)d_in[4];
  const float* apv = (const float*)d_in[5];
  const float* apg = (const float*)d_in[6];
  const float* apb = (const float*)d_in[7];
  // d_in[8] emotion_bias: softmax-invariant -> dropped (exact)
  const float* ln2_g = (const float*)d_in[9];
  const float* ln2_b = (const float*)d_in[10];
  const float* w_fc = (const float*)d_in[11];
  const float* b_fc = (const float*)d_in[12];
  const float* mpv = (const float*)d_in[13];
  const float* mpg = (const float*)d_in[14];
  const float* mpb = (const float*)d_in[15];

  char* w = (char*)d_ws;
  const size_t MBs = 1ull << 20;
  unsigned short* xln = (unsigned short*)(w + 0);
  float* hidden2 = (float*)(w + 0);
  unsigned short* vtbuf = (unsigned short*)(w + 32 * MBs);
  unsigned short* hbuf = (unsigned short*)(w + 32 * MBs);
  unsigned short* qkv = (unsigned short*)(w + 96 * MBs);
  unsigned short* wfc_bf = (unsigned short*)(w + 96 * MBs);
  unsigned short* partH = (unsigned short*)(w + 96 * MBs);   // 4x16MB bf16 partials
  unsigned short* xln2 = (unsigned short*)(w + 128 * MBs);
  unsigned short* attn_out = (unsigned short*)(w + 144 * MBs);
  unsigned short* wqkv_bf = (unsigned short*)(w + 160 * MBs);
  unsigned short* w2_bf = (unsigned short*)(w + 160 * MBs);
  unsigned short* wproj_bf = (unsigned short*)(w + 192 * MBs);
  float* s_attn = (float*)(w + 200 * MBs);
  float* s_mlp = (float*)(w + 200 * MBs + 32768);
  float* part_attn = (float*)(w + 201 * MBs);
  float* part_mlp = (float*)(w + 202 * MBs);

  hipFuncSetAttribute((const void*)g1_qkv256, hipFuncAttributeMaxDynamicSharedMemorySize, 65536);
  hipFuncSetAttribute((const void*)g3_fc64, hipFuncAttributeMaxDynamicSharedMemorySize, 131072);
  hipFuncSetAttribute((const void*)g4_sk64, hipFuncAttributeMaxDynamicSharedMemorySize, 131072);

  // weight prep
  cast_k<<<2048, 256, 0, stream>>>(w_qkv, wqkv_bf, (6144 * 2048) / 4);
  colnorm1_k<<<dim3(4, 32), 256, 0, stream>>>(apv, part_attn, 2048);
  colnorm2_k<<<8, 256, 0, stream>>>(part_attn, apg, s_attn, 2048, 32);
  scale_cast_k<<<2048, 256, 0, stream>>>(apv, s_attn, wproj_bf, 2048, (2048 * 2048) / 4);
  colnorm1_k<<<dim3(16, 32), 256, 0, stream>>>(mpv, part_mlp, 8192);
  colnorm2_k<<<32, 256, 0, stream>>>(part_mlp, mpg, s_mlp, 8192, 32);

  // LN1 -> xln (bf16)
  ln_k<<<4096, 256, 0, stream>>>(hidden, ln1_g, ln1_b, xln);

  // GEMM1 (256^2 2-phase): qkv = xln @ w_qkv^T + b
  GemmP p1 = {xln, wqkv_bf, b_qkv, nullptr, nullptr, qkv, 4096, 6144, 2048};
  g1_qkv256<<<384, 512, 65536, stream>>>(p1);

  // V slice of qkv -> V^T
  vtrans_k<<<1024, 256, 0, stream>>>(qkv, vtbuf);

  // attention (QBLK=128, 8 waves) -> attn_out
  attn_k<<<512, 512, 0, stream>>>(qkv, vtbuf, attn_out);

  // weight casts for MLP
  cast_k<<<2048, 256, 0, stream>>>(w_fc, wfc_bf, (8192 * 2048) / 4);
  scale_cast_k<<<4096, 256, 0, stream>>>(mpv, s_mlp, w2_bf, 8192, (2048 * 8192) / 4);

  // GEMM2 (128^2): hidden2 = attn_out @ w_proj^T + b + hidden
  GemmP p2 = {attn_out, wproj_bf, apb, hidden, hidden2, nullptr, 4096, 2048, 2048};
  g2_proj128<<<512, 256, 0, stream>>>(p2);

  // LN2 -> xln2
  ln_k<<<4096, 256, 0, stream>>>(hidden2, ln2_g, ln2_b, xln2);

  // GEMM3 (BK=64 ring-2)
  GemmP p3 = {xln2, wfc_bf, b_fc, nullptr, nullptr, hbuf, 4096, 8192, 2048};
  g3_fc64<<<512, 512, 131072, stream>>>(p3);

  // GEMM4 (BK=64 ring-2, split-K4) -> fused reduce
  GemmP p4 = {hbuf, w2_bf, mpb, nullptr, nullptr, partH, 4096, 2048, 8192};
  g4_sk64<<<512, 512, 131072, stream>>>(p4);
  g4red_k<<<2048, 256, 0, stream>>>(partH, mpb, hidden2, (float*)d_out,
                                    (4096 * 2048) / 4);
}

// Round 14
// 733.314 us; speedup vs baseline: 1.0414x; 1.0034x over previous
//
#include <hip/hip_runtime.h>
#include <hip/hip_bf16.h>

#define DEVI __device__ __forceinline__

typedef __attribute__((ext_vector_type(8))) __bf16 bf16x8;
typedef __attribute__((ext_vector_type(4))) float f32x4;
typedef __attribute__((ext_vector_type(4))) unsigned short u16x4;
typedef __attribute__((ext_vector_type(8))) unsigned short u16x8;

DEVI unsigned short f2bf(float f) {
  unsigned int u = __float_as_uint(f);
  u += 0x7FFFu + ((u >> 16) & 1u);   // RNE
  return (unsigned short)(u >> 16);
}
DEVI float bf2f(unsigned short u) {
  return __uint_as_float(((unsigned int)u) << 16);
}

#define GLD16(g, l) __builtin_amdgcn_global_load_lds(                      \
    (const __attribute__((address_space(1))) void*)(g),                    \
    (__attribute__((address_space(3))) void*)(l), 16, 0, 0)

// ---------------------------------------------------------------- helpers

__global__ __launch_bounds__(256) void cast_k(const float* __restrict__ in,
                                              unsigned short* __restrict__ out,
                                              int n4) {
  for (int i = blockIdx.x * 256 + threadIdx.x; i < n4; i += gridDim.x * 256) {
    f32x4 v = ((const f32x4*)in)[i];
    u16x4 o;
    o.x = f2bf(v.x); o.y = f2bf(v.y); o.z = f2bf(v.z); o.w = f2bf(v.w);
    ((u16x4*)out)[i] = o;
  }
}

// colnorm phase 1: partial column sumsq over a 64-row x 512-col tile.
__global__ __launch_bounds__(256) void colnorm1_k(const float* __restrict__ v,
                                                  float* __restrict__ part,
                                                  int cols) {
  const int tid = threadIdx.x;
  const int g = tid & 127;
  const int s = tid >> 7;
  const int c0 = blockIdx.x * 512;
  const int r0 = blockIdx.y * 64 + s * 32;
  const float* base = v + (size_t)r0 * cols + c0 + g * 4;
  f32x4 acc = {};
#pragma unroll 4
  for (int i = 0; i < 32; ++i) {
    f32x4 x = *(const f32x4*)(base + (size_t)i * cols);
    acc.x += x.x * x.x; acc.y += x.y * x.y;
    acc.z += x.z * x.z; acc.w += x.w * x.w;
  }
  __shared__ f32x4 red[256];
  red[tid] = acc;
  __syncthreads();
  if (s == 0) {
    f32x4 a = red[tid], b = red[tid + 128];
    f32x4 o;
    o.x = a.x + b.x; o.y = a.y + b.y; o.z = a.z + b.z; o.w = a.w + b.w;
    *(f32x4*)(part + (size_t)blockIdx.y * cols + c0 + g * 4) = o;
  }
}

// colnorm phase 2: s[c] = g[c] * rsqrt(sum_rc part[rc][c])
__global__ __launch_bounds__(256) void colnorm2_k(const float* __restrict__ part,
                                                  const float* __restrict__ g,
                                                  float* __restrict__ s,
                                                  int cols, int nrc) {
  const int c = blockIdx.x * 256 + threadIdx.x;
  float acc = 0.f;
  for (int i = 0; i < nrc; ++i) acc += part[(size_t)i * cols + c];
  s[c] = g[c] * rsqrtf(acc);
}

__global__ __launch_bounds__(256) void scale_cast_k(const float* __restrict__ in,
                                                    const float* __restrict__ s,
                                                    unsigned short* __restrict__ out,
                                                    int cols, int n4) {
  const int cmask4 = (cols >> 2) - 1;
  for (int i = blockIdx.x * 256 + threadIdx.x; i < n4; i += gridDim.x * 256) {
    f32x4 v = ((const f32x4*)in)[i];
    f32x4 sv = ((const f32x4*)s)[i & cmask4];
    u16x4 o;
    o.x = f2bf(v.x * sv.x); o.y = f2bf(v.y * sv.y);
    o.z = f2bf(v.z * sv.z); o.w = f2bf(v.w * sv.w);
    ((u16x4*)out)[i] = o;
  }
}

// LayerNorm: one block per row of 2048 fp32, out bf16
__global__ __launch_bounds__(256) void ln_k(const float* __restrict__ x,
                                            const float* __restrict__ g,
                                            const float* __restrict__ b,
                                            unsigned short* __restrict__ out) {
  const int tid = threadIdx.x, lane = tid & 63, wid = tid >> 6;
  const int row = blockIdx.x;
  const float* xr = x + (size_t)row * 2048;
  f32x4 a0 = ((const f32x4*)xr)[tid];
  f32x4 a1 = ((const f32x4*)xr)[tid + 256];
  float s = a0.x + a0.y + a0.z + a0.w + a1.x + a1.y + a1.z + a1.w;
  float ss = a0.x * a0.x + a0.y * a0.y + a0.z * a0.z + a0.w * a0.w +
             a1.x * a1.x + a1.y * a1.y + a1.z * a1.z + a1.w * a1.w;
#pragma unroll
  for (int m = 1; m < 64; m <<= 1) {
    s += __shfl_xor(s, m);
    ss += __shfl_xor(ss, m);
  }
  __shared__ float red[8];
  if (lane == 0) { red[wid] = s; red[4 + wid] = ss; }
  __syncthreads();
  s = red[0] + red[1] + red[2] + red[3];
  ss = red[4] + red[5] + red[6] + red[7];
  const float mu = s * (1.f / 2048.f);
  const float var = ss * (1.f / 2048.f) - mu * mu;
  const float rs = rsqrtf(var + 1e-5f);
  f32x4 g0 = ((const f32x4*)g)[tid], g1 = ((const f32x4*)g)[tid + 256];
  f32x4 b0 = ((const f32x4*)b)[tid], b1 = ((const f32x4*)b)[tid + 256];
  u16x4 o0, o1;
  o0.x = f2bf((a0.x - mu) * rs * g0.x + b0.x);
  o0.y = f2bf((a0.y - mu) * rs * g0.y + b0.y);
  o0.z = f2bf((a0.z - mu) * rs * g0.z + b0.z);
  o0.w = f2bf((a0.w - mu) * rs * g0.w + b0.w);
  o1.x = f2bf((a1.x - mu) * rs * g1.x + b1.x);
  o1.y = f2bf((a1.y - mu) * rs * g1.y + b1.y);
  o1.z = f2bf((a1.z - mu) * rs * g1.z + b1.z);
  o1.w = f2bf((a1.w - mu) * rs * g1.w + b1.w);
  unsigned short* orow = out + (size_t)row * 2048;
  *(u16x4*)(orow + 4 * tid) = o0;
  *(u16x4*)(orow + 1024 + 4 * tid) = o1;
}

// V transpose: V slice of qkv [4096][6144] -> vt [32][128][2048]
__global__ __launch_bounds__(256) void vtrans_k(const unsigned short* __restrict__ qkv,
                                                unsigned short* __restrict__ vt) {
  __shared__ unsigned short t[64][134];
  const int tid = threadIdx.x;
  const int bh = blockIdx.x >> 5, st = blockIdx.x & 31;
  const int b = bh >> 4, h = bh & 15;
  const unsigned short* vb = qkv + (size_t)(b * 2048 + st * 64) * 6144 + 4096 + h * 128;
#pragma unroll
  for (int i = 0; i < 4; ++i) {
    int f = tid + (i << 8);
    int row = f >> 4, c8 = f & 15;
    u16x8 x = *(const u16x8*)(vb + (size_t)row * 6144 + c8 * 8);
#pragma unroll
    for (int j = 0; j < 4; ++j) {
      unsigned int pk = ((unsigned int)x[2 * j + 1] << 16) | x[2 * j];
      *(unsigned int*)&t[row][c8 * 8 + 2 * j] = pk;
    }
  }
  __syncthreads();
  const int lane = tid & 63, wid = tid >> 6;
  unsigned short* ob = vt + ((size_t)bh << 18) + (st << 6);
#pragma unroll
  for (int j = 0; j < 32; ++j) {
    int d = (wid << 5) + j;
    ob[((size_t)d << 11) + lane] = t[lane][d];
  }
}

// split-K4 reduce: out = sum(bf16 parts 0..3) + bias + res (fp32)
__global__ __launch_bounds__(256) void g4red_k(const unsigned short* __restrict__ parts,
                                               const float* __restrict__ bias,
                                               const float* __restrict__ res,
                                               float* __restrict__ out, int n4) {
  const size_t PS = (size_t)4096 * 2048;
  for (int i = blockIdx.x * 256 + threadIdx.x; i < n4; i += gridDim.x * 256) {
    u16x4 a = ((const u16x4*)(parts))[i];
    u16x4 b = ((const u16x4*)(parts + PS))[i];
    u16x4 c = ((const u16x4*)(parts + 2 * PS))[i];
    u16x4 d = ((const u16x4*)(parts + 3 * PS))[i];
    f32x4 r = ((const f32x4*)res)[i];
    f32x4 bb = ((const f32x4*)bias)[i & 511];
    f32x4 o;
    o.x = bf2f(a.x) + bf2f(b.x) + bf2f(c.x) + bf2f(d.x) + r.x + bb.x;
    o.y = bf2f(a.y) + bf2f(b.y) + bf2f(c.y) + bf2f(d.y) + r.y + bb.y;
    o.z = bf2f(a.z) + bf2f(b.z) + bf2f(c.z) + bf2f(d.z) + r.z + bb.z;
    o.w = bf2f(a.w) + bf2f(b.w) + bf2f(c.w) + bf2f(d.w) + r.w + bb.w;
    ((f32x4*)out)[i] = o;
  }
}

// ---------------------------------------------------------------- GEMM params
struct GemmP {
  const unsigned short* A;
  const unsigned short* B;
  const float* bias;
  const float* res;
  float* outF;
  unsigned short* outH;
  int M, N, K;
};

// ---------------------------------------------------------------- 128^2 GEMM (2-phase)
// +bias +res -> fp32
DEVI void gemm128_body(const GemmP& p, int m0, int n0, int k0, int nk) {
  const int tid = threadIdx.x, lane = tid & 63, wid = tid >> 6;
  const int K = p.K;
  const int wr = wid >> 1, wc = wid & 1;

  __shared__ __align__(16) unsigned short sA[2][4096];
  __shared__ __align__(16) unsigned short sB[2][4096];

  const int c0 = tid, c1 = tid + 256;
  const unsigned short* gA0 = p.A + (size_t)(m0 + (c0 >> 2)) * K + k0 + ((c0 & 3) << 3);
  const unsigned short* gA1 = p.A + (size_t)(m0 + (c1 >> 2)) * K + k0 + ((c1 & 3) << 3);
  const unsigned short* gB0 = p.B + (size_t)(n0 + (c0 >> 2)) * K + k0 + ((c0 & 3) << 3);
  const unsigned short* gB1 = p.B + (size_t)(n0 + (c1 >> 2)) * K + k0 + ((c1 & 3) << 3);
  const int l0 = wid << 9, l1 = (wid << 9) + 2048;

  f32x4 acc[4][4] = {};
  const int arow = (wr << 6) + (lane & 15);
  const int brow = (wc << 6) + (lane & 15);
  const int koff = (lane >> 4) << 3;

#define STAGE128(bufi, t) do { int ko = (t) << 5;       \
    GLD16(gA0 + ko, &sA[bufi][l0]);                     \
    GLD16(gA1 + ko, &sA[bufi][l1]);                     \
    GLD16(gB0 + ko, &sB[bufi][l0]);                     \
    GLD16(gB1 + ko, &sB[bufi][l1]); } while (0)

  STAGE128(0, 0);
  __syncthreads();
  int cur = 0;
  for (int t = 0; t < nk; ++t) {
    if (t + 1 < nk) STAGE128(cur ^ 1, t + 1);
    bf16x8 af[4], bfr[4];
#pragma unroll
    for (int i = 0; i < 4; ++i)
      af[i] = *(const bf16x8*)&sA[cur][(arow + (i << 4)) * 32 + koff];
#pragma unroll
    for (int i = 0; i < 4; ++i)
      bfr[i] = *(const bf16x8*)&sB[cur][(brow + (i << 4)) * 32 + koff];
#pragma unroll
    for (int i = 0; i < 4; ++i)
#pragma unroll
      for (int j = 0; j < 4; ++j)
        acc[i][j] = __builtin_amdgcn_mfma_f32_16x16x32_bf16(af[i], bfr[j], acc[i][j], 0, 0, 0);
    __syncthreads();
    cur ^= 1;
  }
#undef STAGE128

  const int rbase = m0 + (wr << 6) + ((lane >> 4) << 2);
  const int cbase = n0 + (wc << 6) + (lane & 15);
#pragma unroll
  for (int mi = 0; mi < 4; ++mi) {
#pragma unroll
    for (int ni = 0; ni < 4; ++ni) {
      const int col = cbase + (ni << 4);
#pragma unroll
      for (int r = 0; r < 4; ++r) {
        const int row = rbase + (mi << 4) + r;
        const size_t o = (size_t)row * p.N + col;
        p.outF[o] = acc[mi][ni][r] + p.bias[col] + p.res[o];
      }
    }
  }
}

// G2: M=4096,N=2048 -> nbm=32,nbn=16. Region/XCD = 8x8.
__global__ __launch_bounds__(256) void g2_proj128(GemmP p) {
  const int x = blockIdx.x & 7, i = blockIdx.x >> 3;  // i in [0,64)
  const int bm = (x >> 1) * 8 + (i >> 3);
  const int bn = (x & 1) * 8 + (i & 7);
  gemm128_body(p, bm << 7, bn << 7, 0, p.K >> 5);
}

// ---------------------------------------------------------------- 256^2 tile common
DEVI void setup256(const GemmP& p, int m0, int n0, int k0,
                   const unsigned short*& gsA0, const unsigned short*& gsA1,
                   const unsigned short*& gsB0, const unsigned short*& gsB1) {
  const int tid = threadIdx.x;
  int r_[2], c_[2];
#pragma unroll
  for (int j = 0; j < 2; ++j) {
    int d = tid * 16 + j * 8192;
    int w = (d & 1023) ^ (((d >> 9) & 1) << 5);   // st_16x32 involution
    r_[j] = ((d >> 10) << 4) + (w >> 6);
    c_[j] = (w & 63) >> 1;
  }
  gsA0 = p.A + (size_t)(m0 + r_[0]) * p.K + k0 + c_[0];
  gsA1 = p.A + (size_t)(m0 + r_[1]) * p.K + k0 + c_[1];
  gsB0 = p.B + (size_t)(n0 + r_[0]) * p.K + k0 + c_[0];
  gsB1 = p.B + (size_t)(n0 + r_[1]) * p.K + k0 + c_[1];
}

// epilogue: EPI 0 = +bias -> bf16   2 = +bias fast-GELU -> bf16   5 = raw -> bf16
template <int EPI>
DEVI void epi256(const GemmP& p, f32x4 (&acc)[8][4], int m0, int n0,
                 unsigned short* outH) {
  const int lane = threadIdx.x & 63, wid = threadIdx.x >> 6;
  const int wr = wid >> 2, wc = wid & 3;
  const int lr = lane & 15, lk = lane >> 4;
  const int rbase = m0 + wr * 128 + (lk << 2);
  const int cbase = n0 + wc * 64 + lr;
#pragma unroll
  for (int m = 0; m < 8; ++m) {
#pragma unroll
    for (int n = 0; n < 4; ++n) {
      const int col = cbase + (n << 4);
      const float bb = (EPI == 5) ? 0.f : p.bias[col];
#pragma unroll
      for (int r = 0; r < 4; ++r) {
        const int row = rbase + (m << 4) + r;
        float v = acc[m][n][r] + bb;
        if constexpr (EPI == 2) {
          float y = 0.7978845608028654f * (v + 0.044715f * v * v * v);
          float u = __expf(2.f * y);
          v = (y > 40.f) ? v : v * (u / (u + 1.f));
        }
        outH[(size_t)row * p.N + col] = f2bf(v);
      }
    }
  }
}

// ---------------------------------------------------------------- 256^2 2-phase
template <int EPI>
DEVI void gemm2p_body(const GemmP& p, unsigned short* lds_raw, int m0, int n0,
                      int k0, int nk, unsigned short* outH) {
  const int tid = threadIdx.x, lane = tid & 63, wid = tid >> 6;
  const int wr = wid >> 2, wc = wid & 3;
  const int lr = lane & 15, lk = lane >> 4;
  const int fb = (lr * 64 + lk * 16) ^ ((lr & 8) << 2);

  const unsigned short *gsA0, *gsA1, *gsB0, *gsB1;
  setup256(p, m0, n0, k0, gsA0, gsA1, gsB0, gsB1);

#define STG2(b, kt) do { unsigned short* _d = lds_raw + ((b) << 14);     \
    GLD16(gsA0 + ((size_t)(kt) << 5), _d + (tid << 3));                  \
    GLD16(gsA1 + ((size_t)(kt) << 5), _d + 4096 + (tid << 3));           \
    GLD16(gsB0 + ((size_t)(kt) << 5), _d + 8192 + (tid << 3));           \
    GLD16(gsB1 + ((size_t)(kt) << 5), _d + 12288 + (tid << 3)); } while (0)

  f32x4 acc[8][4] = {};
  STG2(0, 0);
  __syncthreads();
  int cur = 0;
  for (int t = 0; t < nk; ++t) {
    if (t + 1 < nk) STG2(cur ^ 1, t + 1);
    const char* tA = (const char*)(lds_raw + (cur << 14));
    const char* tB = tA + 16384;
    bf16x8 a_[8], b_[4];
#pragma unroll
    for (int n = 0; n < 4; ++n)
      b_[n] = *(const bf16x8*)(tB + (((wc << 2) + n) << 10) + fb);
#pragma unroll
    for (int m = 0; m < 8; ++m)
      a_[m] = *(const bf16x8*)(tA + (((wr << 3) + m) << 10) + fb);
#pragma unroll
    for (int m = 0; m < 8; ++m)
#pragma unroll
      for (int n = 0; n < 4; ++n)
        acc[m][n] = __builtin_amdgcn_mfma_f32_16x16x32_bf16(a_[m], b_[n], acc[m][n], 0, 0, 0);
    __syncthreads();
    cur ^= 1;
  }
#undef STG2
  epi256<EPI>(p, acc, m0, n0, outH);
}

// ---------------------------------------------------------------- 256^2 BK=64 ring-2
// (round-13 structure, kept for g4 as the A/B control)
template <int EPI>
DEVI void gemmr2k64_body(const GemmP& p, unsigned short* lds_raw, int m0, int n0,
                         int k0, int nk64, unsigned short* outH) {
  const int tid = threadIdx.x, lane = tid & 63, wid = tid >> 6;
  const int wr = wid >> 2, wc = wid & 3;
  const int lr = lane & 15, lk = lane >> 4;
  const int fb = (lr * 64 + lk * 16) ^ ((lr & 8) << 2);

  const unsigned short *gsA0, *gsA1, *gsB0, *gsB1;
  setup256(p, m0, n0, k0, gsA0, gsA1, gsB0, gsB1);

#define STG64(bufi, kt) do { unsigned short* _d = lds_raw + ((bufi) << 15);  \
    int _ko = (kt) << 6;                                                     \
    GLD16(gsA0 + _ko,      _d + (tid << 3));                                 \
    GLD16(gsA1 + _ko,      _d + 4096 + (tid << 3));                          \
    GLD16(gsA0 + _ko + 32, _d + 8192 + (tid << 3));                          \
    GLD16(gsA1 + _ko + 32, _d + 12288 + (tid << 3));                         \
    GLD16(gsB0 + _ko,      _d + 16384 + (tid << 3));                         \
    GLD16(gsB1 + _ko,      _d + 20480 + (tid << 3));                         \
    GLD16(gsB0 + _ko + 32, _d + 24576 + (tid << 3));                         \
    GLD16(gsB1 + _ko + 32, _d + 28672 + (tid << 3)); } while (0)

  f32x4 acc[8][4] = {};
  STG64(0, 0);
  asm volatile("s_waitcnt vmcnt(0)" ::: "memory");
  __builtin_amdgcn_s_barrier();
  asm volatile("" ::: "memory");

  for (int t = 0; t < nk64; ++t) {
    if (t + 1 < nk64) STG64((t + 1) & 1, t + 1);
    const char* base = (const char*)(lds_raw + ((t & 1) << 15));
#pragma unroll
    for (int s = 0; s < 2; ++s) {
      const char* tA = base + s * 16384;
      const char* tB = base + 32768 + s * 16384;
      bf16x8 a_[8], b_[4];
#pragma unroll
      for (int n = 0; n < 4; ++n)
        b_[n] = *(const bf16x8*)(tB + (((wc << 2) + n) << 10) + fb);
#pragma unroll
      for (int m = 0; m < 8; ++m)
        a_[m] = *(const bf16x8*)(tA + (((wr << 3) + m) << 10) + fb);
      __builtin_amdgcn_s_setprio(1);
#pragma unroll
      for (int m = 0; m < 8; ++m)
#pragma unroll
        for (int n = 0; n < 4; ++n)
          acc[m][n] = __builtin_amdgcn_mfma_f32_16x16x32_bf16(a_[m], b_[n], acc[m][n], 0, 0, 0);
      __builtin_amdgcn_s_setprio(0);
    }
    if (t + 1 < nk64) asm volatile("s_waitcnt vmcnt(0)" ::: "memory");
    __builtin_amdgcn_s_barrier();
    asm volatile("" ::: "memory");
  }
#undef STG64
  epi256<EPI>(p, acc, m0, n0, outH);
}

// ---------------------------------------------------------------- 256^2 8-PHASE
// Faithful m201-template port: BK=64 K-tiles, 2 x 64KB buffers, half-tiles
// {A0,A1,B0,B1} of 128x64 (2 gload_lds each), per-phase one C-quadrant
// (16 MFMA) with 2 barriers; A/B frags register-cached across phases.
// Stage slots WAR-audited: each half overwritten >=1 full barrier after its
// last reader. vmcnt(4)@ph4, vmcnt(8)@ph8 (counted, never 0 in steady state).
template <int EPI>
DEVI void gemm8p_body(const GemmP& p, unsigned short* lds_raw, int m0, int n0,
                      int k0, int nt, unsigned short* outH) {
  const int tid = threadIdx.x, lane = tid & 63, wid = tid >> 6;
  const int wr = wid >> 2, wc = wid & 3;
  const int lr = lane & 15, lk = lane >> 4;
  const int fb = (lr * 64 + lk * 16) ^ ((lr & 8) << 2);
  char* Lc = (char*)lds_raw;

  const unsigned short *gsA0, *gsA1, *gsB0, *gsB1;
  setup256(p, m0, n0, k0, gsA0, gsA1, gsB0, gsB1);

  // stage one half-tile (128x64) of K-tile tt into buffer bufb, half h:
  // h: 0=A0(gsA0) 1=A1(gsA1) 2=B0(gsB0) 3=B1(gsB1)
#define STGH(bufb, h, gp, tt) do {                                        \
    char* _d = Lc + ((bufb) << 16) + ((h) << 14) + tid * 16;              \
    GLD16((gp) + ((size_t)(tt) << 6),      _d);                           \
    GLD16((gp) + ((size_t)(tt) << 6) + 32, _d + 8192); } while (0)

  const char* Abase = Lc + (wr << 14);                 // this wave's A half
  const char* Bbase = Lc + 32768 + ((wc >> 1) << 14);  // this wave's B half
  const int bg = (wc & 1) << 2;                        // B row-group base

#define RDA(dst, bufb, mq) do {                                           \
    const char* _a = Abase + ((bufb) << 16);                              \
    _Pragma("unroll") for (int mi = 0; mi < 4; ++mi)                      \
      _Pragma("unroll") for (int ks = 0; ks < 2; ++ks)                    \
        dst[mi][ks] = *(const bf16x8*)(_a + ks * 8192 +                   \
                        (((mq) * 4 + mi) << 10) + fb); } while (0)
#define RDB(bufb, nq) do {                                                \
    const char* _b = Bbase + ((bufb) << 16);                              \
    _Pragma("unroll") for (int ni = 0; ni < 2; ++ni)                      \
      _Pragma("unroll") for (int ks = 0; ks < 2; ++ks)                    \
        bq[ni][ks] = *(const bf16x8*)(_b + ks * 8192 +                    \
                        ((bg + (nq) * 2 + ni) << 10) + fb); } while (0)
#define MFMAQ(av, mq, nq) do {                                            \
    __builtin_amdgcn_s_setprio(1);                                        \
    _Pragma("unroll") for (int mi = 0; mi < 4; ++mi)                      \
      _Pragma("unroll") for (int ni = 0; ni < 2; ++ni)                    \
        _Pragma("unroll") for (int ks = 0; ks < 2; ++ks)                  \
          acc[(mq) * 4 + mi][(nq) * 2 + ni] =                             \
            __builtin_amdgcn_mfma_f32_16x16x32_bf16(                      \
              av[mi][ks], bq[ni][ks], acc[(mq) * 4 + mi][(nq) * 2 + ni],  \
              0, 0, 0);                                                   \
    __builtin_amdgcn_s_setprio(0); } while (0)
#define BAR __builtin_amdgcn_s_barrier()
#define LGKM0 do { asm volatile("s_waitcnt lgkmcnt(0)" ::: "memory");     \
                   __builtin_amdgcn_sched_barrier(0); } while (0)

  f32x4 acc[8][4] = {};
  bf16x8 aq[4][2], a2[4][2], bq[2][2];

  // prologue: tiles 0 -> buf0, 1 -> buf1 (full)
  STGH(0, 0, gsA0, 0); STGH(0, 1, gsA1, 0); STGH(0, 2, gsB0, 0); STGH(0, 3, gsB1, 0);
  STGH(1, 0, gsA0, 1); STGH(1, 1, gsA1, 1); STGH(1, 2, gsB0, 1); STGH(1, 3, gsB1, 1);
  asm volatile("s_waitcnt vmcnt(0)" ::: "memory");
  BAR;
  asm volatile("" ::: "memory");

  const int NIT = nt >> 1;   // nt = K/64 tiles, 2 per iter
  for (int i = 0; i < NIT; ++i) {
    const int T = 2 * i;
    const bool G2 = (T + 2 < nt), G3 = (T + 3 < nt);
    // ---- buf0 = tile T ----
    // ph1: reads A-m0, B-n0
    RDA(aq, 0, 0); RDB(0, 0);
    BAR; LGKM0; MFMAQ(aq, 0, 0); BAR;
    // ph2: reads A-m1 (B cached)
    RDA(a2, 0, 1);
    BAR; LGKM0; MFMAQ(a2, 1, 0); BAR;
    // ph3: reads B-n1 (A cached); stage buf0.A0 <- T+2
    RDB(0, 1);
    if (G2) STGH(0, 0, gsA0, T + 2);
    BAR; LGKM0; MFMAQ(aq, 0, 1); BAR;
    // ph4: stage buf0.A1 <- T+2; vmcnt(4)
    if (G2) STGH(0, 1, gsA1, T + 2);
    asm volatile("s_waitcnt vmcnt(4)" ::: "memory");
    BAR; MFMAQ(a2, 1, 1); BAR;
    // ---- buf1 = tile T+1 ----
    // ph5: reads A-m0, B-n0; stage buf0.B0 <- T+2
    RDA(aq, 1, 0); RDB(1, 0);
    if (G2) STGH(0, 2, gsB0, T + 2);
    BAR; LGKM0; MFMAQ(aq, 0, 0); BAR;
    // ph6: reads A-m1; stage buf0.B1 <- T+2
    RDA(a2, 1, 1);
    if (G2) STGH(0, 3, gsB1, T + 2);
    BAR; LGKM0; MFMAQ(a2, 1, 0); BAR;
    // ph7: reads B-n1; stage buf1.A0,A1 <- T+3
    RDB(1, 1);
    if (G3) { STGH(1, 0, gsA0, T + 3); STGH(1, 1, gsA1, T + 3); }
    BAR; LGKM0; MFMAQ(aq, 0, 1); BAR;
    // ph8: stage buf1.B0,B1 <- T+3; vmcnt(8)
    if (G3) { STGH(1, 2, gsB0, T + 3); STGH(1, 3, gsB1, T + 3); }
    asm volatile("s_waitcnt vmcnt(8)" ::: "memory");
    BAR; MFMAQ(a2, 1, 1); BAR;
    asm volatile("" ::: "memory");
  }
#undef STGH
#undef RDA
#undef RDB
#undef MFMAQ
#undef BAR
#undef LGKM0
  epi256<EPI>(p, acc, m0, n0, outH);
}

// G1 (256^2 2-phase): M=4096,N=6144 -> nbm=16,nbn=24; region 8x6 per XCD.
__global__ __launch_bounds__(512, 2) void g1_qkv256(GemmP p) {
  extern __shared__ unsigned short lds_raw[];
  const int x = blockIdx.x & 7, i = blockIdx.x >> 3;   // i in [0,48)
  const int bm = (x & 1) * 8 + (i & 7);
  const int bn = (x >> 1) * 6 + (i >> 3);
  gemm2p_body<0>(p, lds_raw, bm << 8, bn << 8, 0, p.K >> 5, p.outH);
}
// G3 8-phase (128KB LDS, 1 block/CU). The m201-template A/B arm.
__global__ __launch_bounds__(512, 1) void g3_fc8p(GemmP p) {
  extern __shared__ unsigned short lds_raw[];
  const int x = blockIdx.x & 7, i = blockIdx.x >> 3;   // i in [0,64)
  const int bm = (x & 1) * 8 + (i & 7);
  const int bn = (x >> 1) * 8 + (i >> 3);
  gemm8p_body<2>(p, lds_raw, bm << 8, bn << 8, 0, 32, p.outH);
}
// G4 BK=64 ring-2, split-K4 (control arm)
__global__ __launch_bounds__(512, 1) void g4_sk64(GemmP p) {
  extern __shared__ unsigned short lds_raw[];
  const int x = blockIdx.x & 7, i = blockIdx.x >> 3;   // i in [0,64)
  const int ks = x & 3;
  const int bm = (x >> 2) * 8 + (i >> 3);
  const int bn = i & 7;
  unsigned short* outH = p.outH + (size_t)ks * 4096 * 2048;
  gemmr2k64_body<5>(p, lds_raw, bm << 8, bn << 8, ks << 11, 32, outH);
}

// ---------------------------------------------------------------- attention
// QBLK=128 (8 waves). Q,K from unified qkv [4096][6144]; V^T [32][128][2048].
__global__ __launch_bounds__(512) void attn_k(const unsigned short* __restrict__ qkv,
                                              const unsigned short* __restrict__ Vt,
                                              unsigned short* __restrict__ O) {
  const int tid = threadIdx.x, lane = tid & 63, wid = tid >> 6;
  const int bid = blockIdx.x;                 // grid = 512
  const int pos = bid >> 3;                   // [0,64)
  const int bh = (bid & 7) * 4 + (pos >> 4);
  const int qt = pos & 15;
  const int q0 = qt * 128 + wid * 16;
  const int b = bh >> 4, h = bh & 15;
  const float C = 0.08838834764831845f * 1.4426950408889634f;  // scale*log2e

  __shared__ __align__(16) unsigned short sK[64 * 128];
  __shared__ __align__(16) unsigned short sV[128 * 64];
  __shared__ __align__(16) unsigned short sP[8][16 * 72];

  const unsigned short* Qb = qkv + (size_t)(b * 2048) * 6144 + h * 128;
  const unsigned short* Kb = qkv + (size_t)(b * 2048) * 6144 + 2048 + h * 128;
  const unsigned short* Vb = Vt + ((size_t)bh << 18);

  bf16x8 qf[4];
  {
    const unsigned short* qp = Qb + (size_t)(q0 + (lane & 15)) * 6144 + ((lane >> 4) << 3);
#pragma unroll
    for (int kk = 0; kk < 4; ++kk) qf[kk] = *(const bf16x8*)(qp + kk * 32);
  }

  int koffs[2], voffs[2];
#pragma unroll
  for (int i = 0; i < 2; ++i) {
    const int c = tid + (i << 9);
    const int kv = c >> 4, jj = c & 15;
    const int js = (jj & 8) | ((jj ^ kv) & 7);
    koffs[i] = kv * 6144 + (js << 3);
    const int d = c >> 3, j2 = c & 7;
    const int js2 = j2 ^ (d & 7);
    voffs[i] = d * 2048 + (js2 << 3);
  }
  u16x8 kreg[2], vreg[2];
  auto PREF = [&](int kt) {
    const int kv0 = kt << 6;
    const unsigned short* kb = Kb + (size_t)kv0 * 6144;
#pragma unroll
    for (int i = 0; i < 2; ++i) {
      kreg[i] = *(const u16x8*)(kb + koffs[i]);
      vreg[i] = *(const u16x8*)(Vb + kv0 + voffs[i]);
    }
  };

  f32x4 oacc[8] = {};
  float mrun = -3e38f, lrun = 0.f;
  PREF(0);

  for (int kt = 0; kt < 32; ++kt) {
#pragma unroll
    for (int i = 0; i < 2; ++i) {
      const int c8 = (tid + (i << 9)) << 3;
      *(u16x8*)&sK[c8] = kreg[i];
      *(u16x8*)&sV[c8] = vreg[i];
    }
    __syncthreads();
    if (kt + 1 < 32) PREF(kt + 1);

    f32x4 sc[4] = {};
    __builtin_amdgcn_s_setprio(1);
#pragma unroll
    for (int ti = 0; ti < 4; ++ti) {
#pragma unroll
      for (int kk = 0; kk < 4; ++kk) {
        const int row = (ti << 4) + (lane & 15);
        int bo = (row << 8) + (kk << 6) + ((lane >> 4) << 4);
        bo ^= (row & 7) << 4;
        bf16x8 kf = *(const bf16x8*)((const char*)sK + bo);
        sc[ti] = __builtin_amdgcn_mfma_f32_16x16x32_bf16(kf, qf[kk], sc[ti], 0, 0, 0);
      }
    }
    __builtin_amdgcn_s_setprio(0);

    float pv[16];
    float mx = -3e38f;
#pragma unroll
    for (int ti = 0; ti < 4; ++ti)
#pragma unroll
      for (int r = 0; r < 4; ++r) {
        float x = sc[ti][r];         // raw scores
        pv[(ti << 2) + r] = x;
        mx = fmaxf(mx, x);
      }
    mx = fmaxf(mx, __shfl_xor(mx, 16));
    mx = fmaxf(mx, __shfl_xor(mx, 32));

    float corr = 1.f;
    if (!__all(mx - mrun <= 90.50966799f)) {   // 8 / scale
      const float mnew = fmaxf(mrun, mx);
      corr = exp2f((mrun - mnew) * C);
      mrun = mnew;
      float fr[4];
#pragma unroll
      for (int r = 0; r < 4; ++r) fr[r] = __shfl(corr, ((lane >> 4) << 2) + r);
#pragma unroll
      for (int di = 0; di < 8; ++di)
#pragma unroll
        for (int r = 0; r < 4; ++r) oacc[di][r] *= fr[r];
    }
    float psum = 0.f;
#pragma unroll
    for (int i2 = 0; i2 < 16; ++i2) {
      float e = exp2f((pv[i2] - mrun) * C);
      pv[i2] = e;
      psum += e;
    }
    psum += __shfl_xor(psum, 16);
    psum += __shfl_xor(psum, 32);
    lrun = lrun * corr + psum;

    unsigned short* prow = &sP[wid][(lane & 15) * 72];
#pragma unroll
    for (int ti = 0; ti < 4; ++ti) {
      u16x4 w4;
      w4.x = f2bf(pv[(ti << 2) + 0]);
      w4.y = f2bf(pv[(ti << 2) + 1]);
      w4.z = f2bf(pv[(ti << 2) + 2]);
      w4.w = f2bf(pv[(ti << 2) + 3]);
      *(u16x4*)&prow[(ti << 4) + ((lane >> 4) << 2)] = w4;
    }

    bf16x8 pfA, pfB;
    {
      const char* pb = (const char*)&sP[wid][0] + (lane & 15) * 144 + ((lane >> 4) << 4);
      pfA = *(const bf16x8*)(pb);
      pfB = *(const bf16x8*)(pb + 64);
    }
    __builtin_amdgcn_s_setprio(1);
#pragma unroll
    for (int di = 0; di < 8; ++di) {
#pragma unroll
      for (int ks = 0; ks < 2; ++ks) {
        const int dr = (di << 4) + (lane & 15);
        int bo = (dr << 7) + (ks << 6) + ((lane >> 4) << 4);
        bo ^= (dr & 7) << 4;
        bf16x8 vf = *(const bf16x8*)((const char*)sV + bo);
        oacc[di] = __builtin_amdgcn_mfma_f32_16x16x32_bf16(ks ? pfB : pfA, vf, oacc[di], 0, 0, 0);
      }
    }
    __builtin_amdgcn_s_setprio(0);
    __syncthreads();
  }

  float il[4];
#pragma unroll
  for (int r = 0; r < 4; ++r) il[r] = 1.f / __shfl(lrun, ((lane >> 4) << 2) + r);
  const size_t obase = ((size_t)(b * 2048 + q0)) * 2048 + h * 128;
#pragma unroll
  for (int di = 0; di < 8; ++di)
#pragma unroll
    for (int r = 0; r < 4; ++r) {
      const size_t o = obase + (size_t)(((lane >> 4) << 2) + r) * 2048 + (di << 4) + (lane & 15);
      O[o] = f2bf(oacc[di][r] * il[r]);
    }
}

// ---------------------------------------------------------------- launch

extern "C" void kernel_launch(void* const* d_in, const int* in_sizes, int n_in,
                              void* d_out, int out_size, void* d_ws, size_t ws_size,
                              hipStream_t stream) {
  (void)in_sizes; (void)n_in; (void)out_size; (void)ws_size;
  const float* hidden = (const float*)d_in[0];
  const float* ln1_g = (const float*)d_in[1];
  const float* ln1_b = (const float*)d_in[2];
  const float* w_qkv = (const float*)d_in[3];
  const float* b_qkv = (const float*)d_in[4];
  const float* apv = (const float*)d_in[5];
  const float* apg = (const float*)d_in[6];
  const float* apb = (const float*)d_in[7];
  // d_in[8] emotion_bias: softmax-invariant -> dropped (exact)
  const float* ln2_g = (const float*)d_in[9];
  const float* ln2_b = (const float*)d_in[10];
  const float* w_fc = (const float*)d_in[11];
  const float* b_fc = (const float*)d_in[12];
  const float* mpv = (const float*)d_in[13];
  const float* mpg = (const float*)d_in[14];
  const float* mpb = (const float*)d_in[15];

  char* w = (char*)d_ws;
  const size_t MBs = 1ull << 20;
  unsigned short* xln = (unsigned short*)(w + 0);
  float* hidden2 = (float*)(w + 0);
  unsigned short* vtbuf = (unsigned short*)(w + 32 * MBs);
  unsigned short* hbuf = (unsigned short*)(w + 32 * MBs);
  unsigned short* qkv = (unsigned short*)(w + 96 * MBs);
  unsigned short* wfc_bf = (unsigned short*)(w + 96 * MBs);
  unsigned short* partH = (unsigned short*)(w + 96 * MBs);   // 4x16MB bf16 partials
  unsigned short* xln2 = (unsigned short*)(w + 128 * MBs);
  unsigned short* attn_out = (unsigned short*)(w + 144 * MBs);
  unsigned short* wqkv_bf = (unsigned short*)(w + 160 * MBs);
  unsigned short* w2_bf = (unsigned short*)(w + 160 * MBs);
  unsigned short* wproj_bf = (unsigned short*)(w + 192 * MBs);
  float* s_attn = (float*)(w + 200 * MBs);
  float* s_mlp = (float*)(w + 200 * MBs + 32768);
  float* part_attn = (float*)(w + 201 * MBs);
  float* part_mlp = (float*)(w + 202 * MBs);

  hipFuncSetAttribute((const void*)g1_qkv256, hipFuncAttributeMaxDynamicSharedMemorySize, 65536);
  hipFuncSetAttribute((const void*)g3_fc8p, hipFuncAttributeMaxDynamicSharedMemorySize, 131072);
  hipFuncSetAttribute((const void*)g4_sk64, hipFuncAttributeMaxDynamicSharedMemorySize, 131072);

  // weight prep
  cast_k<<<2048, 256, 0, stream>>>(w_qkv, wqkv_bf, (6144 * 2048) / 4);
  colnorm1_k<<<dim3(4, 32), 256, 0, stream>>>(apv, part_attn, 2048);
  colnorm2_k<<<8, 256, 0, stream>>>(part_attn, apg, s_attn, 2048, 32);
  scale_cast_k<<<2048, 256, 0, stream>>>(apv, s_attn, wproj_bf, 2048, (2048 * 2048) / 4);
  colnorm1_k<<<dim3(16, 32), 256, 0, stream>>>(mpv, part_mlp, 8192);
  colnorm2_k<<<32, 256, 0, stream>>>(part_mlp, mpg, s_mlp, 8192, 32);

  // LN1 -> xln (bf16)
  ln_k<<<4096, 256, 0, stream>>>(hidden, ln1_g, ln1_b, xln);

  // GEMM1 (256^2 2-phase): qkv = xln @ w_qkv^T + b
  GemmP p1 = {xln, wqkv_bf, b_qkv, nullptr, nullptr, qkv, 4096, 6144, 2048};
  g1_qkv256<<<384, 512, 65536, stream>>>(p1);

  // V slice of qkv -> V^T
  vtrans_k<<<1024, 256, 0, stream>>>(qkv, vtbuf);

  // attention (QBLK=128, 8 waves) -> attn_out
  attn_k<<<512, 512, 0, stream>>>(qkv, vtbuf, attn_out);

  // weight casts for MLP
  cast_k<<<2048, 256, 0, stream>>>(w_fc, wfc_bf, (8192 * 2048) / 4);
  scale_cast_k<<<4096, 256, 0, stream>>>(mpv, s_mlp, w2_bf, 8192, (2048 * 8192) / 4);

  // GEMM2 (128^2): hidden2 = attn_out @ w_proj^T + b + hidden
  GemmP p2 = {attn_out, wproj_bf, apb, hidden, hidden2, nullptr, 4096, 2048, 2048};
  g2_proj128<<<512, 256, 0, stream>>>(p2);

  // LN2 -> xln2
  ln_k<<<4096, 256, 0, stream>>>(hidden2, ln2_g, ln2_b, xln2);

  // GEMM3 (8-phase, m201 template) -- A/B vs g4's ring-2
  GemmP p3 = {xln2, wfc_bf, b_fc, nullptr, nullptr, hbuf, 4096, 8192, 2048};
  g3_fc8p<<<512, 512, 131072, stream>>>(p3);

  // GEMM4 (BK=64 ring-2, split-K4) -> fused reduce
  GemmP p4 = {hbuf, w2_bf, mpb, nullptr, nullptr, partH, 4096, 2048, 8192};
  g4_sk64<<<512, 512, 131072, stream>>>(p4);
  g4red_k<<<2048, 256, 0, stream>>>(partH, mpb, hidden2, (float*)d_out,
                                    (4096 * 2048) / 4);
}

// Round 15
// 727.972 us; speedup vs baseline: 1.0490x; 1.0073x over previous
//
#include <hip/hip_runtime.h>
#include <hip/hip_bf16.h>

#define DEVI __device__ __forceinline__

typedef __attribute__((ext_vector_type(8))) __bf16 bf16x8;
typedef __attribute__((ext_vector_type(4))) float f32x4;
typedef __attribute__((ext_vector_type(4))) unsigned short u16x4;
typedef __attribute__((ext_vector_type(8))) unsigned short u16x8;

DEVI unsigned short f2bf(float f) {
  unsigned int u = __float_as_uint(f);
  u += 0x7FFFu + ((u >> 16) & 1u);   // RNE
  return (unsigned short)(u >> 16);
}
DEVI float bf2f(unsigned short u) {
  return __uint_as_float(((unsigned int)u) << 16);
}

#define GLD16(g, l) __builtin_amdgcn_global_load_lds(                      \
    (const __attribute__((address_space(1))) void*)(g),                    \
    (__attribute__((address_space(3))) void*)(l), 16, 0, 0)

// ---------------------------------------------------------------- fused-prep bodies

DEVI void cast_body(int blk, int nblk, const float* __restrict__ in,
                    unsigned short* __restrict__ out, int n4) {
  for (int i = blk * 256 + threadIdx.x; i < n4; i += nblk * 256) {
    f32x4 v = ((const f32x4*)in)[i];
    u16x4 o;
    o.x = f2bf(v.x); o.y = f2bf(v.y); o.z = f2bf(v.z); o.w = f2bf(v.w);
    ((u16x4*)out)[i] = o;
  }
}

DEVI void scale_cast_body(int blk, int nblk, const float* __restrict__ in,
                          const float* __restrict__ s,
                          unsigned short* __restrict__ out, int cols, int n4) {
  const int cmask4 = (cols >> 2) - 1;
  for (int i = blk * 256 + threadIdx.x; i < n4; i += nblk * 256) {
    f32x4 v = ((const f32x4*)in)[i];
    f32x4 sv = ((const f32x4*)s)[i & cmask4];
    u16x4 o;
    o.x = f2bf(v.x * sv.x); o.y = f2bf(v.y * sv.y);
    o.z = f2bf(v.z * sv.z); o.w = f2bf(v.w * sv.w);
    ((u16x4*)out)[i] = o;
  }
}

DEVI void colnorm1_body(int bx, int by, const float* __restrict__ v,
                        float* __restrict__ part, int cols) {
  const int tid = threadIdx.x;
  const int g = tid & 127;
  const int s = tid >> 7;
  const int c0 = bx * 512;
  const int r0 = by * 64 + s * 32;
  const float* base = v + (size_t)r0 * cols + c0 + g * 4;
  f32x4 acc = {};
#pragma unroll 4
  for (int i = 0; i < 32; ++i) {
    f32x4 x = *(const f32x4*)(base + (size_t)i * cols);
    acc.x += x.x * x.x; acc.y += x.y * x.y;
    acc.z += x.z * x.z; acc.w += x.w * x.w;
  }
  __shared__ f32x4 red1[256];
  red1[tid] = acc;
  __syncthreads();
  if (s == 0) {
    f32x4 a = red1[tid], b = red1[tid + 128];
    f32x4 o;
    o.x = a.x + b.x; o.y = a.y + b.y; o.z = a.z + b.z; o.w = a.w + b.w;
    *(f32x4*)(part + (size_t)by * cols + c0 + g * 4) = o;
  }
}

DEVI void colnorm2_body(int blk, const float* __restrict__ part,
                        const float* __restrict__ g, float* __restrict__ s,
                        int cols, int nrc) {
  const int c = blk * 256 + threadIdx.x;
  float acc = 0.f;
  for (int i = 0; i < nrc; ++i) acc += part[(size_t)i * cols + c];
  s[c] = g[c] * rsqrtf(acc);
}

DEVI void ln_body(int row, const float* __restrict__ x, const float* __restrict__ g,
                  const float* __restrict__ b, unsigned short* __restrict__ out) {
  const int tid = threadIdx.x, lane = tid & 63, wid = tid >> 6;
  const float* xr = x + (size_t)row * 2048;
  f32x4 a0 = ((const f32x4*)xr)[tid];
  f32x4 a1 = ((const f32x4*)xr)[tid + 256];
  float s = a0.x + a0.y + a0.z + a0.w + a1.x + a1.y + a1.z + a1.w;
  float ss = a0.x * a0.x + a0.y * a0.y + a0.z * a0.z + a0.w * a0.w +
             a1.x * a1.x + a1.y * a1.y + a1.z * a1.z + a1.w * a1.w;
#pragma unroll
  for (int m = 1; m < 64; m <<= 1) {
    s += __shfl_xor(s, m);
    ss += __shfl_xor(ss, m);
  }
  __shared__ float red2[8];
  if (lane == 0) { red2[wid] = s; red2[4 + wid] = ss; }
  __syncthreads();
  s = red2[0] + red2[1] + red2[2] + red2[3];
  ss = red2[4] + red2[5] + red2[6] + red2[7];
  const float mu = s * (1.f / 2048.f);
  const float var = ss * (1.f / 2048.f) - mu * mu;
  const float rs = rsqrtf(var + 1e-5f);
  f32x4 g0 = ((const f32x4*)g)[tid], g1 = ((const f32x4*)g)[tid + 256];
  f32x4 b0 = ((const f32x4*)b)[tid], b1 = ((const f32x4*)b)[tid + 256];
  u16x4 o0, o1;
  o0.x = f2bf((a0.x - mu) * rs * g0.x + b0.x);
  o0.y = f2bf((a0.y - mu) * rs * g0.y + b0.y);
  o0.z = f2bf((a0.z - mu) * rs * g0.z + b0.z);
  o0.w = f2bf((a0.w - mu) * rs * g0.w + b0.w);
  o1.x = f2bf((a1.x - mu) * rs * g1.x + b1.x);
  o1.y = f2bf((a1.y - mu) * rs * g1.y + b1.y);
  o1.z = f2bf((a1.z - mu) * rs * g1.z + b1.z);
  o1.w = f2bf((a1.w - mu) * rs * g1.w + b1.w);
  unsigned short* orow = out + (size_t)row * 2048;
  *(u16x4*)(orow + 4 * tid) = o0;
  *(u16x4*)(orow + 1024 + 4 * tid) = o1;
}

DEVI void vtrans_body(int bid, const unsigned short* __restrict__ qkv,
                      unsigned short* __restrict__ vt) {
  __shared__ unsigned short tsh[64][134];
  const int tid = threadIdx.x;
  const int bh = bid >> 5, st = bid & 31;
  const int b = bh >> 4, h = bh & 15;
  const unsigned short* vb = qkv + (size_t)(b * 2048 + st * 64) * 6144 + 4096 + h * 128;
#pragma unroll
  for (int i = 0; i < 4; ++i) {
    int f = tid + (i << 8);
    int row = f >> 4, c8 = f & 15;
    u16x8 x = *(const u16x8*)(vb + (size_t)row * 6144 + c8 * 8);
#pragma unroll
    for (int j = 0; j < 4; ++j) {
      unsigned int pk = ((unsigned int)x[2 * j + 1] << 16) | x[2 * j];
      *(unsigned int*)&tsh[row][c8 * 8 + 2 * j] = pk;
    }
  }
  __syncthreads();
  const int lane = tid & 63, wid = tid >> 6;
  unsigned short* ob = vt + ((size_t)bh << 18) + (st << 6);
#pragma unroll
  for (int j = 0; j < 32; ++j) {
    int d = (wid << 5) + j;
    ob[((size_t)d << 11) + lane] = tsh[lane][d];
  }
}

// combine two kv-half attention partials -> normalized bf16 output
DEVI void combine_body(int blk, const unsigned short* __restrict__ po,
                       const float* __restrict__ marr, const float* __restrict__ larr,
                       unsigned short* __restrict__ O) {
  const size_t PS = (size_t)32 * 2048 * 128;
  const float C = 0.08838834764831845f * 1.4426950408889634f;
  const int tid = threadIdx.x;
  const int row = blk * 32 + (tid >> 3);      // global row = bh*2048 + q
  const int bh = row >> 11, q = row & 2047;
  const int d0 = (tid & 7) * 16;
  const float m0 = marr[row], m1 = marr[65536 + row];
  const float l0 = larr[row], l1 = larr[65536 + row];
  const float M = fmaxf(m0, m1);
  const float w0 = exp2f((m0 - M) * C), w1 = exp2f((m1 - M) * C);
  const float inv = 1.f / (l0 * w0 + l1 * w1);
  const float s0 = w0 * inv, s1 = w1 * inv;
  const unsigned short* p0 = po + ((size_t)row << 7) + d0;
  const unsigned short* p1 = p0 + PS;
  const int b = bh >> 4, h = bh & 15;
  unsigned short* ob = O + ((size_t)(b * 2048 + q)) * 2048 + h * 128 + d0;
#pragma unroll
  for (int c = 0; c < 2; ++c) {
    u16x8 a = *(const u16x8*)(p0 + c * 8);
    u16x8 bb = *(const u16x8*)(p1 + c * 8);
    u16x8 o;
#pragma unroll
    for (int j = 0; j < 8; ++j)
      o[j] = f2bf(bf2f(a[j]) * s0 + bf2f(bb[j]) * s1);
    *(u16x8*)(ob + c * 8) = o;
  }
}

// ---------------------------------------------------------------- fused launchers

__global__ __launch_bounds__(256) void prep1_k(const float* wq, unsigned short* wqb,
                                               const float* apv, float* part_a,
                                               const float* mpv, float* part_m,
                                               const float* hid, const float* g1v,
                                               const float* b1v, unsigned short* xln) {
  const int blk = blockIdx.x;
  if (blk < 2048)       cast_body(blk, 2048, wq, wqb, (6144 * 2048) / 4);
  else if (blk < 2176) { int i = blk - 2048; colnorm1_body(i & 3, i >> 2, apv, part_a, 2048); }
  else if (blk < 2688) { int i = blk - 2176; colnorm1_body(i & 15, i >> 4, mpv, part_m, 8192); }
  else                  ln_body(blk - 2688, hid, g1v, b1v, xln);
}

__global__ __launch_bounds__(256) void prep2_k(const float* part_a, const float* apg,
                                               float* s_attn, const float* part_m,
                                               const float* mpg, float* s_mlp) {
  const int blk = blockIdx.x;
  if (blk < 8) colnorm2_body(blk, part_a, apg, s_attn, 2048, 32);
  else         colnorm2_body(blk - 8, part_m, mpg, s_mlp, 8192, 32);
}

__global__ __launch_bounds__(256) void mid_k(const unsigned short* qkv,
                                             unsigned short* vt,
                                             const float* apv, const float* s_attn,
                                             unsigned short* wproj_bf) {
  const int blk = blockIdx.x;
  if (blk < 1024) vtrans_body(blk, qkv, vt);
  else            scale_cast_body(blk - 1024, 2048, apv, s_attn, wproj_bf, 2048,
                                  (2048 * 2048) / 4);
}

__global__ __launch_bounds__(256) void post_k(const unsigned short* po,
                                              const float* marr, const float* larr,
                                              unsigned short* attn_out,
                                              const float* wfc, unsigned short* wfc_bf,
                                              const float* mpv, const float* s_mlp,
                                              unsigned short* w2_bf) {
  const int blk = blockIdx.x;
  if (blk < 2048)       combine_body(blk, po, marr, larr, attn_out);
  else if (blk < 4096)  cast_body(blk - 2048, 2048, wfc, wfc_bf, (8192 * 2048) / 4);
  else                  scale_cast_body(blk - 4096, 2048, mpv, s_mlp, w2_bf, 8192,
                                        (2048 * 8192) / 4);
}

// LN2 standalone
__global__ __launch_bounds__(256) void ln_k(const float* __restrict__ x,
                                            const float* __restrict__ g,
                                            const float* __restrict__ b,
                                            unsigned short* __restrict__ out) {
  ln_body(blockIdx.x, x, g, b, out);
}

// split-K4 reduce: out = sum(bf16 parts 0..3) + bias + res (fp32)
__global__ __launch_bounds__(256) void g4red_k(const unsigned short* __restrict__ parts,
                                               const float* __restrict__ bias,
                                               const float* __restrict__ res,
                                               float* __restrict__ out, int n4) {
  const size_t PS = (size_t)4096 * 2048;
  for (int i = blockIdx.x * 256 + threadIdx.x; i < n4; i += gridDim.x * 256) {
    u16x4 a = ((const u16x4*)(parts))[i];
    u16x4 b = ((const u16x4*)(parts + PS))[i];
    u16x4 c = ((const u16x4*)(parts + 2 * PS))[i];
    u16x4 d = ((const u16x4*)(parts + 3 * PS))[i];
    f32x4 r = ((const f32x4*)res)[i];
    f32x4 bb = ((const f32x4*)bias)[i & 511];
    f32x4 o;
    o.x = bf2f(a.x) + bf2f(b.x) + bf2f(c.x) + bf2f(d.x) + r.x + bb.x;
    o.y = bf2f(a.y) + bf2f(b.y) + bf2f(c.y) + bf2f(d.y) + r.y + bb.y;
    o.z = bf2f(a.z) + bf2f(b.z) + bf2f(c.z) + bf2f(d.z) + r.z + bb.z;
    o.w = bf2f(a.w) + bf2f(b.w) + bf2f(c.w) + bf2f(d.w) + r.w + bb.w;
    ((f32x4*)out)[i] = o;
  }
}

// ---------------------------------------------------------------- GEMM params
struct GemmP {
  const unsigned short* A;
  const unsigned short* B;
  const float* bias;
  const float* res;
  float* outF;
  unsigned short* outH;
  int M, N, K;
};

// ---------------------------------------------------------------- 128^2 GEMM (2-phase)
DEVI void gemm128_body(const GemmP& p, int m0, int n0, int k0, int nk) {
  const int tid = threadIdx.x, lane = tid & 63, wid = tid >> 6;
  const int K = p.K;
  const int wr = wid >> 1, wc = wid & 1;

  __shared__ __align__(16) unsigned short sA[2][4096];
  __shared__ __align__(16) unsigned short sB[2][4096];

  const int c0 = tid, c1 = tid + 256;
  const unsigned short* gA0 = p.A + (size_t)(m0 + (c0 >> 2)) * K + k0 + ((c0 & 3) << 3);
  const unsigned short* gA1 = p.A + (size_t)(m0 + (c1 >> 2)) * K + k0 + ((c1 & 3) << 3);
  const unsigned short* gB0 = p.B + (size_t)(n0 + (c0 >> 2)) * K + k0 + ((c0 & 3) << 3);
  const unsigned short* gB1 = p.B + (size_t)(n0 + (c1 >> 2)) * K + k0 + ((c1 & 3) << 3);
  const int l0 = wid << 9, l1 = (wid << 9) + 2048;

  f32x4 acc[4][4] = {};
  const int arow = (wr << 6) + (lane & 15);
  const int brow = (wc << 6) + (lane & 15);
  const int koff = (lane >> 4) << 3;

#define STAGE128(bufi, t) do { int ko = (t) << 5;       \
    GLD16(gA0 + ko, &sA[bufi][l0]);                     \
    GLD16(gA1 + ko, &sA[bufi][l1]);                     \
    GLD16(gB0 + ko, &sB[bufi][l0]);                     \
    GLD16(gB1 + ko, &sB[bufi][l1]); } while (0)

  STAGE128(0, 0);
  __syncthreads();
  int cur = 0;
  for (int t = 0; t < nk; ++t) {
    if (t + 1 < nk) STAGE128(cur ^ 1, t + 1);
    bf16x8 af[4], bfr[4];
#pragma unroll
    for (int i = 0; i < 4; ++i)
      af[i] = *(const bf16x8*)&sA[cur][(arow + (i << 4)) * 32 + koff];
#pragma unroll
    for (int i = 0; i < 4; ++i)
      bfr[i] = *(const bf16x8*)&sB[cur][(brow + (i << 4)) * 32 + koff];
#pragma unroll
    for (int i = 0; i < 4; ++i)
#pragma unroll
      for (int j = 0; j < 4; ++j)
        acc[i][j] = __builtin_amdgcn_mfma_f32_16x16x32_bf16(af[i], bfr[j], acc[i][j], 0, 0, 0);
    __syncthreads();
    cur ^= 1;
  }
#undef STAGE128

  const int rbase = m0 + (wr << 6) + ((lane >> 4) << 2);
  const int cbase = n0 + (wc << 6) + (lane & 15);
#pragma unroll
  for (int mi = 0; mi < 4; ++mi) {
#pragma unroll
    for (int ni = 0; ni < 4; ++ni) {
      const int col = cbase + (ni << 4);
#pragma unroll
      for (int r = 0; r < 4; ++r) {
        const int row = rbase + (mi << 4) + r;
        const size_t o = (size_t)row * p.N + col;
        p.outF[o] = acc[mi][ni][r] + p.bias[col] + p.res[o];
      }
    }
  }
}

__global__ __launch_bounds__(256) void g2_proj128(GemmP p) {
  const int x = blockIdx.x & 7, i = blockIdx.x >> 3;
  const int bm = (x >> 1) * 8 + (i >> 3);
  const int bn = (x & 1) * 8 + (i & 7);
  gemm128_body(p, bm << 7, bn << 7, 0, p.K >> 5);
}

// ---------------------------------------------------------------- 256^2 tile common
DEVI void setup256(const GemmP& p, int m0, int n0, int k0,
                   const unsigned short*& gsA0, const unsigned short*& gsA1,
                   const unsigned short*& gsB0, const unsigned short*& gsB1) {
  const int tid = threadIdx.x;
  int r_[2], c_[2];
#pragma unroll
  for (int j = 0; j < 2; ++j) {
    int d = tid * 16 + j * 8192;
    int w = (d & 1023) ^ (((d >> 9) & 1) << 5);   // st_16x32 involution
    r_[j] = ((d >> 10) << 4) + (w >> 6);
    c_[j] = (w & 63) >> 1;
  }
  gsA0 = p.A + (size_t)(m0 + r_[0]) * p.K + k0 + c_[0];
  gsA1 = p.A + (size_t)(m0 + r_[1]) * p.K + k0 + c_[1];
  gsB0 = p.B + (size_t)(n0 + r_[0]) * p.K + k0 + c_[0];
  gsB1 = p.B + (size_t)(n0 + r_[1]) * p.K + k0 + c_[1];
}

template <int EPI>
DEVI void epi256(const GemmP& p, f32x4 (&acc)[8][4], int m0, int n0,
                 unsigned short* outH) {
  const int lane = threadIdx.x & 63, wid = threadIdx.x >> 6;
  const int wr = wid >> 2, wc = wid & 3;
  const int lr = lane & 15, lk = lane >> 4;
  const int rbase = m0 + wr * 128 + (lk << 2);
  const int cbase = n0 + wc * 64 + lr;
#pragma unroll
  for (int m = 0; m < 8; ++m) {
#pragma unroll
    for (int n = 0; n < 4; ++n) {
      const int col = cbase + (n << 4);
      const float bb = (EPI == 5) ? 0.f : p.bias[col];
#pragma unroll
      for (int r = 0; r < 4; ++r) {
        const int row = rbase + (m << 4) + r;
        float v = acc[m][n][r] + bb;
        if constexpr (EPI == 2) {
          float y = 0.7978845608028654f * (v + 0.044715f * v * v * v);
          float u = __expf(2.f * y);
          v = (y > 40.f) ? v : v * (u / (u + 1.f));
        }
        outH[(size_t)row * p.N + col] = f2bf(v);
      }
    }
  }
}

// ---------------------------------------------------------------- 256^2 2-phase
template <int EPI>
DEVI void gemm2p_body(const GemmP& p, unsigned short* lds_raw, int m0, int n0,
                      int k0, int nk, unsigned short* outH) {
  const int tid = threadIdx.x, lane = tid & 63, wid = tid >> 6;
  const int wr = wid >> 2, wc = wid & 3;
  const int lr = lane & 15, lk = lane >> 4;
  const int fb = (lr * 64 + lk * 16) ^ ((lr & 8) << 2);

  const unsigned short *gsA0, *gsA1, *gsB0, *gsB1;
  setup256(p, m0, n0, k0, gsA0, gsA1, gsB0, gsB1);

#define STG2(b, kt) do { unsigned short* _d = lds_raw + ((b) << 14);     \
    GLD16(gsA0 + ((size_t)(kt) << 5), _d + (tid << 3));                  \
    GLD16(gsA1 + ((size_t)(kt) << 5), _d + 4096 + (tid << 3));           \
    GLD16(gsB0 + ((size_t)(kt) << 5), _d + 8192 + (tid << 3));           \
    GLD16(gsB1 + ((size_t)(kt) << 5), _d + 12288 + (tid << 3)); } while (0)

  f32x4 acc[8][4] = {};
  STG2(0, 0);
  __syncthreads();
  int cur = 0;
  for (int t = 0; t < nk; ++t) {
    if (t + 1 < nk) STG2(cur ^ 1, t + 1);
    const char* tA = (const char*)(lds_raw + (cur << 14));
    const char* tB = tA + 16384;
    bf16x8 a_[8], b_[4];
#pragma unroll
    for (int n = 0; n < 4; ++n)
      b_[n] = *(const bf16x8*)(tB + (((wc << 2) + n) << 10) + fb);
#pragma unroll
    for (int m = 0; m < 8; ++m)
      a_[m] = *(const bf16x8*)(tA + (((wr << 3) + m) << 10) + fb);
#pragma unroll
    for (int m = 0; m < 8; ++m)
#pragma unroll
      for (int n = 0; n < 4; ++n)
        acc[m][n] = __builtin_amdgcn_mfma_f32_16x16x32_bf16(a_[m], b_[n], acc[m][n], 0, 0, 0);
    __syncthreads();
    cur ^= 1;
  }
#undef STG2
  epi256<EPI>(p, acc, m0, n0, outH);
}

// ---------------------------------------------------------------- 256^2 BK=64 ring-2
template <int EPI>
DEVI void gemmr2k64_body(const GemmP& p, unsigned short* lds_raw, int m0, int n0,
                         int k0, int nk64, unsigned short* outH) {
  const int tid = threadIdx.x, lane = tid & 63, wid = tid >> 6;
  const int wr = wid >> 2, wc = wid & 3;
  const int lr = lane & 15, lk = lane >> 4;
  const int fb = (lr * 64 + lk * 16) ^ ((lr & 8) << 2);

  const unsigned short *gsA0, *gsA1, *gsB0, *gsB1;
  setup256(p, m0, n0, k0, gsA0, gsA1, gsB0, gsB1);

#define STG64(bufi, kt) do { unsigned short* _d = lds_raw + ((bufi) << 15);  \
    int _ko = (kt) << 6;                                                     \
    GLD16(gsA0 + _ko,      _d + (tid << 3));                                 \
    GLD16(gsA1 + _ko,      _d + 4096 + (tid << 3));                          \
    GLD16(gsA0 + _ko + 32, _d + 8192 + (tid << 3));                          \
    GLD16(gsA1 + _ko + 32, _d + 12288 + (tid << 3));                         \
    GLD16(gsB0 + _ko,      _d + 16384 + (tid << 3));                         \
    GLD16(gsB1 + _ko,      _d + 20480 + (tid << 3));                         \
    GLD16(gsB0 + _ko + 32, _d + 24576 + (tid << 3));                         \
    GLD16(gsB1 + _ko + 32, _d + 28672 + (tid << 3)); } while (0)

  f32x4 acc[8][4] = {};
  STG64(0, 0);
  asm volatile("s_waitcnt vmcnt(0)" ::: "memory");
  __builtin_amdgcn_s_barrier();
  asm volatile("" ::: "memory");

  for (int t = 0; t < nk64; ++t) {
    if (t + 1 < nk64) STG64((t + 1) & 1, t + 1);
    const char* base = (const char*)(lds_raw + ((t & 1) << 15));
#pragma unroll
    for (int s = 0; s < 2; ++s) {
      const char* tA = base + s * 16384;
      const char* tB = base + 32768 + s * 16384;
      bf16x8 a_[8], b_[4];
#pragma unroll
      for (int n = 0; n < 4; ++n)
        b_[n] = *(const bf16x8*)(tB + (((wc << 2) + n) << 10) + fb);
#pragma unroll
      for (int m = 0; m < 8; ++m)
        a_[m] = *(const bf16x8*)(tA + (((wr << 3) + m) << 10) + fb);
      __builtin_amdgcn_s_setprio(1);
#pragma unroll
      for (int m = 0; m < 8; ++m)
#pragma unroll
        for (int n = 0; n < 4; ++n)
          acc[m][n] = __builtin_amdgcn_mfma_f32_16x16x32_bf16(a_[m], b_[n], acc[m][n], 0, 0, 0);
      __builtin_amdgcn_s_setprio(0);
    }
    if (t + 1 < nk64) asm volatile("s_waitcnt vmcnt(0)" ::: "memory");
    __builtin_amdgcn_s_barrier();
    asm volatile("" ::: "memory");
  }
#undef STG64
  epi256<EPI>(p, acc, m0, n0, outH);
}

// G1 (256^2 2-phase)
__global__ __launch_bounds__(512, 2) void g1_qkv256(GemmP p) {
  extern __shared__ unsigned short lds_raw[];
  const int x = blockIdx.x & 7, i = blockIdx.x >> 3;
  const int bm = (x & 1) * 8 + (i & 7);
  const int bn = (x >> 1) * 6 + (i >> 3);
  gemm2p_body<0>(p, lds_raw, bm << 8, bn << 8, 0, p.K >> 5, p.outH);
}
// G3 BK=64 ring-2
__global__ __launch_bounds__(512, 1) void g3_fc64(GemmP p) {
  extern __shared__ unsigned short lds_raw[];
  const int x = blockIdx.x & 7, i = blockIdx.x >> 3;
  const int bm = (x & 1) * 8 + (i & 7);
  const int bn = (x >> 1) * 8 + (i >> 3);
  gemmr2k64_body<2>(p, lds_raw, bm << 8, bn << 8, 0, 32, p.outH);
}
// G4 BK=64 ring-2, split-K4
__global__ __launch_bounds__(512, 1) void g4_sk64(GemmP p) {
  extern __shared__ unsigned short lds_raw[];
  const int x = blockIdx.x & 7, i = blockIdx.x >> 3;
  const int ks = x & 3;
  const int bm = (x >> 2) * 8 + (i >> 3);
  const int bn = i & 7;
  unsigned short* outH = p.outH + (size_t)ks * 4096 * 2048;
  gemmr2k64_body<5>(p, lds_raw, bm << 8, bn << 8, ks << 11, 32, outH);
}

// ---------------------------------------------------------------- attention
// KV-split x2 flash-decode: grid 1024; each block does 16 of 32 kv-tiles for
// (bh, qt); emits unnormalized bf16 O-partial + per-row (m, l). Combine in post_k.
__global__ __launch_bounds__(512) void attn_k(const unsigned short* __restrict__ qkv,
                                              const unsigned short* __restrict__ Vt,
                                              unsigned short* __restrict__ po,
                                              float* __restrict__ marr,
                                              float* __restrict__ larr) {
  const int tid = threadIdx.x, lane = tid & 63, wid = tid >> 6;
  const int bid = blockIdx.x;                 // grid = 1024
  const int j = bid >> 3;                     // [0,128)
  const int bh = (bid & 7) * 4 + (j >> 5);
  const int rest = j & 31;
  const int qt = rest >> 1, kvh = rest & 1;
  const int q0 = qt * 128 + wid * 16;
  const int b = bh >> 4, h = bh & 15;
  const int kt0 = kvh << 4;
  const float C = 0.08838834764831845f * 1.4426950408889634f;  // scale*log2e

  __shared__ __align__(16) unsigned short sK[64 * 128];
  __shared__ __align__(16) unsigned short sV[128 * 64];
  __shared__ __align__(16) unsigned short sP[8][16 * 72];

  const unsigned short* Qb = qkv + (size_t)(b * 2048) * 6144 + h * 128;
  const unsigned short* Kb = qkv + (size_t)(b * 2048) * 6144 + 2048 + h * 128;
  const unsigned short* Vb = Vt + ((size_t)bh << 18);

  bf16x8 qf[4];
  {
    const unsigned short* qp = Qb + (size_t)(q0 + (lane & 15)) * 6144 + ((lane >> 4) << 3);
#pragma unroll
    for (int kk = 0; kk < 4; ++kk) qf[kk] = *(const bf16x8*)(qp + kk * 32);
  }

  int koffs[2], voffs[2];
#pragma unroll
  for (int i = 0; i < 2; ++i) {
    const int c = tid + (i << 9);
    const int kv = c >> 4, jj = c & 15;
    const int js = (jj & 8) | ((jj ^ kv) & 7);
    koffs[i] = kv * 6144 + (js << 3);
    const int d = c >> 3, j2 = c & 7;
    const int js2 = j2 ^ (d & 7);
    voffs[i] = d * 2048 + (js2 << 3);
  }
  u16x8 kreg[2], vreg[2];
  auto PREF = [&](int kt) {
    const int kv0 = kt << 6;
    const unsigned short* kb = Kb + (size_t)kv0 * 6144;
#pragma unroll
    for (int i = 0; i < 2; ++i) {
      kreg[i] = *(const u16x8*)(kb + koffs[i]);
      vreg[i] = *(const u16x8*)(Vb + kv0 + voffs[i]);
    }
  };

  f32x4 oacc[8] = {};
  float mrun = -3e38f, lrun = 0.f;
  PREF(kt0);

  for (int kt = 0; kt < 16; ++kt) {
#pragma unroll
    for (int i = 0; i < 2; ++i) {
      const int c8 = (tid + (i << 9)) << 3;
      *(u16x8*)&sK[c8] = kreg[i];
      *(u16x8*)&sV[c8] = vreg[i];
    }
    __syncthreads();
    if (kt + 1 < 16) PREF(kt0 + kt + 1);

    f32x4 sc[4] = {};
    __builtin_amdgcn_s_setprio(1);
#pragma unroll
    for (int ti = 0; ti < 4; ++ti) {
#pragma unroll
      for (int kk = 0; kk < 4; ++kk) {
        const int row = (ti << 4) + (lane & 15);
        int bo = (row << 8) + (kk << 6) + ((lane >> 4) << 4);
        bo ^= (row & 7) << 4;
        bf16x8 kf = *(const bf16x8*)((const char*)sK + bo);
        sc[ti] = __builtin_amdgcn_mfma_f32_16x16x32_bf16(kf, qf[kk], sc[ti], 0, 0, 0);
      }
    }
    __builtin_amdgcn_s_setprio(0);

    float pv[16];
    float mx = -3e38f;
#pragma unroll
    for (int ti = 0; ti < 4; ++ti)
#pragma unroll
      for (int r = 0; r < 4; ++r) {
        float x = sc[ti][r];
        pv[(ti << 2) + r] = x;
        mx = fmaxf(mx, x);
      }
    mx = fmaxf(mx, __shfl_xor(mx, 16));
    mx = fmaxf(mx, __shfl_xor(mx, 32));

    float corr = 1.f;
    if (!__all(mx - mrun <= 90.50966799f)) {
      const float mnew = fmaxf(mrun, mx);
      corr = exp2f((mrun - mnew) * C);
      mrun = mnew;
      float fr[4];
#pragma unroll
      for (int r = 0; r < 4; ++r) fr[r] = __shfl(corr, ((lane >> 4) << 2) + r);
#pragma unroll
      for (int di = 0; di < 8; ++di)
#pragma unroll
        for (int r = 0; r < 4; ++r) oacc[di][r] *= fr[r];
    }
    float psum = 0.f;
#pragma unroll
    for (int i2 = 0; i2 < 16; ++i2) {
      float e = exp2f((pv[i2] - mrun) * C);
      pv[i2] = e;
      psum += e;
    }
    psum += __shfl_xor(psum, 16);
    psum += __shfl_xor(psum, 32);
    lrun = lrun * corr + psum;

    unsigned short* prow = &sP[wid][(lane & 15) * 72];
#pragma unroll
    for (int ti = 0; ti < 4; ++ti) {
      u16x4 w4;
      w4.x = f2bf(pv[(ti << 2) + 0]);
      w4.y = f2bf(pv[(ti << 2) + 1]);
      w4.z = f2bf(pv[(ti << 2) + 2]);
      w4.w = f2bf(pv[(ti << 2) + 3]);
      *(u16x4*)&prow[(ti << 4) + ((lane >> 4) << 2)] = w4;
    }

    bf16x8 pfA, pfB;
    {
      const char* pb = (const char*)&sP[wid][0] + (lane & 15) * 144 + ((lane >> 4) << 4);
      pfA = *(const bf16x8*)(pb);
      pfB = *(const bf16x8*)(pb + 64);
    }
    __builtin_amdgcn_s_setprio(1);
#pragma unroll
    for (int di = 0; di < 8; ++di) {
#pragma unroll
      for (int ks = 0; ks < 2; ++ks) {
        const int dr = (di << 4) + (lane & 15);
        int bo = (dr << 7) + (ks << 6) + ((lane >> 4) << 4);
        bo ^= (dr & 7) << 4;
        bf16x8 vf = *(const bf16x8*)((const char*)sV + bo);
        oacc[di] = __builtin_amdgcn_mfma_f32_16x16x32_bf16(ks ? pfB : pfA, vf, oacc[di], 0, 0, 0);
      }
    }
    __builtin_amdgcn_s_setprio(0);
    __syncthreads();
  }

  // store unnormalized partial (bf16) + per-row m,l
  const size_t PS = (size_t)32 * 2048 * 128;
  unsigned short* pob = po + (size_t)kvh * PS + ((size_t)bh << 18);
#pragma unroll
  for (int di = 0; di < 8; ++di)
#pragma unroll
    for (int r = 0; r < 4; ++r) {
      const size_t o = (size_t)(q0 + ((lane >> 4) << 2) + r) * 128 + (di << 4) + (lane & 15);
      pob[o] = f2bf(oacc[di][r]);
    }
  if (lane < 16) {
    const int idx = kvh * 65536 + (bh << 11) + q0 + lane;
    marr[idx] = mrun;
    larr[idx] = lrun;
  }
}

// ---------------------------------------------------------------- launch

extern "C" void kernel_launch(void* const* d_in, const int* in_sizes, int n_in,
                              void* d_out, int out_size, void* d_ws, size_t ws_size,
                              hipStream_t stream) {
  (void)in_sizes; (void)n_in; (void)out_size; (void)ws_size;
  const float* hidden = (const float*)d_in[0];
  const float* ln1_g = (const float*)d_in[1];
  const float* ln1_b = (const float*)d_in[2];
  const float* w_qkv = (const float*)d_in[3];
  const float* b_qkv = (const float*)d_in[4];
  const float* apv = (const float*)d_in[5];
  const float* apg = (const float*)d_in[6];
  const float* apb = (const float*)d_in[7];
  // d_in[8] emotion_bias: softmax-invariant -> dropped (exact)
  const float* ln2_g = (const float*)d_in[9];
  const float* ln2_b = (const float*)d_in[10];
  const float* w_fc = (const float*)d_in[11];
  const float* b_fc = (const float*)d_in[12];
  const float* mpv = (const float*)d_in[13];
  const float* mpg = (const float*)d_in[14];
  const float* mpb = (const float*)d_in[15];

  char* w = (char*)d_ws;
  const size_t MBs = 1ull << 20;
  // [0,16) xln (prep1->g1), then attn partial kvh0 (attn->post), then hidden2 lo
  // [16,32) attn partial kvh1; hidden2 hi (g2->end over [0,32))
  // [32,48) vtbuf (mid->attn); hbuf [32,96) (g3->g4)
  // [96,144) qkv (g1->attn); then wfc_bf [96,128) (post->g3); partH [96,160) (g4->g4red)
  // [128,144) xln2 (ln2->g3); [144,160) attn_out (post->g2)
  // [160,192) wqkv_bf (prep1->g1) then w2_bf (post->g4)
  // [192,200) wproj_bf (mid->g2); [200+) small scratch
  unsigned short* xln = (unsigned short*)(w + 0);
  unsigned short* po = (unsigned short*)(w + 0);
  float* hidden2 = (float*)(w + 0);
  unsigned short* vtbuf = (unsigned short*)(w + 32 * MBs);
  unsigned short* hbuf = (unsigned short*)(w + 32 * MBs);
  unsigned short* qkv = (unsigned short*)(w + 96 * MBs);
  unsigned short* wfc_bf = (unsigned short*)(w + 96 * MBs);
  unsigned short* partH = (unsigned short*)(w + 96 * MBs);
  unsigned short* xln2 = (unsigned short*)(w + 128 * MBs);
  unsigned short* attn_out = (unsigned short*)(w + 144 * MBs);
  unsigned short* wqkv_bf = (unsigned short*)(w + 160 * MBs);
  unsigned short* w2_bf = (unsigned short*)(w + 160 * MBs);
  unsigned short* wproj_bf = (unsigned short*)(w + 192 * MBs);
  float* s_attn = (float*)(w + 200 * MBs);
  float* s_mlp = (float*)(w + 200 * MBs + 32768);
  float* part_attn = (float*)(w + 201 * MBs);
  float* part_mlp = (float*)(w + 202 * MBs);
  float* marr = (float*)(w + 203 * MBs);
  float* larr = (float*)(w + 203 * MBs + (1 << 19));

  hipFuncSetAttribute((const void*)g1_qkv256, hipFuncAttributeMaxDynamicSharedMemorySize, 65536);
  hipFuncSetAttribute((const void*)g3_fc64, hipFuncAttributeMaxDynamicSharedMemorySize, 131072);
  hipFuncSetAttribute((const void*)g4_sk64, hipFuncAttributeMaxDynamicSharedMemorySize, 131072);

  // prep1: cast wqkv + colnorm1 x2 + LN1 (fused)
  prep1_k<<<6784, 256, 0, stream>>>(w_qkv, wqkv_bf, apv, part_attn, mpv, part_mlp,
                                    hidden, ln1_g, ln1_b, xln);
  // prep2: colnorm2 x2
  prep2_k<<<40, 256, 0, stream>>>(part_attn, apg, s_attn, part_mlp, mpg, s_mlp);

  // GEMM1 (256^2 2-phase): qkv = xln @ w_qkv^T + b
  GemmP p1 = {xln, wqkv_bf, b_qkv, nullptr, nullptr, qkv, 4096, 6144, 2048};
  g1_qkv256<<<384, 512, 65536, stream>>>(p1);

  // mid: vtrans + wproj scale-cast (fused)
  mid_k<<<3072, 256, 0, stream>>>(qkv, vtbuf, apv, s_attn, wproj_bf);

  // attention (kv-split x2) -> partials
  attn_k<<<1024, 512, 0, stream>>>(qkv, vtbuf, po, marr, larr);

  // post: combine + wfc cast + w2 scale-cast (fused)
  post_k<<<6144, 256, 0, stream>>>(po, marr, larr, attn_out, w_fc, wfc_bf,
                                   mpv, s_mlp, w2_bf);

  // GEMM2 (128^2): hidden2 = attn_out @ w_proj^T + b + hidden
  GemmP p2 = {attn_out, wproj_bf, apb, hidden, hidden2, nullptr, 4096, 2048, 2048};
  g2_proj128<<<512, 256, 0, stream>>>(p2);

  // LN2 -> xln2
  ln_k<<<4096, 256, 0, stream>>>(hidden2, ln2_g, ln2_b, xln2);

  // GEMM3 (BK=64 ring-2)
  GemmP p3 = {xln2, wfc_bf, b_fc, nullptr, nullptr, hbuf, 4096, 8192, 2048};
  g3_fc64<<<512, 512, 131072, stream>>>(p3);

  // GEMM4 (BK=64 ring-2, split-K4) -> fused reduce
  GemmP p4 = {hbuf, w2_bf, mpb, nullptr, nullptr, partH, 4096, 2048, 8192};
  g4_sk64<<<512, 512, 131072, stream>>>(p4);
  g4red_k<<<2048, 256, 0, stream>>>(partH, mpb, hidden2, (float*)d_out,
                                    (4096 * 2048) / 4);
}

// Round 16
// 725.914 us; speedup vs baseline: 1.0520x; 1.0028x over previous
//
#include <hip/hip_runtime.h>
#include <hip/hip_bf16.h>

#define DEVI __device__ __forceinline__

typedef __attribute__((ext_vector_type(8))) __bf16 bf16x8;
typedef __attribute__((ext_vector_type(4))) float f32x4;
typedef __attribute__((ext_vector_type(4))) unsigned short u16x4;
typedef __attribute__((ext_vector_type(8))) unsigned short u16x8;

DEVI unsigned short f2bf(float f) {
  unsigned int u = __float_as_uint(f);
  u += 0x7FFFu + ((u >> 16) & 1u);   // RNE
  return (unsigned short)(u >> 16);
}
DEVI float bf2f(unsigned short u) {
  return __uint_as_float(((unsigned int)u) << 16);
}

#define GLD16(g, l) __builtin_amdgcn_global_load_lds(                      \
    (const __attribute__((address_space(1))) void*)(g),                    \
    (__attribute__((address_space(3))) void*)(l), 16, 0, 0)

// ---------------------------------------------------------------- fused-prep bodies

DEVI void cast_body(int blk, int nblk, const float* __restrict__ in,
                    unsigned short* __restrict__ out, int n4) {
  for (int i = blk * 256 + threadIdx.x; i < n4; i += nblk * 256) {
    f32x4 v = ((const f32x4*)in)[i];
    u16x4 o;
    o.x = f2bf(v.x); o.y = f2bf(v.y); o.z = f2bf(v.z); o.w = f2bf(v.w);
    ((u16x4*)out)[i] = o;
  }
}

DEVI void scale_cast_body(int blk, int nblk, const float* __restrict__ in,
                          const float* __restrict__ s,
                          unsigned short* __restrict__ out, int cols, int n4) {
  const int cmask4 = (cols >> 2) - 1;
  for (int i = blk * 256 + threadIdx.x; i < n4; i += nblk * 256) {
    f32x4 v = ((const f32x4*)in)[i];
    f32x4 sv = ((const f32x4*)s)[i & cmask4];
    u16x4 o;
    o.x = f2bf(v.x * sv.x); o.y = f2bf(v.y * sv.y);
    o.z = f2bf(v.z * sv.z); o.w = f2bf(v.w * sv.w);
    ((u16x4*)out)[i] = o;
  }
}

DEVI void colnorm1_body(int bx, int by, const float* __restrict__ v,
                        float* __restrict__ part, int cols) {
  const int tid = threadIdx.x;
  const int g = tid & 127;
  const int s = tid >> 7;
  const int c0 = bx * 512;
  const int r0 = by * 64 + s * 32;
  const float* base = v + (size_t)r0 * cols + c0 + g * 4;
  f32x4 acc = {};
#pragma unroll 4
  for (int i = 0; i < 32; ++i) {
    f32x4 x = *(const f32x4*)(base + (size_t)i * cols);
    acc.x += x.x * x.x; acc.y += x.y * x.y;
    acc.z += x.z * x.z; acc.w += x.w * x.w;
  }
  __shared__ f32x4 red1[256];
  red1[tid] = acc;
  __syncthreads();
  if (s == 0) {
    f32x4 a = red1[tid], b = red1[tid + 128];
    f32x4 o;
    o.x = a.x + b.x; o.y = a.y + b.y; o.z = a.z + b.z; o.w = a.w + b.w;
    *(f32x4*)(part + (size_t)by * cols + c0 + g * 4) = o;
  }
}

DEVI void colnorm2_body(int blk, const float* __restrict__ part,
                        const float* __restrict__ g, float* __restrict__ s,
                        int cols, int nrc) {
  const int c = blk * 256 + threadIdx.x;
  float acc = 0.f;
  for (int i = 0; i < nrc; ++i) acc += part[(size_t)i * cols + c];
  s[c] = g[c] * rsqrtf(acc);
}

DEVI void ln_body(int row, const float* __restrict__ x, const float* __restrict__ g,
                  const float* __restrict__ b, unsigned short* __restrict__ out) {
  const int tid = threadIdx.x, lane = tid & 63, wid = tid >> 6;
  const float* xr = x + (size_t)row * 2048;
  f32x4 a0 = ((const f32x4*)xr)[tid];
  f32x4 a1 = ((const f32x4*)xr)[tid + 256];
  float s = a0.x + a0.y + a0.z + a0.w + a1.x + a1.y + a1.z + a1.w;
  float ss = a0.x * a0.x + a0.y * a0.y + a0.z * a0.z + a0.w * a0.w +
             a1.x * a1.x + a1.y * a1.y + a1.z * a1.z + a1.w * a1.w;
#pragma unroll
  for (int m = 1; m < 64; m <<= 1) {
    s += __shfl_xor(s, m);
    ss += __shfl_xor(ss, m);
  }
  __shared__ float red2[8];
  if (lane == 0) { red2[wid] = s; red2[4 + wid] = ss; }
  __syncthreads();
  s = red2[0] + red2[1] + red2[2] + red2[3];
  ss = red2[4] + red2[5] + red2[6] + red2[7];
  const float mu = s * (1.f / 2048.f);
  const float var = ss * (1.f / 2048.f) - mu * mu;
  const float rs = rsqrtf(var + 1e-5f);
  f32x4 g0 = ((const f32x4*)g)[tid], g1 = ((const f32x4*)g)[tid + 256];
  f32x4 b0 = ((const f32x4*)b)[tid], b1 = ((const f32x4*)b)[tid + 256];
  u16x4 o0, o1;
  o0.x = f2bf((a0.x - mu) * rs * g0.x + b0.x);
  o0.y = f2bf((a0.y - mu) * rs * g0.y + b0.y);
  o0.z = f2bf((a0.z - mu) * rs * g0.z + b0.z);
  o0.w = f2bf((a0.w - mu) * rs * g0.w + b0.w);
  o1.x = f2bf((a1.x - mu) * rs * g1.x + b1.x);
  o1.y = f2bf((a1.y - mu) * rs * g1.y + b1.y);
  o1.z = f2bf((a1.z - mu) * rs * g1.z + b1.z);
  o1.w = f2bf((a1.w - mu) * rs * g1.w + b1.w);
  unsigned short* orow = out + (size_t)row * 2048;
  *(u16x4*)(orow + 4 * tid) = o0;
  *(u16x4*)(orow + 1024 + 4 * tid) = o1;
}

DEVI void vtrans_body(int bid, const unsigned short* __restrict__ qkv,
                      unsigned short* __restrict__ vt) {
  __shared__ unsigned short tsh[64][134];
  const int tid = threadIdx.x;
  const int bh = bid >> 5, st = bid & 31;
  const int b = bh >> 4, h = bh & 15;
  const unsigned short* vb = qkv + (size_t)(b * 2048 + st * 64) * 6144 + 4096 + h * 128;
#pragma unroll
  for (int i = 0; i < 4; ++i) {
    int f = tid + (i << 8);
    int row = f >> 4, c8 = f & 15;
    u16x8 x = *(const u16x8*)(vb + (size_t)row * 6144 + c8 * 8);
#pragma unroll
    for (int j = 0; j < 4; ++j) {
      unsigned int pk = ((unsigned int)x[2 * j + 1] << 16) | x[2 * j];
      *(unsigned int*)&tsh[row][c8 * 8 + 2 * j] = pk;
    }
  }
  __syncthreads();
  const int lane = tid & 63, wid = tid >> 6;
  unsigned short* ob = vt + ((size_t)bh << 18) + (st << 6);
#pragma unroll
  for (int j = 0; j < 32; ++j) {
    int d = (wid << 5) + j;
    ob[((size_t)d << 11) + lane] = tsh[lane][d];
  }
}

// combine two kv-half attention partials -> normalized bf16 output
DEVI void combine_body(int blk, const unsigned short* __restrict__ po,
                       const float* __restrict__ marr, const float* __restrict__ larr,
                       unsigned short* __restrict__ O) {
  const size_t PS = (size_t)32 * 2048 * 128;
  const float C = 0.08838834764831845f * 1.4426950408889634f;
  const int tid = threadIdx.x;
  const int row = blk * 32 + (tid >> 3);      // global row = bh*2048 + q
  const int bh = row >> 11, q = row & 2047;
  const int d0 = (tid & 7) * 16;
  const float m0 = marr[row], m1 = marr[65536 + row];
  const float l0 = larr[row], l1 = larr[65536 + row];
  const float M = fmaxf(m0, m1);
  const float w0 = exp2f((m0 - M) * C), w1 = exp2f((m1 - M) * C);
  const float inv = 1.f / (l0 * w0 + l1 * w1);
  const float s0 = w0 * inv, s1 = w1 * inv;
  const unsigned short* p0 = po + ((size_t)row << 7) + d0;
  const unsigned short* p1 = p0 + PS;
  const int b = bh >> 4, h = bh & 15;
  unsigned short* ob = O + ((size_t)(b * 2048 + q)) * 2048 + h * 128 + d0;
#pragma unroll
  for (int c = 0; c < 2; ++c) {
    u16x8 a = *(const u16x8*)(p0 + c * 8);
    u16x8 bb = *(const u16x8*)(p1 + c * 8);
    u16x8 o;
#pragma unroll
    for (int j = 0; j < 8; ++j)
      o[j] = f2bf(bf2f(a[j]) * s0 + bf2f(bb[j]) * s1);
    *(u16x8*)(ob + c * 8) = o;
  }
}

// ---------------------------------------------------------------- fused launchers

__global__ __launch_bounds__(256) void prep1_k(const float* wq, unsigned short* wqb,
                                               const float* apv, float* part_a,
                                               const float* mpv, float* part_m,
                                               const float* hid, const float* g1v,
                                               const float* b1v, unsigned short* xln) {
  const int blk = blockIdx.x;
  if (blk < 2048)       cast_body(blk, 2048, wq, wqb, (6144 * 2048) / 4);
  else if (blk < 2176) { int i = blk - 2048; colnorm1_body(i & 3, i >> 2, apv, part_a, 2048); }
  else if (blk < 2688) { int i = blk - 2176; colnorm1_body(i & 15, i >> 4, mpv, part_m, 8192); }
  else                  ln_body(blk - 2688, hid, g1v, b1v, xln);
}

__global__ __launch_bounds__(256) void prep2_k(const float* part_a, const float* apg,
                                               float* s_attn, const float* part_m,
                                               const float* mpg, float* s_mlp) {
  const int blk = blockIdx.x;
  if (blk < 8) colnorm2_body(blk, part_a, apg, s_attn, 2048, 32);
  else         colnorm2_body(blk - 8, part_m, mpg, s_mlp, 8192, 32);
}

__global__ __launch_bounds__(256) void mid_k(const unsigned short* qkv,
                                             unsigned short* vt,
                                             const float* apv, const float* s_attn,
                                             unsigned short* wproj_bf) {
  const int blk = blockIdx.x;
  if (blk < 1024) vtrans_body(blk, qkv, vt);
  else            scale_cast_body(blk - 1024, 2048, apv, s_attn, wproj_bf, 2048,
                                  (2048 * 2048) / 4);
}

__global__ __launch_bounds__(256) void post_k(const unsigned short* po,
                                              const float* marr, const float* larr,
                                              unsigned short* attn_out,
                                              const float* wfc, unsigned short* wfc_bf,
                                              const float* mpv, const float* s_mlp,
                                              unsigned short* w2_bf) {
  const int blk = blockIdx.x;
  if (blk < 2048)       combine_body(blk, po, marr, larr, attn_out);
  else if (blk < 4096)  cast_body(blk - 2048, 2048, wfc, wfc_bf, (8192 * 2048) / 4);
  else                  scale_cast_body(blk - 4096, 2048, mpv, s_mlp, w2_bf, 8192,
                                        (2048 * 8192) / 4);
}

// LN2 standalone
__global__ __launch_bounds__(256) void ln_k(const float* __restrict__ x,
                                            const float* __restrict__ g,
                                            const float* __restrict__ b,
                                            unsigned short* __restrict__ out) {
  ln_body(blockIdx.x, x, g, b, out);
}

// split-K2 reduce: out = part0 + part1 (bf16) + bias + res (fp32)
__global__ __launch_bounds__(256) void g4red_k(const unsigned short* __restrict__ parts,
                                               const float* __restrict__ bias,
                                               const float* __restrict__ res,
                                               float* __restrict__ out, int n4) {
  const size_t PS = (size_t)4096 * 2048;
  for (int i = blockIdx.x * 256 + threadIdx.x; i < n4; i += gridDim.x * 256) {
    u16x4 a = ((const u16x4*)(parts))[i];
    u16x4 b = ((const u16x4*)(parts + PS))[i];
    f32x4 r = ((const f32x4*)res)[i];
    f32x4 bb = ((const f32x4*)bias)[i & 511];
    f32x4 o;
    o.x = bf2f(a.x) + bf2f(b.x) + r.x + bb.x;
    o.y = bf2f(a.y) + bf2f(b.y) + r.y + bb.y;
    o.z = bf2f(a.z) + bf2f(b.z) + r.z + bb.z;
    o.w = bf2f(a.w) + bf2f(b.w) + r.w + bb.w;
    ((f32x4*)out)[i] = o;
  }
}

// ---------------------------------------------------------------- GEMM params
struct GemmP {
  const unsigned short* A;
  const unsigned short* B;
  const float* bias;
  const float* res;
  float* outF;
  unsigned short* outH;
  int M, N, K;
};

// ---------------------------------------------------------------- 128^2 GEMM (2-phase)
DEVI void gemm128_body(const GemmP& p, int m0, int n0, int k0, int nk) {
  const int tid = threadIdx.x, lane = tid & 63, wid = tid >> 6;
  const int K = p.K;
  const int wr = wid >> 1, wc = wid & 1;

  __shared__ __align__(16) unsigned short sA[2][4096];
  __shared__ __align__(16) unsigned short sB[2][4096];

  const int c0 = tid, c1 = tid + 256;
  const unsigned short* gA0 = p.A + (size_t)(m0 + (c0 >> 2)) * K + k0 + ((c0 & 3) << 3);
  const unsigned short* gA1 = p.A + (size_t)(m0 + (c1 >> 2)) * K + k0 + ((c1 & 3) << 3);
  const unsigned short* gB0 = p.B + (size_t)(n0 + (c0 >> 2)) * K + k0 + ((c0 & 3) << 3);
  const unsigned short* gB1 = p.B + (size_t)(n0 + (c1 >> 2)) * K + k0 + ((c1 & 3) << 3);
  const int l0 = wid << 9, l1 = (wid << 9) + 2048;

  f32x4 acc[4][4] = {};
  const int arow = (wr << 6) + (lane & 15);
  const int brow = (wc << 6) + (lane & 15);
  const int koff = (lane >> 4) << 3;

#define STAGE128(bufi, t) do { int ko = (t) << 5;       \
    GLD16(gA0 + ko, &sA[bufi][l0]);                     \
    GLD16(gA1 + ko, &sA[bufi][l1]);                     \
    GLD16(gB0 + ko, &sB[bufi][l0]);                     \
    GLD16(gB1 + ko, &sB[bufi][l1]); } while (0)

  STAGE128(0, 0);
  __syncthreads();
  int cur = 0;
  for (int t = 0; t < nk; ++t) {
    if (t + 1 < nk) STAGE128(cur ^ 1, t + 1);
    bf16x8 af[4], bfr[4];
#pragma unroll
    for (int i = 0; i < 4; ++i)
      af[i] = *(const bf16x8*)&sA[cur][(arow + (i << 4)) * 32 + koff];
#pragma unroll
    for (int i = 0; i < 4; ++i)
      bfr[i] = *(const bf16x8*)&sB[cur][(brow + (i << 4)) * 32 + koff];
#pragma unroll
    for (int i = 0; i < 4; ++i)
#pragma unroll
      for (int j = 0; j < 4; ++j)
        acc[i][j] = __builtin_amdgcn_mfma_f32_16x16x32_bf16(af[i], bfr[j], acc[i][j], 0, 0, 0);
    __syncthreads();
    cur ^= 1;
  }
#undef STAGE128

  const int rbase = m0 + (wr << 6) + ((lane >> 4) << 2);
  const int cbase = n0 + (wc << 6) + (lane & 15);
#pragma unroll
  for (int mi = 0; mi < 4; ++mi) {
#pragma unroll
    for (int ni = 0; ni < 4; ++ni) {
      const int col = cbase + (ni << 4);
#pragma unroll
      for (int r = 0; r < 4; ++r) {
        const int row = rbase + (mi << 4) + r;
        const size_t o = (size_t)row * p.N + col;
        p.outF[o] = acc[mi][ni][r] + p.bias[col] + p.res[o];
      }
    }
  }
}

__global__ __launch_bounds__(256) void g2_proj128(GemmP p) {
  const int x = blockIdx.x & 7, i = blockIdx.x >> 3;
  const int bm = (x >> 1) * 8 + (i >> 3);
  const int bn = (x & 1) * 8 + (i & 7);
  gemm128_body(p, bm << 7, bn << 7, 0, p.K >> 5);
}

// ---------------------------------------------------------------- 256^2 tile common
DEVI void setup256(const GemmP& p, int m0, int n0, int k0,
                   const unsigned short*& gsA0, const unsigned short*& gsA1,
                   const unsigned short*& gsB0, const unsigned short*& gsB1) {
  const int tid = threadIdx.x;
  int r_[2], c_[2];
#pragma unroll
  for (int j = 0; j < 2; ++j) {
    int d = tid * 16 + j * 8192;
    int w = (d & 1023) ^ (((d >> 9) & 1) << 5);   // st_16x32 involution
    r_[j] = ((d >> 10) << 4) + (w >> 6);
    c_[j] = (w & 63) >> 1;
  }
  gsA0 = p.A + (size_t)(m0 + r_[0]) * p.K + k0 + c_[0];
  gsA1 = p.A + (size_t)(m0 + r_[1]) * p.K + k0 + c_[1];
  gsB0 = p.B + (size_t)(n0 + r_[0]) * p.K + k0 + c_[0];
  gsB1 = p.B + (size_t)(n0 + r_[1]) * p.K + k0 + c_[1];
}

template <int EPI>
DEVI void epi256(const GemmP& p, f32x4 (&acc)[8][4], int m0, int n0,
                 unsigned short* outH) {
  const int lane = threadIdx.x & 63, wid = threadIdx.x >> 6;
  const int wr = wid >> 2, wc = wid & 3;
  const int lr = lane & 15, lk = lane >> 4;
  const int rbase = m0 + wr * 128 + (lk << 2);
  const int cbase = n0 + wc * 64 + lr;
#pragma unroll
  for (int m = 0; m < 8; ++m) {
#pragma unroll
    for (int n = 0; n < 4; ++n) {
      const int col = cbase + (n << 4);
      const float bb = (EPI == 5) ? 0.f : p.bias[col];
#pragma unroll
      for (int r = 0; r < 4; ++r) {
        const int row = rbase + (m << 4) + r;
        float v = acc[m][n][r] + bb;
        if constexpr (EPI == 2) {
          float y = 0.7978845608028654f * (v + 0.044715f * v * v * v);
          float u = __expf(2.f * y);
          v = (y > 40.f) ? v : v * (u / (u + 1.f));
        }
        outH[(size_t)row * p.N + col] = f2bf(v);
      }
    }
  }
}

// ---------------------------------------------------------------- 256^2 2-phase
template <int EPI>
DEVI void gemm2p_body(const GemmP& p, unsigned short* lds_raw, int m0, int n0,
                      int k0, int nk, unsigned short* outH) {
  const int tid = threadIdx.x, lane = tid & 63, wid = tid >> 6;
  const int wr = wid >> 2, wc = wid & 3;
  const int lr = lane & 15, lk = lane >> 4;
  const int fb = (lr * 64 + lk * 16) ^ ((lr & 8) << 2);

  const unsigned short *gsA0, *gsA1, *gsB0, *gsB1;
  setup256(p, m0, n0, k0, gsA0, gsA1, gsB0, gsB1);

#define STG2(b, kt) do { unsigned short* _d = lds_raw + ((b) << 14);     \
    GLD16(gsA0 + ((size_t)(kt) << 5), _d + (tid << 3));                  \
    GLD16(gsA1 + ((size_t)(kt) << 5), _d + 4096 + (tid << 3));           \
    GLD16(gsB0 + ((size_t)(kt) << 5), _d + 8192 + (tid << 3));           \
    GLD16(gsB1 + ((size_t)(kt) << 5), _d + 12288 + (tid << 3)); } while (0)

  f32x4 acc[8][4] = {};
  STG2(0, 0);
  __syncthreads();
  int cur = 0;
  for (int t = 0; t < nk; ++t) {
    if (t + 1 < nk) STG2(cur ^ 1, t + 1);
    const char* tA = (const char*)(lds_raw + (cur << 14));
    const char* tB = tA + 16384;
    bf16x8 a_[8], b_[4];
#pragma unroll
    for (int n = 0; n < 4; ++n)
      b_[n] = *(const bf16x8*)(tB + (((wc << 2) + n) << 10) + fb);
#pragma unroll
    for (int m = 0; m < 8; ++m)
      a_[m] = *(const bf16x8*)(tA + (((wr << 3) + m) << 10) + fb);
#pragma unroll
    for (int m = 0; m < 8; ++m)
#pragma unroll
      for (int n = 0; n < 4; ++n)
        acc[m][n] = __builtin_amdgcn_mfma_f32_16x16x32_bf16(a_[m], b_[n], acc[m][n], 0, 0, 0);
    __syncthreads();
    cur ^= 1;
  }
#undef STG2
  epi256<EPI>(p, acc, m0, n0, outH);
}

// ---------------------------------------------------------------- 256^2 BK=64 ring-2
template <int EPI>
DEVI void gemmr2k64_body(const GemmP& p, unsigned short* lds_raw, int m0, int n0,
                         int k0, int nk64, unsigned short* outH) {
  const int tid = threadIdx.x, lane = tid & 63, wid = tid >> 6;
  const int wr = wid >> 2, wc = wid & 3;
  const int lr = lane & 15, lk = lane >> 4;
  const int fb = (lr * 64 + lk * 16) ^ ((lr & 8) << 2);

  const unsigned short *gsA0, *gsA1, *gsB0, *gsB1;
  setup256(p, m0, n0, k0, gsA0, gsA1, gsB0, gsB1);

#define STG64(bufi, kt) do { unsigned short* _d = lds_raw + ((bufi) << 15);  \
    int _ko = (kt) << 6;                                                     \
    GLD16(gsA0 + _ko,      _d + (tid << 3));                                 \
    GLD16(gsA1 + _ko,      _d + 4096 + (tid << 3));                          \
    GLD16(gsA0 + _ko + 32, _d + 8192 + (tid << 3));                          \
    GLD16(gsA1 + _ko + 32, _d + 12288 + (tid << 3));                         \
    GLD16(gsB0 + _ko,      _d + 16384 + (tid << 3));                         \
    GLD16(gsB1 + _ko,      _d + 20480 + (tid << 3));                         \
    GLD16(gsB0 + _ko + 32, _d + 24576 + (tid << 3));                         \
    GLD16(gsB1 + _ko + 32, _d + 28672 + (tid << 3)); } while (0)

  f32x4 acc[8][4] = {};
  STG64(0, 0);
  asm volatile("s_waitcnt vmcnt(0)" ::: "memory");
  __builtin_amdgcn_s_barrier();
  asm volatile("" ::: "memory");

  for (int t = 0; t < nk64; ++t) {
    if (t + 1 < nk64) STG64((t + 1) & 1, t + 1);
    const char* base = (const char*)(lds_raw + ((t & 1) << 15));
#pragma unroll
    for (int s = 0; s < 2; ++s) {
      const char* tA = base + s * 16384;
      const char* tB = base + 32768 + s * 16384;
      bf16x8 a_[8], b_[4];
#pragma unroll
      for (int n = 0; n < 4; ++n)
        b_[n] = *(const bf16x8*)(tB + (((wc << 2) + n) << 10) + fb);
#pragma unroll
      for (int m = 0; m < 8; ++m)
        a_[m] = *(const bf16x8*)(tA + (((wr << 3) + m) << 10) + fb);
      __builtin_amdgcn_s_setprio(1);
#pragma unroll
      for (int m = 0; m < 8; ++m)
#pragma unroll
        for (int n = 0; n < 4; ++n)
          acc[m][n] = __builtin_amdgcn_mfma_f32_16x16x32_bf16(a_[m], b_[n], acc[m][n], 0, 0, 0);
      __builtin_amdgcn_s_setprio(0);
    }
    if (t + 1 < nk64) asm volatile("s_waitcnt vmcnt(0)" ::: "memory");
    __builtin_amdgcn_s_barrier();
    asm volatile("" ::: "memory");
  }
#undef STG64
  epi256<EPI>(p, acc, m0, n0, outH);
}

// G1 (256^2 2-phase)
__global__ __launch_bounds__(512, 2) void g1_qkv256(GemmP p) {
  extern __shared__ unsigned short lds_raw[];
  const int x = blockIdx.x & 7, i = blockIdx.x >> 3;
  const int bm = (x & 1) * 8 + (i & 7);
  const int bn = (x >> 1) * 6 + (i >> 3);
  gemm2p_body<0>(p, lds_raw, bm << 8, bn << 8, 0, p.K >> 5, p.outH);
}
// G3 BK=64 ring-2
__global__ __launch_bounds__(512, 1) void g3_fc64(GemmP p) {
  extern __shared__ unsigned short lds_raw[];
  const int x = blockIdx.x & 7, i = blockIdx.x >> 3;
  const int bm = (x & 1) * 8 + (i & 7);
  const int bn = (x >> 1) * 8 + (i >> 3);
  gemmr2k64_body<2>(p, lds_raw, bm << 8, bn << 8, 0, 32, p.outH);
}
// G4 BK=64 ring-2, split-K2: 256 blocks (1/CU, all co-resident).
// ks = x&1 (4 XCDs per K-half), bm = (x>>1)*4 + (i>>3), bn = i&7.
__global__ __launch_bounds__(512, 1) void g4_sk64(GemmP p) {
  extern __shared__ unsigned short lds_raw[];
  const int x = blockIdx.x & 7, i = blockIdx.x >> 3;   // i in [0,32)
  const int ks = x & 1;
  const int bm = (x >> 1) * 4 + (i >> 3);
  const int bn = i & 7;
  unsigned short* outH = p.outH + (size_t)ks * 4096 * 2048;
  gemmr2k64_body<5>(p, lds_raw, bm << 8, bn << 8, ks << 12, 64, outH);
}

// ---------------------------------------------------------------- attention
// KV-split x2 flash-decode: grid 1024; each block does 16 of 32 kv-tiles for
// (bh, qt); emits unnormalized bf16 O-partial + per-row (m, l). Combine in post_k.
__global__ __launch_bounds__(512) void attn_k(const unsigned short* __restrict__ qkv,
                                              const unsigned short* __restrict__ Vt,
                                              unsigned short* __restrict__ po,
                                              float* __restrict__ marr,
                                              float* __restrict__ larr) {
  const int tid = threadIdx.x, lane = tid & 63, wid = tid >> 6;
  const int bid = blockIdx.x;                 // grid = 1024
  const int j = bid >> 3;                     // [0,128)
  const int bh = (bid & 7) * 4 + (j >> 5);
  const int rest = j & 31;
  const int qt = rest >> 1, kvh = rest & 1;
  const int q0 = qt * 128 + wid * 16;
  const int b = bh >> 4, h = bh & 15;
  const int kt0 = kvh << 4;
  const float C = 0.08838834764831845f * 1.4426950408889634f;  // scale*log2e

  __shared__ __align__(16) unsigned short sK[64 * 128];
  __shared__ __align__(16) unsigned short sV[128 * 64];
  __shared__ __align__(16) unsigned short sP[8][16 * 72];

  const unsigned short* Qb = qkv + (size_t)(b * 2048) * 6144 + h * 128;
  const unsigned short* Kb = qkv + (size_t)(b * 2048) * 6144 + 2048 + h * 128;
  const unsigned short* Vb = Vt + ((size_t)bh << 18);

  bf16x8 qf[4];
  {
    const unsigned short* qp = Qb + (size_t)(q0 + (lane & 15)) * 6144 + ((lane >> 4) << 3);
#pragma unroll
    for (int kk = 0; kk < 4; ++kk) qf[kk] = *(const bf16x8*)(qp + kk * 32);
  }

  int koffs[2], voffs[2];
#pragma unroll
  for (int i = 0; i < 2; ++i) {
    const int c = tid + (i << 9);
    const int kv = c >> 4, jj = c & 15;
    const int js = (jj & 8) | ((jj ^ kv) & 7);
    koffs[i] = kv * 6144 + (js << 3);
    const int d = c >> 3, j2 = c & 7;
    const int js2 = j2 ^ (d & 7);
    voffs[i] = d * 2048 + (js2 << 3);
  }
  u16x8 kreg[2], vreg[2];
  auto PREF = [&](int kt) {
    const int kv0 = kt << 6;
    const unsigned short* kb = Kb + (size_t)kv0 * 6144;
#pragma unroll
    for (int i = 0; i < 2; ++i) {
      kreg[i] = *(const u16x8*)(kb + koffs[i]);
      vreg[i] = *(const u16x8*)(Vb + kv0 + voffs[i]);
    }
  };

  f32x4 oacc[8] = {};
  float mrun = -3e38f, lrun = 0.f;
  PREF(kt0);

  for (int kt = 0; kt < 16; ++kt) {
#pragma unroll
    for (int i = 0; i < 2; ++i) {
      const int c8 = (tid + (i << 9)) << 3;
      *(u16x8*)&sK[c8] = kreg[i];
      *(u16x8*)&sV[c8] = vreg[i];
    }
    __syncthreads();
    if (kt + 1 < 16) PREF(kt0 + kt + 1);

    f32x4 sc[4] = {};
    __builtin_amdgcn_s_setprio(1);
#pragma unroll
    for (int ti = 0; ti < 4; ++ti) {
#pragma unroll
      for (int kk = 0; kk < 4; ++kk) {
        const int row = (ti << 4) + (lane & 15);
        int bo = (row << 8) + (kk << 6) + ((lane >> 4) << 4);
        bo ^= (row & 7) << 4;
        bf16x8 kf = *(const bf16x8*)((const char*)sK + bo);
        sc[ti] = __builtin_amdgcn_mfma_f32_16x16x32_bf16(kf, qf[kk], sc[ti], 0, 0, 0);
      }
    }
    __builtin_amdgcn_s_setprio(0);

    float pv[16];
    float mx = -3e38f;
#pragma unroll
    for (int ti = 0; ti < 4; ++ti)
#pragma unroll
      for (int r = 0; r < 4; ++r) {
        float x = sc[ti][r];
        pv[(ti << 2) + r] = x;
        mx = fmaxf(mx, x);
      }
    mx = fmaxf(mx, __shfl_xor(mx, 16));
    mx = fmaxf(mx, __shfl_xor(mx, 32));

    float corr = 1.f;
    if (!__all(mx - mrun <= 90.50966799f)) {
      const float mnew = fmaxf(mrun, mx);
      corr = exp2f((mrun - mnew) * C);
      mrun = mnew;
      float fr[4];
#pragma unroll
      for (int r = 0; r < 4; ++r) fr[r] = __shfl(corr, ((lane >> 4) << 2) + r);
#pragma unroll
      for (int di = 0; di < 8; ++di)
#pragma unroll
        for (int r = 0; r < 4; ++r) oacc[di][r] *= fr[r];
    }
    float psum = 0.f;
#pragma unroll
    for (int i2 = 0; i2 < 16; ++i2) {
      float e = exp2f((pv[i2] - mrun) * C);
      pv[i2] = e;
      psum += e;
    }
    psum += __shfl_xor(psum, 16);
    psum += __shfl_xor(psum, 32);
    lrun = lrun * corr + psum;

    unsigned short* prow = &sP[wid][(lane & 15) * 72];
#pragma unroll
    for (int ti = 0; ti < 4; ++ti) {
      u16x4 w4;
      w4.x = f2bf(pv[(ti << 2) + 0]);
      w4.y = f2bf(pv[(ti << 2) + 1]);
      w4.z = f2bf(pv[(ti << 2) + 2]);
      w4.w = f2bf(pv[(ti << 2) + 3]);
      *(u16x4*)&prow[(ti << 4) + ((lane >> 4) << 2)] = w4;
    }

    bf16x8 pfA, pfB;
    {
      const char* pb = (const char*)&sP[wid][0] + (lane & 15) * 144 + ((lane >> 4) << 4);
      pfA = *(const bf16x8*)(pb);
      pfB = *(const bf16x8*)(pb + 64);
    }
    __builtin_amdgcn_s_setprio(1);
#pragma unroll
    for (int di = 0; di < 8; ++di) {
#pragma unroll
      for (int ks = 0; ks < 2; ++ks) {
        const int dr = (di << 4) + (lane & 15);
        int bo = (dr << 7) + (ks << 6) + ((lane >> 4) << 4);
        bo ^= (dr & 7) << 4;
        bf16x8 vf = *(const bf16x8*)((const char*)sV + bo);
        oacc[di] = __builtin_amdgcn_mfma_f32_16x16x32_bf16(ks ? pfB : pfA, vf, oacc[di], 0, 0, 0);
      }
    }
    __builtin_amdgcn_s_setprio(0);
    __syncthreads();
  }

  // store unnormalized partial (bf16) + per-row m,l
  const size_t PS = (size_t)32 * 2048 * 128;
  unsigned short* pob = po + (size_t)kvh * PS + ((size_t)bh << 18);
#pragma unroll
  for (int di = 0; di < 8; ++di)
#pragma unroll
    for (int r = 0; r < 4; ++r) {
      const size_t o = (size_t)(q0 + ((lane >> 4) << 2) + r) * 128 + (di << 4) + (lane & 15);
      pob[o] = f2bf(oacc[di][r]);
    }
  if (lane < 16) {
    const int idx = kvh * 65536 + (bh << 11) + q0 + lane;
    marr[idx] = mrun;
    larr[idx] = lrun;
  }
}

// ---------------------------------------------------------------- launch

extern "C" void kernel_launch(void* const* d_in, const int* in_sizes, int n_in,
                              void* d_out, int out_size, void* d_ws, size_t ws_size,
                              hipStream_t stream) {
  (void)in_sizes; (void)n_in; (void)out_size; (void)ws_size;
  const float* hidden = (const float*)d_in[0];
  const float* ln1_g = (const float*)d_in[1];
  const float* ln1_b = (const float*)d_in[2];
  const float* w_qkv = (const float*)d_in[3];
  const float* b_qkv = (const float*)d_in[4];
  const float* apv = (const float*)d_in[5];
  const float* apg = (const float*)d_in[6];
  const float* apb = (const float*)d_in[7];
  // d_in[8] emotion_bias: softmax-invariant -> dropped (exact)
  const float* ln2_g = (const float*)d_in[9];
  const float* ln2_b = (const float*)d_in[10];
  const float* w_fc = (const float*)d_in[11];
  const float* b_fc = (const float*)d_in[12];
  const float* mpv = (const float*)d_in[13];
  const float* mpg = (const float*)d_in[14];
  const float* mpb = (const float*)d_in[15];

  char* w = (char*)d_ws;
  const size_t MBs = 1ull << 20;
  unsigned short* xln = (unsigned short*)(w + 0);
  unsigned short* po = (unsigned short*)(w + 0);
  float* hidden2 = (float*)(w + 0);
  unsigned short* vtbuf = (unsigned short*)(w + 32 * MBs);
  unsigned short* hbuf = (unsigned short*)(w + 32 * MBs);
  unsigned short* qkv = (unsigned short*)(w + 96 * MBs);
  unsigned short* wfc_bf = (unsigned short*)(w + 96 * MBs);
  unsigned short* partH = (unsigned short*)(w + 96 * MBs);   // 2x16MB bf16 partials
  unsigned short* xln2 = (unsigned short*)(w + 128 * MBs);
  unsigned short* attn_out = (unsigned short*)(w + 144 * MBs);
  unsigned short* wqkv_bf = (unsigned short*)(w + 160 * MBs);
  unsigned short* w2_bf = (unsigned short*)(w + 160 * MBs);
  unsigned short* wproj_bf = (unsigned short*)(w + 192 * MBs);
  float* s_attn = (float*)(w + 200 * MBs);
  float* s_mlp = (float*)(w + 200 * MBs + 32768);
  float* part_attn = (float*)(w + 201 * MBs);
  float* part_mlp = (float*)(w + 202 * MBs);
  float* marr = (float*)(w + 203 * MBs);
  float* larr = (float*)(w + 203 * MBs + (1 << 19));

  hipFuncSetAttribute((const void*)g1_qkv256, hipFuncAttributeMaxDynamicSharedMemorySize, 65536);
  hipFuncSetAttribute((const void*)g3_fc64, hipFuncAttributeMaxDynamicSharedMemorySize, 131072);
  hipFuncSetAttribute((const void*)g4_sk64, hipFuncAttributeMaxDynamicSharedMemorySize, 131072);

  // prep1: cast wqkv + colnorm1 x2 + LN1 (fused)
  prep1_k<<<6784, 256, 0, stream>>>(w_qkv, wqkv_bf, apv, part_attn, mpv, part_mlp,
                                    hidden, ln1_g, ln1_b, xln);
  // prep2: colnorm2 x2
  prep2_k<<<40, 256, 0, stream>>>(part_attn, apg, s_attn, part_mlp, mpg, s_mlp);

  // GEMM1 (256^2 2-phase): qkv = xln @ w_qkv^T + b
  GemmP p1 = {xln, wqkv_bf, b_qkv, nullptr, nullptr, qkv, 4096, 6144, 2048};
  g1_qkv256<<<384, 512, 65536, stream>>>(p1);

  // mid: vtrans + wproj scale-cast (fused)
  mid_k<<<3072, 256, 0, stream>>>(qkv, vtbuf, apv, s_attn, wproj_bf);

  // attention (kv-split x2) -> partials
  attn_k<<<1024, 512, 0, stream>>>(qkv, vtbuf, po, marr, larr);

  // post: combine + wfc cast + w2 scale-cast (fused)
  post_k<<<6144, 256, 0, stream>>>(po, marr, larr, attn_out, w_fc, wfc_bf,
                                   mpv, s_mlp, w2_bf);

  // GEMM2 (128^2): hidden2 = attn_out @ w_proj^T + b + hidden
  GemmP p2 = {attn_out, wproj_bf, apb, hidden, hidden2, nullptr, 4096, 2048, 2048};
  g2_proj128<<<512, 256, 0, stream>>>(p2);

  // LN2 -> xln2
  ln_k<<<4096, 256, 0, stream>>>(hidden2, ln2_g, ln2_b, xln2);

  // GEMM3 (BK=64 ring-2)
  GemmP p3 = {xln2, wfc_bf, b_fc, nullptr, nullptr, hbuf, 4096, 8192, 2048};
  g3_fc64<<<512, 512, 131072, stream>>>(p3);

  // GEMM4 (BK=64 ring-2, split-K2, 256 blocks) -> fused reduce
  GemmP p4 = {hbuf, w2_bf, mpb, nullptr, nullptr, partH, 4096, 2048, 8192};
  g4_sk64<<<256, 512, 131072, stream>>>(p4);
  g4red_k<<<1024, 256, 0, stream>>>(partH, mpb, hidden2, (float*)d_out,
                                    (4096 * 2048) / 4);
}

// Round 17
// 720.910 us; speedup vs baseline: 1.0593x; 1.0069x over previous
//
#include <hip/hip_runtime.h>
#include <hip/hip_bf16.h>

#define DEVI __device__ __forceinline__

typedef __attribute__((ext_vector_type(8))) __bf16 bf16x8;
typedef __attribute__((ext_vector_type(4))) float f32x4;
typedef __attribute__((ext_vector_type(4))) unsigned short u16x4;
typedef __attribute__((ext_vector_type(8))) unsigned short u16x8;

DEVI unsigned short f2bf(float f) {
  unsigned int u = __float_as_uint(f);
  u += 0x7FFFu + ((u >> 16) & 1u);   // RNE
  return (unsigned short)(u >> 16);
}
DEVI float bf2f(unsigned short u) {
  return __uint_as_float(((unsigned int)u) << 16);
}

#define GLD16(g, l) __builtin_amdgcn_global_load_lds(                      \
    (const __attribute__((address_space(1))) void*)(g),                    \
    (__attribute__((address_space(3))) void*)(l), 16, 0, 0)

// ---------------------------------------------------------------- fused-prep bodies

DEVI void cast_body(int blk, int nblk, const float* __restrict__ in,
                    unsigned short* __restrict__ out, int n4) {
  for (int i = blk * 256 + threadIdx.x; i < n4; i += nblk * 256) {
    f32x4 v = ((const f32x4*)in)[i];
    u16x4 o;
    o.x = f2bf(v.x); o.y = f2bf(v.y); o.z = f2bf(v.z); o.w = f2bf(v.w);
    ((u16x4*)out)[i] = o;
  }
}

DEVI void scale_cast_body(int blk, int nblk, const float* __restrict__ in,
                          const float* __restrict__ s,
                          unsigned short* __restrict__ out, int cols, int n4) {
  const int cmask4 = (cols >> 2) - 1;
  for (int i = blk * 256 + threadIdx.x; i < n4; i += nblk * 256) {
    f32x4 v = ((const f32x4*)in)[i];
    f32x4 sv = ((const f32x4*)s)[i & cmask4];
    u16x4 o;
    o.x = f2bf(v.x * sv.x); o.y = f2bf(v.y * sv.y);
    o.z = f2bf(v.z * sv.z); o.w = f2bf(v.w * sv.w);
    ((u16x4*)out)[i] = o;
  }
}

DEVI void colnorm1_body(int bx, int by, const float* __restrict__ v,
                        float* __restrict__ part, int cols) {
  const int tid = threadIdx.x;
  const int g = tid & 127;
  const int s = tid >> 7;
  const int c0 = bx * 512;
  const int r0 = by * 64 + s * 32;
  const float* base = v + (size_t)r0 * cols + c0 + g * 4;
  f32x4 acc = {};
#pragma unroll 4
  for (int i = 0; i < 32; ++i) {
    f32x4 x = *(const f32x4*)(base + (size_t)i * cols);
    acc.x += x.x * x.x; acc.y += x.y * x.y;
    acc.z += x.z * x.z; acc.w += x.w * x.w;
  }
  __shared__ f32x4 red1[256];
  red1[tid] = acc;
  __syncthreads();
  if (s == 0) {
    f32x4 a = red1[tid], b = red1[tid + 128];
    f32x4 o;
    o.x = a.x + b.x; o.y = a.y + b.y; o.z = a.z + b.z; o.w = a.w + b.w;
    *(f32x4*)(part + (size_t)by * cols + c0 + g * 4) = o;
  }
}

DEVI void colnorm2_body(int blk, const float* __restrict__ part,
                        const float* __restrict__ g, float* __restrict__ s,
                        int cols, int nrc) {
  const int c = blk * 256 + threadIdx.x;
  float acc = 0.f;
  for (int i = 0; i < nrc; ++i) acc += part[(size_t)i * cols + c];
  s[c] = g[c] * rsqrtf(acc);
}

DEVI void ln_body(int row, const float* __restrict__ x, const float* __restrict__ g,
                  const float* __restrict__ b, unsigned short* __restrict__ out) {
  const int tid = threadIdx.x, lane = tid & 63, wid = tid >> 6;
  const float* xr = x + (size_t)row * 2048;
  f32x4 a0 = ((const f32x4*)xr)[tid];
  f32x4 a1 = ((const f32x4*)xr)[tid + 256];
  float s = a0.x + a0.y + a0.z + a0.w + a1.x + a1.y + a1.z + a1.w;
  float ss = a0.x * a0.x + a0.y * a0.y + a0.z * a0.z + a0.w * a0.w +
             a1.x * a1.x + a1.y * a1.y + a1.z * a1.z + a1.w * a1.w;
#pragma unroll
  for (int m = 1; m < 64; m <<= 1) {
    s += __shfl_xor(s, m);
    ss += __shfl_xor(ss, m);
  }
  __shared__ float red2[8];
  if (lane == 0) { red2[wid] = s; red2[4 + wid] = ss; }
  __syncthreads();
  s = red2[0] + red2[1] + red2[2] + red2[3];
  ss = red2[4] + red2[5] + red2[6] + red2[7];
  const float mu = s * (1.f / 2048.f);
  const float var = ss * (1.f / 2048.f) - mu * mu;
  const float rs = rsqrtf(var + 1e-5f);
  f32x4 g0 = ((const f32x4*)g)[tid], g1 = ((const f32x4*)g)[tid + 256];
  f32x4 b0 = ((const f32x4*)b)[tid], b1 = ((const f32x4*)b)[tid + 256];
  u16x4 o0, o1;
  o0.x = f2bf((a0.x - mu) * rs * g0.x + b0.x);
  o0.y = f2bf((a0.y - mu) * rs * g0.y + b0.y);
  o0.z = f2bf((a0.z - mu) * rs * g0.z + b0.z);
  o0.w = f2bf((a0.w - mu) * rs * g0.w + b0.w);
  o1.x = f2bf((a1.x - mu) * rs * g1.x + b1.x);
  o1.y = f2bf((a1.y - mu) * rs * g1.y + b1.y);
  o1.z = f2bf((a1.z - mu) * rs * g1.z + b1.z);
  o1.w = f2bf((a1.w - mu) * rs * g1.w + b1.w);
  unsigned short* orow = out + (size_t)row * 2048;
  *(u16x4*)(orow + 4 * tid) = o0;
  *(u16x4*)(orow + 1024 + 4 * tid) = o1;
}

DEVI void vtrans_body(int bid, const unsigned short* __restrict__ qkv,
                      unsigned short* __restrict__ vt) {
  __shared__ unsigned short tsh[64][134];
  const int tid = threadIdx.x;
  const int bh = bid >> 5, st = bid & 31;
  const int b = bh >> 4, h = bh & 15;
  const unsigned short* vb = qkv + (size_t)(b * 2048 + st * 64) * 6144 + 4096 + h * 128;
#pragma unroll
  for (int i = 0; i < 4; ++i) {
    int f = tid + (i << 8);
    int row = f >> 4, c8 = f & 15;
    u16x8 x = *(const u16x8*)(vb + (size_t)row * 6144 + c8 * 8);
#pragma unroll
    for (int j = 0; j < 4; ++j) {
      unsigned int pk = ((unsigned int)x[2 * j + 1] << 16) | x[2 * j];
      *(unsigned int*)&tsh[row][c8 * 8 + 2 * j] = pk;
    }
  }
  __syncthreads();
  const int lane = tid & 63, wid = tid >> 6;
  unsigned short* ob = vt + ((size_t)bh << 18) + (st << 6);
#pragma unroll
  for (int j = 0; j < 32; ++j) {
    int d = (wid << 5) + j;
    ob[((size_t)d << 11) + lane] = tsh[lane][d];
  }
}

// combine two kv-half attention partials -> normalized bf16 output
DEVI void combine_body(int blk, const unsigned short* __restrict__ po,
                       const float* __restrict__ marr, const float* __restrict__ larr,
                       unsigned short* __restrict__ O) {
  const size_t PS = (size_t)32 * 2048 * 128;
  const float C = 0.08838834764831845f * 1.4426950408889634f;
  const int tid = threadIdx.x;
  const int row = blk * 32 + (tid >> 3);      // global row = bh*2048 + q
  const int bh = row >> 11, q = row & 2047;
  const int d0 = (tid & 7) * 16;
  const float m0 = marr[row], m1 = marr[65536 + row];
  const float l0 = larr[row], l1 = larr[65536 + row];
  const float M = fmaxf(m0, m1);
  const float w0 = exp2f((m0 - M) * C), w1 = exp2f((m1 - M) * C);
  const float inv = 1.f / (l0 * w0 + l1 * w1);
  const float s0 = w0 * inv, s1 = w1 * inv;
  const unsigned short* p0 = po + ((size_t)row << 7) + d0;
  const unsigned short* p1 = p0 + PS;
  const int b = bh >> 4, h = bh & 15;
  unsigned short* ob = O + ((size_t)(b * 2048 + q)) * 2048 + h * 128 + d0;
#pragma unroll
  for (int c = 0; c < 2; ++c) {
    u16x8 a = *(const u16x8*)(p0 + c * 8);
    u16x8 bb = *(const u16x8*)(p1 + c * 8);
    u16x8 o;
#pragma unroll
    for (int j = 0; j < 8; ++j)
      o[j] = f2bf(bf2f(a[j]) * s0 + bf2f(bb[j]) * s1);
    *(u16x8*)(ob + c * 8) = o;
  }
}

// ---------------------------------------------------------------- fused launchers

__global__ __launch_bounds__(256) void prep1_k(const float* wq, unsigned short* wqb,
                                               const float* apv, float* part_a,
                                               const float* mpv, float* part_m,
                                               const float* hid, const float* g1v,
                                               const float* b1v, unsigned short* xln) {
  const int blk = blockIdx.x;
  if (blk < 2048)       cast_body(blk, 2048, wq, wqb, (6144 * 2048) / 4);
  else if (blk < 2176) { int i = blk - 2048; colnorm1_body(i & 3, i >> 2, apv, part_a, 2048); }
  else if (blk < 2688) { int i = blk - 2176; colnorm1_body(i & 15, i >> 4, mpv, part_m, 8192); }
  else                  ln_body(blk - 2688, hid, g1v, b1v, xln);
}

__global__ __launch_bounds__(256) void prep2_k(const float* part_a, const float* apg,
                                               float* s_attn, const float* part_m,
                                               const float* mpg, float* s_mlp) {
  const int blk = blockIdx.x;
  if (blk < 8) colnorm2_body(blk, part_a, apg, s_attn, 2048, 32);
  else         colnorm2_body(blk - 8, part_m, mpg, s_mlp, 8192, 32);
}

__global__ __launch_bounds__(256) void mid_k(const unsigned short* qkv,
                                             unsigned short* vt,
                                             const float* apv, const float* s_attn,
                                             unsigned short* wproj_bf) {
  const int blk = blockIdx.x;
  if (blk < 1024) vtrans_body(blk, qkv, vt);
  else            scale_cast_body(blk - 1024, 2048, apv, s_attn, wproj_bf, 2048,
                                  (2048 * 2048) / 4);
}

__global__ __launch_bounds__(256) void post_k(const unsigned short* po,
                                              const float* marr, const float* larr,
                                              unsigned short* attn_out,
                                              const float* wfc, unsigned short* wfc_bf,
                                              const float* mpv, const float* s_mlp,
                                              unsigned short* w2_bf) {
  const int blk = blockIdx.x;
  if (blk < 2048)       combine_body(blk, po, marr, larr, attn_out);
  else if (blk < 4096)  cast_body(blk - 2048, 2048, wfc, wfc_bf, (8192 * 2048) / 4);
  else                  scale_cast_body(blk - 4096, 2048, mpv, s_mlp, w2_bf, 8192,
                                        (2048 * 8192) / 4);
}

// LN2 standalone
__global__ __launch_bounds__(256) void ln_k(const float* __restrict__ x,
                                            const float* __restrict__ g,
                                            const float* __restrict__ b,
                                            unsigned short* __restrict__ out) {
  ln_body(blockIdx.x, x, g, b, out);
}

// ---------------------------------------------------------------- GEMM params
struct GemmP {
  const unsigned short* A;
  const unsigned short* B;
  const float* bias;
  const float* res;
  float* outF;
  unsigned short* outH;
  int M, N, K;
};

// ---------------------------------------------------------------- 256^2 tile common
DEVI void setup256(const GemmP& p, int m0, int n0, int k0,
                   const unsigned short*& gsA0, const unsigned short*& gsA1,
                   const unsigned short*& gsB0, const unsigned short*& gsB1) {
  const int tid = threadIdx.x;
  int r_[2], c_[2];
#pragma unroll
  for (int j = 0; j < 2; ++j) {
    int d = tid * 16 + j * 8192;
    int w = (d & 1023) ^ (((d >> 9) & 1) << 5);   // st_16x32 involution
    r_[j] = ((d >> 10) << 4) + (w >> 6);
    c_[j] = (w & 63) >> 1;
  }
  gsA0 = p.A + (size_t)(m0 + r_[0]) * p.K + k0 + c_[0];
  gsA1 = p.A + (size_t)(m0 + r_[1]) * p.K + k0 + c_[1];
  gsB0 = p.B + (size_t)(n0 + r_[0]) * p.K + k0 + c_[0];
  gsB1 = p.B + (size_t)(n0 + r_[1]) * p.K + k0 + c_[1];
}

template <int EPI>
DEVI void epi256(const GemmP& p, f32x4 (&acc)[8][4], int m0, int n0,
                 unsigned short* outH) {
  const int lane = threadIdx.x & 63, wid = threadIdx.x >> 6;
  const int wr = wid >> 2, wc = wid & 3;
  const int lr = lane & 15, lk = lane >> 4;
  const int rbase = m0 + wr * 128 + (lk << 2);
  const int cbase = n0 + wc * 64 + lr;
#pragma unroll
  for (int m = 0; m < 8; ++m) {
#pragma unroll
    for (int n = 0; n < 4; ++n) {
      const int col = cbase + (n << 4);
      const float bb = p.bias[col];
#pragma unroll
      for (int r = 0; r < 4; ++r) {
        const int row = rbase + (m << 4) + r;
        float v = acc[m][n][r] + bb;
        if constexpr (EPI == 2) {
          float y = 0.7978845608028654f * (v + 0.044715f * v * v * v);
          float u = __expf(2.f * y);
          v = (y > 40.f) ? v : v * (u / (u + 1.f));
        }
        outH[(size_t)row * p.N + col] = f2bf(v);
      }
    }
  }
}

// ---------------------------------------------------------------- 256^2 2-phase
template <int EPI>
DEVI void gemm2p_body(const GemmP& p, unsigned short* lds_raw, int m0, int n0,
                      int k0, int nk, unsigned short* outH) {
  const int tid = threadIdx.x, lane = tid & 63, wid = tid >> 6;
  const int wr = wid >> 2, wc = wid & 3;
  const int lr = lane & 15, lk = lane >> 4;
  const int fb = (lr * 64 + lk * 16) ^ ((lr & 8) << 2);

  const unsigned short *gsA0, *gsA1, *gsB0, *gsB1;
  setup256(p, m0, n0, k0, gsA0, gsA1, gsB0, gsB1);

#define STG2(b, kt) do { unsigned short* _d = lds_raw + ((b) << 14);     \
    GLD16(gsA0 + ((size_t)(kt) << 5), _d + (tid << 3));                  \
    GLD16(gsA1 + ((size_t)(kt) << 5), _d + 4096 + (tid << 3));           \
    GLD16(gsB0 + ((size_t)(kt) << 5), _d + 8192 + (tid << 3));           \
    GLD16(gsB1 + ((size_t)(kt) << 5), _d + 12288 + (tid << 3)); } while (0)

  f32x4 acc[8][4] = {};
  STG2(0, 0);
  __syncthreads();
  int cur = 0;
  for (int t = 0; t < nk; ++t) {
    if (t + 1 < nk) STG2(cur ^ 1, t + 1);
    const char* tA = (const char*)(lds_raw + (cur << 14));
    const char* tB = tA + 16384;
    bf16x8 a_[8], b_[4];
#pragma unroll
    for (int n = 0; n < 4; ++n)
      b_[n] = *(const bf16x8*)(tB + (((wc << 2) + n) << 10) + fb);
#pragma unroll
    for (int m = 0; m < 8; ++m)
      a_[m] = *(const bf16x8*)(tA + (((wr << 3) + m) << 10) + fb);
#pragma unroll
    for (int m = 0; m < 8; ++m)
#pragma unroll
      for (int n = 0; n < 4; ++n)
        acc[m][n] = __builtin_amdgcn_mfma_f32_16x16x32_bf16(a_[m], b_[n], acc[m][n], 0, 0, 0);
    __syncthreads();
    cur ^= 1;
  }
#undef STG2
  epi256<EPI>(p, acc, m0, n0, outH);
}

// ---------------------------------------------------------------- 256^2 BK=64 ring-2
template <int EPI>
DEVI void gemmr2k64_body(const GemmP& p, unsigned short* lds_raw, int m0, int n0,
                         int k0, int nk64, unsigned short* outH) {
  const int tid = threadIdx.x, lane = tid & 63, wid = tid >> 6;
  const int wr = wid >> 2, wc = wid & 3;
  const int lr = lane & 15, lk = lane >> 4;
  const int fb = (lr * 64 + lk * 16) ^ ((lr & 8) << 2);

  const unsigned short *gsA0, *gsA1, *gsB0, *gsB1;
  setup256(p, m0, n0, k0, gsA0, gsA1, gsB0, gsB1);

#define STG64(bufi, kt) do { unsigned short* _d = lds_raw + ((bufi) << 15);  \
    int _ko = (kt) << 6;                                                     \
    GLD16(gsA0 + _ko,      _d + (tid << 3));                                 \
    GLD16(gsA1 + _ko,      _d + 4096 + (tid << 3));                          \
    GLD16(gsA0 + _ko + 32, _d + 8192 + (tid << 3));                          \
    GLD16(gsA1 + _ko + 32, _d + 12288 + (tid << 3));                         \
    GLD16(gsB0 + _ko,      _d + 16384 + (tid << 3));                         \
    GLD16(gsB1 + _ko,      _d + 20480 + (tid << 3));                         \
    GLD16(gsB0 + _ko + 32, _d + 24576 + (tid << 3));                         \
    GLD16(gsB1 + _ko + 32, _d + 28672 + (tid << 3)); } while (0)

  f32x4 acc[8][4] = {};
  STG64(0, 0);
  asm volatile("s_waitcnt vmcnt(0)" ::: "memory");
  __builtin_amdgcn_s_barrier();
  asm volatile("" ::: "memory");

  for (int t = 0; t < nk64; ++t) {
    if (t + 1 < nk64) STG64((t + 1) & 1, t + 1);
    const char* base = (const char*)(lds_raw + ((t & 1) << 15));
#pragma unroll
    for (int s = 0; s < 2; ++s) {
      const char* tA = base + s * 16384;
      const char* tB = base + 32768 + s * 16384;
      bf16x8 a_[8], b_[4];
#pragma unroll
      for (int n = 0; n < 4; ++n)
        b_[n] = *(const bf16x8*)(tB + (((wc << 2) + n) << 10) + fb);
#pragma unroll
      for (int m = 0; m < 8; ++m)
        a_[m] = *(const bf16x8*)(tA + (((wr << 3) + m) << 10) + fb);
      __builtin_amdgcn_s_setprio(1);
#pragma unroll
      for (int m = 0; m < 8; ++m)
#pragma unroll
        for (int n = 0; n < 4; ++n)
          acc[m][n] = __builtin_amdgcn_mfma_f32_16x16x32_bf16(a_[m], b_[n], acc[m][n], 0, 0, 0);
      __builtin_amdgcn_s_setprio(0);
    }
    if (t + 1 < nk64) asm volatile("s_waitcnt vmcnt(0)" ::: "memory");
    __builtin_amdgcn_s_barrier();
    asm volatile("" ::: "memory");
  }
#undef STG64
  epi256<EPI>(p, acc, m0, n0, outH);
}

// ---------------------------------------------------------------- 128x256 BK=64 ring-2
// BM=128, BN=256: grid = (M/128)x(N/256) = 256 blocks = 1/CU, no K-split needed.
// Per K-tile: A = 2x8KB chunks (ks0/ks1), B = 4x8KB chunks -> 6 gload_lds.
// Buffer = 48KB; ring-2 = 96KB LDS. Waves 2Mx4N, per-wave 64x64, 32 MFMA/K-step.
// Epilogue: fp32 +bias+res (direct output; removes split-K partial round-trip).
template <int NK64>
DEVI void gemmw128_body(const GemmP& p, unsigned short* lds_raw, int m0, int n0) {
  const int tid = threadIdx.x, lane = tid & 63, wid = tid >> 6;
  const int wr = wid >> 2, wc = wid & 3;
  const int lr = lane & 15, lk = lane >> 4;
  const int fb = (lr * 64 + lk * 16) ^ ((lr & 8) << 2);

  const unsigned short *gsA0, *gsA1, *gsB0, *gsB1;
  setup256(p, m0, n0, 0, gsA0, gsA1, gsB0, gsB1);
  (void)gsA1;   // A tile is 128 rows: r_[0]/c_[0] mapping only

#define STGW(bufi, kt) do { unsigned short* _d = lds_raw + (bufi) * 24576;   \
    int _ko = (kt) << 6;                                                     \
    GLD16(gsA0 + _ko,      _d + (tid << 3));                                 \
    GLD16(gsA0 + _ko + 32, _d + 4096 + (tid << 3));                          \
    GLD16(gsB0 + _ko,      _d + 8192 + (tid << 3));                          \
    GLD16(gsB1 + _ko,      _d + 12288 + (tid << 3));                         \
    GLD16(gsB0 + _ko + 32, _d + 16384 + (tid << 3));                         \
    GLD16(gsB1 + _ko + 32, _d + 20480 + (tid << 3)); } while (0)

  f32x4 acc[4][4] = {};
  STGW(0, 0);
  asm volatile("s_waitcnt vmcnt(0)" ::: "memory");
  __builtin_amdgcn_s_barrier();
  asm volatile("" ::: "memory");

  for (int t = 0; t < NK64; ++t) {
    if (t + 1 < NK64) STGW((t + 1) & 1, t + 1);
    const char* base = (const char*)(lds_raw + (t & 1) * 24576);
#pragma unroll
    for (int s = 0; s < 2; ++s) {
      const char* tA = base + s * 8192;               // A chunk for this ks
      const char* tB = base + 16384 + s * 16384;      // B chunks for this ks
      bf16x8 a_[4], b_[4];
#pragma unroll
      for (int ni = 0; ni < 4; ++ni) {
        const int bidx = (wc << 2) + ni;              // B subtile 0..15
        b_[ni] = *(const bf16x8*)(tB + ((bidx >> 3) << 13) + ((bidx & 7) << 10) + fb);
      }
#pragma unroll
      for (int mi = 0; mi < 4; ++mi)
        a_[mi] = *(const bf16x8*)(tA + (((wr << 2) + mi) << 10) + fb);
      __builtin_amdgcn_s_setprio(1);
#pragma unroll
      for (int mi = 0; mi < 4; ++mi)
#pragma unroll
        for (int ni = 0; ni < 4; ++ni)
          acc[mi][ni] = __builtin_amdgcn_mfma_f32_16x16x32_bf16(a_[mi], b_[ni], acc[mi][ni], 0, 0, 0);
      __builtin_amdgcn_s_setprio(0);
    }
    if (t + 1 < NK64) asm volatile("s_waitcnt vmcnt(0)" ::: "memory");
    __builtin_amdgcn_s_barrier();
    asm volatile("" ::: "memory");
  }
#undef STGW

  // epilogue: fp32 +bias +res
  const int rbase = m0 + wr * 64 + (lk << 2);
  const int cbase = n0 + wc * 64 + lr;
#pragma unroll
  for (int mi = 0; mi < 4; ++mi) {
#pragma unroll
    for (int ni = 0; ni < 4; ++ni) {
      const int col = cbase + (ni << 4);
      const float bb = p.bias[col];
#pragma unroll
      for (int r = 0; r < 4; ++r) {
        const int row = rbase + (mi << 4) + r;
        const size_t o = (size_t)row * p.N + col;
        p.outF[o] = acc[mi][ni][r] + bb + p.res[o];
      }
    }
  }
}

// G1 (256^2 2-phase)
__global__ __launch_bounds__(512, 2) void g1_qkv256(GemmP p) {
  extern __shared__ unsigned short lds_raw[];
  const int x = blockIdx.x & 7, i = blockIdx.x >> 3;
  const int bm = (x & 1) * 8 + (i & 7);
  const int bn = (x >> 1) * 6 + (i >> 3);
  gemm2p_body<0>(p, lds_raw, bm << 8, bn << 8, 0, p.K >> 5, p.outH);
}
// G3 BK=64 ring-2
__global__ __launch_bounds__(512, 1) void g3_fc64(GemmP p) {
  extern __shared__ unsigned short lds_raw[];
  const int x = blockIdx.x & 7, i = blockIdx.x >> 3;
  const int bm = (x & 1) * 8 + (i & 7);
  const int bn = (x >> 1) * 8 + (i >> 3);
  gemmr2k64_body<2>(p, lds_raw, bm << 8, bn << 8, 0, 32, p.outH);
}
// G2 (128x256, K=2048): nbm=32, nbn=8; region/XCD = 4(M) x 8(N)
__global__ __launch_bounds__(512, 1) void g2_w128(GemmP p) {
  extern __shared__ unsigned short lds_raw[];
  const int x = blockIdx.x & 7, i = blockIdx.x >> 3;   // i in [0,32)
  const int bm = x * 4 + (i >> 3);
  const int bn = i & 7;
  gemmw128_body<32>(p, lds_raw, bm << 7, bn << 8);
}
// G4 (128x256, K=8192, no split-K): same grid mapping
__global__ __launch_bounds__(512, 1) void g4_w128(GemmP p) {
  extern __shared__ unsigned short lds_raw[];
  const int x = blockIdx.x & 7, i = blockIdx.x >> 3;   // i in [0,32)
  const int bm = x * 4 + (i >> 3);
  const int bn = i & 7;
  gemmw128_body<128>(p, lds_raw, bm << 7, bn << 8);
}

// ---------------------------------------------------------------- attention
// KV-split x2 flash-decode: grid 1024; each block does 16 of 32 kv-tiles for
// (bh, qt); emits unnormalized bf16 O-partial + per-row (m, l). Combine in post_k.
__global__ __launch_bounds__(512) void attn_k(const unsigned short* __restrict__ qkv,
                                              const unsigned short* __restrict__ Vt,
                                              unsigned short* __restrict__ po,
                                              float* __restrict__ marr,
                                              float* __restrict__ larr) {
  const int tid = threadIdx.x, lane = tid & 63, wid = tid >> 6;
  const int bid = blockIdx.x;                 // grid = 1024
  const int j = bid >> 3;                     // [0,128)
  const int bh = (bid & 7) * 4 + (j >> 5);
  const int rest = j & 31;
  const int qt = rest >> 1, kvh = rest & 1;
  const int q0 = qt * 128 + wid * 16;
  const int b = bh >> 4, h = bh & 15;
  const int kt0 = kvh << 4;
  const float C = 0.08838834764831845f * 1.4426950408889634f;  // scale*log2e

  __shared__ __align__(16) unsigned short sK[64 * 128];
  __shared__ __align__(16) unsigned short sV[128 * 64];
  __shared__ __align__(16) unsigned short sP[8][16 * 72];

  const unsigned short* Qb = qkv + (size_t)(b * 2048) * 6144 + h * 128;
  const unsigned short* Kb = qkv + (size_t)(b * 2048) * 6144 + 2048 + h * 128;
  const unsigned short* Vb = Vt + ((size_t)bh << 18);

  bf16x8 qf[4];
  {
    const unsigned short* qp = Qb + (size_t)(q0 + (lane & 15)) * 6144 + ((lane >> 4) << 3);
#pragma unroll
    for (int kk = 0; kk < 4; ++kk) qf[kk] = *(const bf16x8*)(qp + kk * 32);
  }

  int koffs[2], voffs[2];
#pragma unroll
  for (int i = 0; i < 2; ++i) {
    const int c = tid + (i << 9);
    const int kv = c >> 4, jj = c & 15;
    const int js = (jj & 8) | ((jj ^ kv) & 7);
    koffs[i] = kv * 6144 + (js << 3);
    const int d = c >> 3, j2 = c & 7;
    const int js2 = j2 ^ (d & 7);
    voffs[i] = d * 2048 + (js2 << 3);
  }
  u16x8 kreg[2], vreg[2];
  auto PREF = [&](int kt) {
    const int kv0 = kt << 6;
    const unsigned short* kb = Kb + (size_t)kv0 * 6144;
#pragma unroll
    for (int i = 0; i < 2; ++i) {
      kreg[i] = *(const u16x8*)(kb + koffs[i]);
      vreg[i] = *(const u16x8*)(Vb + kv0 + voffs[i]);
    }
  };

  f32x4 oacc[8] = {};
  float mrun = -3e38f, lrun = 0.f;
  PREF(kt0);

  for (int kt = 0; kt < 16; ++kt) {
#pragma unroll
    for (int i = 0; i < 2; ++i) {
      const int c8 = (tid + (i << 9)) << 3;
      *(u16x8*)&sK[c8] = kreg[i];
      *(u16x8*)&sV[c8] = vreg[i];
    }
    __syncthreads();
    if (kt + 1 < 16) PREF(kt0 + kt + 1);

    f32x4 sc[4] = {};
    __builtin_amdgcn_s_setprio(1);
#pragma unroll
    for (int ti = 0; ti < 4; ++ti) {
#pragma unroll
      for (int kk = 0; kk < 4; ++kk) {
        const int row = (ti << 4) + (lane & 15);
        int bo = (row << 8) + (kk << 6) + ((lane >> 4) << 4);
        bo ^= (row & 7) << 4;
        bf16x8 kf = *(const bf16x8*)((const char*)sK + bo);
        sc[ti] = __builtin_amdgcn_mfma_f32_16x16x32_bf16(kf, qf[kk], sc[ti], 0, 0, 0);
      }
    }
    __builtin_amdgcn_s_setprio(0);

    float pv[16];
    float mx = -3e38f;
#pragma unroll
    for (int ti = 0; ti < 4; ++ti)
#pragma unroll
      for (int r = 0; r < 4; ++r) {
        float x = sc[ti][r];
        pv[(ti << 2) + r] = x;
        mx = fmaxf(mx, x);
      }
    mx = fmaxf(mx, __shfl_xor(mx, 16));
    mx = fmaxf(mx, __shfl_xor(mx, 32));

    float corr = 1.f;
    if (!__all(mx - mrun <= 90.50966799f)) {
      const float mnew = fmaxf(mrun, mx);
      corr = exp2f((mrun - mnew) * C);
      mrun = mnew;
      float fr[4];
#pragma unroll
      for (int r = 0; r < 4; ++r) fr[r] = __shfl(corr, ((lane >> 4) << 2) + r);
#pragma unroll
      for (int di = 0; di < 8; ++di)
#pragma unroll
        for (int r = 0; r < 4; ++r) oacc[di][r] *= fr[r];
    }
    float psum = 0.f;
#pragma unroll
    for (int i2 = 0; i2 < 16; ++i2) {
      float e = exp2f((pv[i2] - mrun) * C);
      pv[i2] = e;
      psum += e;
    }
    psum += __shfl_xor(psum, 16);
    psum += __shfl_xor(psum, 32);
    lrun = lrun * corr + psum;

    unsigned short* prow = &sP[wid][(lane & 15) * 72];
#pragma unroll
    for (int ti = 0; ti < 4; ++ti) {
      u16x4 w4;
      w4.x = f2bf(pv[(ti << 2) + 0]);
      w4.y = f2bf(pv[(ti << 2) + 1]);
      w4.z = f2bf(pv[(ti << 2) + 2]);
      w4.w = f2bf(pv[(ti << 2) + 3]);
      *(u16x4*)&prow[(ti << 4) + ((lane >> 4) << 2)] = w4;
    }

    bf16x8 pfA, pfB;
    {
      const char* pb = (const char*)&sP[wid][0] + (lane & 15) * 144 + ((lane >> 4) << 4);
      pfA = *(const bf16x8*)(pb);
      pfB = *(const bf16x8*)(pb + 64);
    }
    __builtin_amdgcn_s_setprio(1);
#pragma unroll
    for (int di = 0; di < 8; ++di) {
#pragma unroll
      for (int ks = 0; ks < 2; ++ks) {
        const int dr = (di << 4) + (lane & 15);
        int bo = (dr << 7) + (ks << 6) + ((lane >> 4) << 4);
        bo ^= (dr & 7) << 4;
        bf16x8 vf = *(const bf16x8*)((const char*)sV + bo);
        oacc[di] = __builtin_amdgcn_mfma_f32_16x16x32_bf16(ks ? pfB : pfA, vf, oacc[di], 0, 0, 0);
      }
    }
    __builtin_amdgcn_s_setprio(0);
    __syncthreads();
  }

  // store unnormalized partial (bf16) + per-row m,l
  const size_t PS = (size_t)32 * 2048 * 128;
  unsigned short* pob = po + (size_t)kvh * PS + ((size_t)bh << 18);
#pragma unroll
  for (int di = 0; di < 8; ++di)
#pragma unroll
    for (int r = 0; r < 4; ++r) {
      const size_t o = (size_t)(q0 + ((lane >> 4) << 2) + r) * 128 + (di << 4) + (lane & 15);
      pob[o] = f2bf(oacc[di][r]);
    }
  if (lane < 16) {
    const int idx = kvh * 65536 + (bh << 11) + q0 + lane;
    marr[idx] = mrun;
    larr[idx] = lrun;
  }
}

// ---------------------------------------------------------------- launch

extern "C" void kernel_launch(void* const* d_in, const int* in_sizes, int n_in,
                              void* d_out, int out_size, void* d_ws, size_t ws_size,
                              hipStream_t stream) {
  (void)in_sizes; (void)n_in; (void)out_size; (void)ws_size;
  const float* hidden = (const float*)d_in[0];
  const float* ln1_g = (const float*)d_in[1];
  const float* ln1_b = (const float*)d_in[2];
  const float* w_qkv = (const float*)d_in[3];
  const float* b_qkv = (const float*)d_in[4];
  const float* apv = (const float*)d_in[5];
  const float* apg = (const float*)d_in[6];
  const float* apb = (const float*)d_in[7];
  // d_in[8] emotion_bias: softmax-invariant -> dropped (exact)
  const float* ln2_g = (const float*)d_in[9];
  const float* ln2_b = (const float*)d_in[10];
  const float* w_fc = (const float*)d_in[11];
  const float* b_fc = (const float*)d_in[12];
  const float* mpv = (const float*)d_in[13];
  const float* mpg = (const float*)d_in[14];
  const float* mpb = (const float*)d_in[15];

  char* w = (char*)d_ws;
  const size_t MBs = 1ull << 20;
  unsigned short* xln = (unsigned short*)(w + 0);
  unsigned short* po = (unsigned short*)(w + 0);
  float* hidden2 = (float*)(w + 0);
  unsigned short* vtbuf = (unsigned short*)(w + 32 * MBs);
  unsigned short* hbuf = (unsigned short*)(w + 32 * MBs);
  unsigned short* qkv = (unsigned short*)(w + 96 * MBs);
  unsigned short* wfc_bf = (unsigned short*)(w + 96 * MBs);
  unsigned short* xln2 = (unsigned short*)(w + 128 * MBs);
  unsigned short* attn_out = (unsigned short*)(w + 144 * MBs);
  unsigned short* wqkv_bf = (unsigned short*)(w + 160 * MBs);
  unsigned short* w2_bf = (unsigned short*)(w + 160 * MBs);
  unsigned short* wproj_bf = (unsigned short*)(w + 192 * MBs);
  float* s_attn = (float*)(w + 200 * MBs);
  float* s_mlp = (float*)(w + 200 * MBs + 32768);
  float* part_attn = (float*)(w + 201 * MBs);
  float* part_mlp = (float*)(w + 202 * MBs);
  float* marr = (float*)(w + 203 * MBs);
  float* larr = (float*)(w + 203 * MBs + (1 << 19));

  hipFuncSetAttribute((const void*)g1_qkv256, hipFuncAttributeMaxDynamicSharedMemorySize, 65536);
  hipFuncSetAttribute((const void*)g3_fc64, hipFuncAttributeMaxDynamicSharedMemorySize, 131072);
  hipFuncSetAttribute((const void*)g2_w128, hipFuncAttributeMaxDynamicSharedMemorySize, 98304);
  hipFuncSetAttribute((const void*)g4_w128, hipFuncAttributeMaxDynamicSharedMemorySize, 98304);

  // prep1: cast wqkv + colnorm1 x2 + LN1 (fused)
  prep1_k<<<6784, 256, 0, stream>>>(w_qkv, wqkv_bf, apv, part_attn, mpv, part_mlp,
                                    hidden, ln1_g, ln1_b, xln);
  // prep2: colnorm2 x2
  prep2_k<<<40, 256, 0, stream>>>(part_attn, apg, s_attn, part_mlp, mpg, s_mlp);

  // GEMM1 (256^2 2-phase): qkv = xln @ w_qkv^T + b
  GemmP p1 = {xln, wqkv_bf, b_qkv, nullptr, nullptr, qkv, 4096, 6144, 2048};
  g1_qkv256<<<384, 512, 65536, stream>>>(p1);

  // mid: vtrans + wproj scale-cast (fused)
  mid_k<<<3072, 256, 0, stream>>>(qkv, vtbuf, apv, s_attn, wproj_bf);

  // attention (kv-split x2) -> partials
  attn_k<<<1024, 512, 0, stream>>>(qkv, vtbuf, po, marr, larr);

  // post: combine + wfc cast + w2 scale-cast (fused)
  post_k<<<6144, 256, 0, stream>>>(po, marr, larr, attn_out, w_fc, wfc_bf,
                                   mpv, s_mlp, w2_bf);

  // GEMM2 (128x256 ring-2): hidden2 = attn_out @ w_proj^T + b + hidden
  GemmP p2 = {attn_out, wproj_bf, apb, hidden, hidden2, nullptr, 4096, 2048, 2048};
  g2_w128<<<256, 512, 98304, stream>>>(p2);

  // LN2 -> xln2
  ln_k<<<4096, 256, 0, stream>>>(hidden2, ln2_g, ln2_b, xln2);

  // GEMM3 (BK=64 ring-2)
  GemmP p3 = {xln2, wfc_bf, b_fc, nullptr, nullptr, hbuf, 4096, 8192, 2048};
  g3_fc64<<<512, 512, 131072, stream>>>(p3);

  // GEMM4 (128x256 ring-2, K=8192, direct): out = h @ w2^T + b + hidden2
  GemmP p4 = {hbuf, w2_bf, mpb, hidden2, (float*)d_out, nullptr, 4096, 2048, 8192};
  g4_w128<<<256, 512, 98304, stream>>>(p4);
}